// Round 12
// baseline (796.484 us; speedup 1.0000x reference)
//
#include <hip/hip_runtime.h>
#include <cstdint>
#include <cstddef>

#define GXd 480
#define GYd 360
#define NBd 2
#define GXY (480*360)
#define NCELL (NBd*GXY)
#define EPSBN 1e-5f

typedef float  f32x4  __attribute__((ext_vector_type(4)));
typedef short  bf16x8 __attribute__((ext_vector_type(8)));

// ---------- order-preserving float <-> uint map (residual atomics only) ----------
__device__ __forceinline__ unsigned mapf(float f){
    unsigned u = __float_as_uint(f);
    return (u & 0x80000000u) ? ~u : (u | 0x80000000u);
}
__device__ __forceinline__ float unmapf(unsigned m){
    return (m & 0x80000000u) ? __uint_as_float(m ^ 0x80000000u)
                             : __uint_as_float(~m);
}

// ---------- bf16 helpers (RTN-even) ----------
__device__ __forceinline__ unsigned short f2bf(float f){
    unsigned u = __float_as_uint(f);
    unsigned r = (u + 0x7FFFu + ((u >> 16) & 1u)) >> 16;
    return (unsigned short)r;
}
__device__ __forceinline__ float bf2f(unsigned short s){
    return __uint_as_float(((unsigned)s) << 16);
}

// ---------- dense layer helper ----------
template<int DIN, int DOUT>
__device__ __forceinline__ void dense(const float (&in)[DIN], float (&out)[DOUT],
                                      const float* __restrict__ w,
                                      const float* __restrict__ b){
#pragma unroll
    for (int j = 0; j < DOUT; j++) out[j] = b[j];
#pragma unroll
    for (int d = 0; d < DIN; d++){
        float v = in[d];
#pragma unroll
        for (int j = 0; j < DOUT; j++) out[j] = fmaf(v, w[d*DOUT + j], out[j]);
    }
}

// ---------- block-level sum/sumsq reduction ----------
template<int D>
__device__ __forceinline__ void reduce_stats(const float (&h)[D], bool valid,
                                             float* __restrict__ gsum,
                                             float* __restrict__ gsq){
    __shared__ float ssum[D];
    __shared__ float ssq[D];
    int tid = threadIdx.x;
    for (int t = tid; t < D; t += 256){ ssum[t] = 0.f; ssq[t] = 0.f; }
    __syncthreads();
#pragma unroll
    for (int j = 0; j < D; j++){
        float v = valid ? h[j] : 0.f;
        float s = v * v;
#pragma unroll
        for (int o = 32; o > 0; o >>= 1){
            v += __shfl_down(v, o, 64);
            s += __shfl_down(s, o, 64);
        }
        if ((tid & 63) == 0){
            atomicAdd(&ssum[j], v);
            atomicAdd(&ssq[j], s);
        }
    }
    __syncthreads();
    for (int t = tid; t < D; t += 256){
        atomicAdd(&gsum[t], ssum[t]);
        atomicAdd(&gsq[t], ssq[t]);
    }
}

// ---------- stats of raw input columns 0..8 ----------
__global__ __launch_bounds__(256)
void k_stats0(const float* __restrict__ fea, float* gsum, float* gsq, int n){
    int i = blockIdx.x*256 + threadIdx.x;
    bool valid = i < n;
    int i2 = valid ? i : 0;
    float x[9];
#pragma unroll
    for (int d = 0; d < 9; d++) x[d] = fea[(size_t)i2*11 + d];
    reduce_stats<9>(x, valid, gsum, gsq);
}

// ---------- finalize BN ----------
__global__ void k_fin(const float* __restrict__ sum, const float* __restrict__ sq,
                      const float* __restrict__ g, const float* __restrict__ bb,
                      float* __restrict__ a_out, float* __restrict__ c_out,
                      int D, float invN){
    int t = threadIdx.x;
    if (t < D){
        float mu  = sum[t] * invN;
        float var = fmaf(-mu, mu, sq[t] * invN);
        float rs  = rsqrtf(var + EPSBN);
        float a   = rs * g[t];
        a_out[t] = a;
        c_out[t] = fmaf(-mu, a, bb[t]);
    }
}

// ---------- layer1: bn0 -> 9x32; z1; stats; voxel count+rank; res atomics ----------
__global__ __launch_bounds__(256)
void k_l1(const float* __restrict__ fea, const int* __restrict__ ind,
          const float* __restrict__ w1, const float* __restrict__ b1,
          const float* __restrict__ a0, const float* __restrict__ c0,
          float* __restrict__ z1, unsigned* __restrict__ pres,
          unsigned* __restrict__ cnt, unsigned* __restrict__ rank,
          float* gsum, float* gsq, int n){
    int i = blockIdx.x*256 + threadIdx.x;
    bool valid = i < n;
    int i2 = valid ? i : 0;
    float x[9];
#pragma unroll
    for (int d = 0; d < 9; d++) x[d] = fmaf(fea[(size_t)i2*11 + d], a0[d], c0[d]);
    float h[32];
    dense<9,32>(x, h, w1, b1);
    if (valid){
        float4* dst = (float4*)(z1 + (size_t)i*32);
#pragma unroll
        for (int q = 0; q < 8; q++)
            dst[q] = make_float4(h[q*4], h[q*4+1], h[q*4+2], h[q*4+3]);
        float r0 = fea[(size_t)i*11 + 9];
        float r1 = fea[(size_t)i*11 + 10];
        int bb = ind[(size_t)i*3 + 0];
        int gx = ind[(size_t)i*3 + 1];
        int gy = ind[(size_t)i*3 + 2];
        unsigned vox = ((unsigned)bb*GXd + (unsigned)gx)*GYd + (unsigned)gy;
        rank[i] = atomicAdd(&cnt[vox], 1u);
        size_t rbase = (size_t)bb*2*GXY + (size_t)gx*GYd + gy;
        atomicMax(pres + rbase,       mapf(r0));
        atomicMax(pres + rbase + GXY, mapf(r1));
    }
    reduce_stats<32>(h, valid, gsum, gsq);
}

// ---------- layer2 via MFMA: z2[n x 64] = bn1relu(z1)[n x 32] @ w2 ----------
__global__ __launch_bounds__(256)
void k_l2(const float* __restrict__ z1,
          const float* __restrict__ w2, const float* __restrict__ b2,
          const float* __restrict__ a1, const float* __restrict__ c1,
          float* __restrict__ z2, float* gsum, float* gsq, int n){
    __shared__ short w2t[64*40];             // 5120 B
    __shared__ float ssum[64], ssq[64];
    int tid = threadIdx.x;
    if (tid < 64){ ssum[tid] = 0.f; ssq[tid] = 0.f; }
    for (int e = tid; e < 2048; e += 256){
        int k = e >> 6, c = e & 63;
        w2t[c*40 + k] = (short)f2bf(w2[k*64 + c]);
    }
    __syncthreads();

    int lane = tid & 63, wid = tid >> 6;
    int l15 = lane & 15, lg = lane >> 4;
    int p0 = blockIdx.x*64 + wid*16;
    int prow = p0 + l15;
    int prow2 = prow < n ? prow : (n - 1);
    const float* zrow = z1 + (size_t)prow2*32;

    int kbase = lg*8;
    float4 v0 = *(const float4*)(zrow + kbase);
    float4 v1 = *(const float4*)(zrow + kbase + 4);
    float4 av0 = *(const float4*)(a1 + kbase);
    float4 av1 = *(const float4*)(a1 + kbase + 4);
    float4 cv0 = *(const float4*)(c1 + kbase);
    float4 cv1 = *(const float4*)(c1 + kbase + 4);
    bf16x8 af;
    af[0] = (short)f2bf(fmaxf(fmaf(v0.x, av0.x, cv0.x), 0.f));
    af[1] = (short)f2bf(fmaxf(fmaf(v0.y, av0.y, cv0.y), 0.f));
    af[2] = (short)f2bf(fmaxf(fmaf(v0.z, av0.z, cv0.z), 0.f));
    af[3] = (short)f2bf(fmaxf(fmaf(v0.w, av0.w, cv0.w), 0.f));
    af[4] = (short)f2bf(fmaxf(fmaf(v1.x, av1.x, cv1.x), 0.f));
    af[5] = (short)f2bf(fmaxf(fmaf(v1.y, av1.y, cv1.y), 0.f));
    af[6] = (short)f2bf(fmaxf(fmaf(v1.z, av1.z, cv1.z), 0.f));
    af[7] = (short)f2bf(fmaxf(fmaf(v1.w, av1.w, cv1.w), 0.f));

    f32x4 acc[4];
#pragma unroll
    for (int t = 0; t < 4; t++){
        float bv = b2[t*16 + l15];
        acc[t] = (f32x4){bv, bv, bv, bv};
    }
#pragma unroll
    for (int t = 0; t < 4; t++){
        bf16x8 bf = *(const bf16x8*)&w2t[(t*16 + l15)*40 + kbase];
        acc[t] = __builtin_amdgcn_mfma_f32_16x16x32_bf16(af, bf, acc[t], 0, 0, 0);
    }

#pragma unroll
    for (int t = 0; t < 4; t++){
        int c = t*16 + l15;
        float s = 0.f, q = 0.f;
#pragma unroll
        for (int r = 0; r < 4; r++){
            int pr = p0 + lg*4 + r;
            float v = acc[t][r];
            if (pr < n){
                z2[(size_t)pr*64 + c] = v;
                s += v; q += v*v;
            }
        }
        s += __shfl_xor(s, 16, 64);  q += __shfl_xor(q, 16, 64);
        s += __shfl_xor(s, 32, 64);  q += __shfl_xor(q, 32, 64);
        if (lg == 0){ atomicAdd(&ssum[c], s); atomicAdd(&ssq[c], q); }
    }
    __syncthreads();
    if (tid < 64){ atomicAdd(gsum + tid, ssum[tid]); atomicAdd(gsq + tid, ssq[tid]); }
}

// ---------- layer3 via MFMA: z3[n x 128] = bn2relu(z2)[n x 64] @ w3 (bf16 out) ----------
__global__ __launch_bounds__(256)
void k_l3(const float* __restrict__ z2,
          const float* __restrict__ w3, const float* __restrict__ b3,
          const float* __restrict__ a2, const float* __restrict__ c2,
          unsigned short* __restrict__ z3, float* gsum, float* gsq, int n){
    __shared__ short w3t[128*72];            // 18432 B, [c][k] stride 72
    __shared__ float ssum[128], ssq[128];
    int tid = threadIdx.x;
    if (tid < 128){ ssum[tid] = 0.f; ssq[tid] = 0.f; }
    for (int e = tid; e < 8192; e += 256){
        int k = e >> 7, c = e & 127;
        w3t[c*72 + k] = (short)f2bf(w3[k*128 + c]);
    }
    __syncthreads();

    int lane = tid & 63, wid = tid >> 6;
    int l15 = lane & 15, lg = lane >> 4;
    int p0 = blockIdx.x*64 + wid*16;
    int prow = p0 + l15;
    int prow2 = prow < n ? prow : (n - 1);
    const float* zrow = z2 + (size_t)prow2*64;

    f32x4 acc[8];
#pragma unroll
    for (int t = 0; t < 8; t++){
        float bv = b3[t*16 + l15];
        acc[t] = (f32x4){bv, bv, bv, bv};
    }

#pragma unroll
    for (int ks = 0; ks < 2; ks++){
        int kbase = ks*32 + lg*8;
        float4 v0 = *(const float4*)(zrow + kbase);
        float4 v1 = *(const float4*)(zrow + kbase + 4);
        float4 av0 = *(const float4*)(a2 + kbase);
        float4 av1 = *(const float4*)(a2 + kbase + 4);
        float4 cv0 = *(const float4*)(c2 + kbase);
        float4 cv1 = *(const float4*)(c2 + kbase + 4);
        bf16x8 af;
        af[0] = (short)f2bf(fmaxf(fmaf(v0.x, av0.x, cv0.x), 0.f));
        af[1] = (short)f2bf(fmaxf(fmaf(v0.y, av0.y, cv0.y), 0.f));
        af[2] = (short)f2bf(fmaxf(fmaf(v0.z, av0.z, cv0.z), 0.f));
        af[3] = (short)f2bf(fmaxf(fmaf(v0.w, av0.w, cv0.w), 0.f));
        af[4] = (short)f2bf(fmaxf(fmaf(v1.x, av1.x, cv1.x), 0.f));
        af[5] = (short)f2bf(fmaxf(fmaf(v1.y, av1.y, cv1.y), 0.f));
        af[6] = (short)f2bf(fmaxf(fmaf(v1.z, av1.z, cv1.z), 0.f));
        af[7] = (short)f2bf(fmaxf(fmaf(v1.w, av1.w, cv1.w), 0.f));
#pragma unroll
        for (int t = 0; t < 8; t++){
            bf16x8 bf = *(const bf16x8*)&w3t[(t*16 + l15)*72 + kbase];
            acc[t] = __builtin_amdgcn_mfma_f32_16x16x32_bf16(af, bf, acc[t], 0, 0, 0);
        }
    }

#pragma unroll
    for (int t = 0; t < 8; t++){
        int c = t*16 + l15;
        float s = 0.f, q = 0.f;
#pragma unroll
        for (int r = 0; r < 4; r++){
            int pr = p0 + lg*4 + r;
            unsigned short rb = f2bf(acc[t][r]);
            float rv = bf2f(rb);
            if (pr < n){
                z3[(size_t)pr*128 + c] = rb;
                s += rv; q += rv*rv;
            }
        }
        s += __shfl_xor(s, 16, 64);  q += __shfl_xor(q, 16, 64);
        s += __shfl_xor(s, 32, 64);  q += __shfl_xor(q, 32, 64);
        if (lg == 0){ atomicAdd(&ssum[c], s); atomicAdd(&ssq[c], q); }
    }
    __syncthreads();
    if (tid < 128){ atomicAdd(gsum + tid, ssum[tid]); atomicAdd(gsq + tid, ssq[tid]); }
}

// ---------- exclusive scan of cnt via block tickets ----------
__global__ __launch_bounds__(256)
void k_off(const unsigned* __restrict__ cnt, unsigned* __restrict__ off,
           unsigned* __restrict__ gctr){
    __shared__ unsigned wtot[4];
    __shared__ unsigned wbase[4];
    int t = threadIdx.x;
    int lane = t & 63, w = t >> 6;
    int base = blockIdx.x * 1024 + t * 4;
    bool ok = base < NCELL;
    unsigned c0 = 0, c1 = 0, c2 = 0, c3 = 0;
    if (ok){ c0 = cnt[base]; c1 = cnt[base+1]; c2 = cnt[base+2]; c3 = cnt[base+3]; }
    unsigned tot = c0 + c1 + c2 + c3;
    unsigned incl = tot;
#pragma unroll
    for (int o = 1; o < 64; o <<= 1){
        unsigned v = __shfl_up(incl, o, 64);
        if (lane >= o) incl += v;
    }
    if (lane == 63) wtot[w] = incl;
    __syncthreads();
    if (t == 0){
        unsigned bt = wtot[0] + wtot[1] + wtot[2] + wtot[3];
        unsigned gb = atomicAdd(gctr, bt);
        unsigned s = 0;
#pragma unroll
        for (int q = 0; q < 4; q++){ wbase[q] = gb + s; s += wtot[q]; }
    }
    __syncthreads();
    if (ok){
        unsigned tb = wbase[w] + incl - tot;
        off[base]   = tb;
        off[base+1] = tb + c0;
        off[base+2] = tb + c0 + c1;
        off[base+3] = tb + c0 + c1 + c2;
    }
}

// ---------- fill per-cell point lists ----------
__global__ __launch_bounds__(256)
void k_fill(const int* __restrict__ ind, const unsigned* __restrict__ rank,
            const unsigned* __restrict__ off, unsigned* __restrict__ list, int n){
    int i = blockIdx.x*256 + threadIdx.x;
    if (i >= n) return;
    int bb = ind[(size_t)i*3], gx = ind[(size_t)i*3+1], gy = ind[(size_t)i*3+2];
    unsigned vox = ((unsigned)bb*GXd + (unsigned)gx)*GYd + (unsigned)gy;
    list[off[vox] + rank[i]] = (unsigned)i;
}

// ---------- layer4 via MFMA, SORTED output: z4[sorted_pos] = bn3relu(z3[list[pos]]) @ w4 ----------
__global__ __launch_bounds__(256)
void k_l4(const unsigned short* __restrict__ z3, const unsigned* __restrict__ list,
          const float* __restrict__ w4, const float* __restrict__ b4,
          const float* __restrict__ a3, const float* __restrict__ c3,
          unsigned short* __restrict__ z4, int n){
    __shared__ short w4t[256*128];           // 64 KB: bf16 w4^T [c][k], swizzled
    int tid = threadIdx.x;
    for (int e = tid; e < 16384; e += 256){
        int k2 = e >> 8;
        int c  = e & 255;
        unsigned lo = f2bf(w4[(size_t)(2*k2)*256 + c]);
        unsigned hi = f2bf(w4[(size_t)(2*k2+1)*256 + c]);
        int addr = (c*256 + k2*4) ^ ((c & 7) << 4);
        *(unsigned*)((char*)w4t + addr) = lo | (hi << 16);
    }
    __syncthreads();

    int lane = tid & 63, wid = tid >> 6;
    int l15 = lane & 15, lg = lane >> 4;
    int p0 = blockIdx.x*64 + wid*16;
    int prow = p0 + l15;
    int prow2 = prow < n ? prow : (n - 1);
    int srow = (int)list[prow2];             // original point id (sorted by cell)
    const unsigned short* zrow = z3 + (size_t)srow*128;

    f32x4 acc[16];
#pragma unroll
    for (int t = 0; t < 16; t++){
        float bv = b4[t*16 + l15];
        acc[t] = (f32x4){bv, bv, bv, bv};
    }

#pragma unroll
    for (int ks = 0; ks < 4; ks++){
        int kbase = ks*32 + lg*8;
        uint4 ua = *(const uint4*)(zrow + kbase);
        float4 av0 = *(const float4*)(a3 + kbase);
        float4 av1 = *(const float4*)(a3 + kbase + 4);
        float4 cv0 = *(const float4*)(c3 + kbase);
        float4 cv1 = *(const float4*)(c3 + kbase + 4);
        bf16x8 af;
        af[0] = (short)f2bf(fmaxf(fmaf(bf2f((unsigned short)(ua.x & 0xFFFFu)), av0.x, cv0.x), 0.f));
        af[1] = (short)f2bf(fmaxf(fmaf(bf2f((unsigned short)(ua.x >> 16)),     av0.y, cv0.y), 0.f));
        af[2] = (short)f2bf(fmaxf(fmaf(bf2f((unsigned short)(ua.y & 0xFFFFu)), av0.z, cv0.z), 0.f));
        af[3] = (short)f2bf(fmaxf(fmaf(bf2f((unsigned short)(ua.y >> 16)),     av0.w, cv0.w), 0.f));
        af[4] = (short)f2bf(fmaxf(fmaf(bf2f((unsigned short)(ua.z & 0xFFFFu)), av1.x, cv1.x), 0.f));
        af[5] = (short)f2bf(fmaxf(fmaf(bf2f((unsigned short)(ua.z >> 16)),     av1.y, cv1.y), 0.f));
        af[6] = (short)f2bf(fmaxf(fmaf(bf2f((unsigned short)(ua.w & 0xFFFFu)), av1.z, cv1.z), 0.f));
        af[7] = (short)f2bf(fmaxf(fmaf(bf2f((unsigned short)(ua.w >> 16)),     av1.w, cv1.w), 0.f));
#pragma unroll
        for (int t = 0; t < 16; t++){
            int c = t*16 + l15;
            int addr = (c*256 + kbase*2) ^ ((c & 7) << 4);
            bf16x8 bf = *(const bf16x8*)((const char*)w4t + addr);
            acc[t] = __builtin_amdgcn_mfma_f32_16x16x32_bf16(af, bf, acc[t], 0, 0, 0);
        }
    }

#pragma unroll
    for (int t = 0; t < 16; t++){
#pragma unroll
        for (int r = 0; r < 4; r++){
            int pr = p0 + lg*4 + r;
            if (pr < n)
                z4[(size_t)pr*256 + t*16 + l15] = f2bf(acc[t][r]);
        }
    }
}

// ---------- gather-max: streaming — cell's rows are contiguous in sorted z4 ----------
__global__ __launch_bounds__(256)
void k_gather(const unsigned* __restrict__ cnt, const unsigned* __restrict__ off,
              const unsigned short* __restrict__ z4,
              unsigned short* __restrict__ pooled){
    int lane = threadIdx.x & 63;
    int wid  = blockIdx.x*4 + (threadIdx.x >> 6);
    int wstride = gridDim.x * 4;
    for (int cell = wid; cell < NCELL; cell += wstride){
        unsigned cn = cnt[cell];
        unsigned o  = off[cell];
        float m0 = -__builtin_inff(), m1 = m0, m2 = m0, m3 = m0;
        for (unsigned p = 0; p < cn; p++){
            uint2 u = *(const uint2*)(z4 + (size_t)(o + p)*256 + lane*4);
            m0 = fmaxf(m0, __uint_as_float(u.x << 16));
            m1 = fmaxf(m1, __uint_as_float(u.x & 0xFFFF0000u));
            m2 = fmaxf(m2, __uint_as_float(u.y << 16));
            m3 = fmaxf(m3, __uint_as_float(u.y & 0xFFFF0000u));
        }
        if (cn == 0){ m0 = m1 = m2 = m3 = 0.f; }
        unsigned p0 = (__float_as_uint(m0) >> 16) | (__float_as_uint(m1) & 0xFFFF0000u);
        unsigned p1 = (__float_as_uint(m2) >> 16) | (__float_as_uint(m3) & 0xFFFF0000u);
        *(uint2*)(pooled + (size_t)cell*256 + lane*4) = make_uint2(p0, p1);
    }
}

// ---------- 3x3 maxpool: 4gx x 8gy tile, 16 KB LDS -> 8 blocks/CU ----------
// Phase 1: thread (cpair=t&127 -> 2 channels, ysub=t>>7 -> 4 output rows);
// 6-step rolling loop, uint (2ch) loads. Phase 2: c=t, float4 planar stores,
// fully unrolled (8 stores). 360 = 45*8, no ragged tail.
__global__ __launch_bounds__(256)
void k_maxpool(const unsigned short* __restrict__ pooled, float* __restrict__ out){
    __shared__ unsigned short tile[4*8*256];    // [g][yl][c] bf16 = 16 KB
    int t = threadIdx.x;
    int cpair = t & 127;                        // channels 2*cpair, 2*cpair+1
    int ysub  = t >> 7;                         // 0/1: output rows [ysub*4, ysub*4+4)
    int gy0 = blockIdx.x * 8;
    int gx0 = blockIdx.y * 4;
    int b   = blockIdx.z;
    const unsigned short* base = pooled + (size_t)b*GXY*256 + cpair*2;

    float cA0[4], cA1[4], cB0[4], cB1[4];
#pragma unroll
    for (int g = 0; g < 4; g++){ cA0[g]=cA1[g]=cB0[g]=cB1[g]=0.f; }
    int yb = gy0 + ysub*4;
    for (int tt = 0; tt < 6; tt++){
        int yy = yb - 1 + tt;
        bool yok = (unsigned)yy < (unsigned)GYd;
        float v0[6], v1[6];
#pragma unroll
        for (int r = 0; r < 6; r++){
            int xx = gx0 - 1 + r;
            float u0 = -__builtin_inff(), u1 = u0;
            if (yok && (unsigned)xx < (unsigned)GXd){
                unsigned u = *(const unsigned*)(base + ((size_t)xx*GYd + yy)*256);
                u0 = bf2f((unsigned short)(u & 0xFFFFu));
                u1 = bf2f((unsigned short)(u >> 16));
            }
            v0[r] = u0; v1[r] = u1;
        }
        float cm0[4], cm1[4];
#pragma unroll
        for (int g = 0; g < 4; g++){
            cm0[g] = fmaxf(fmaxf(v0[g], v0[g+1]), v0[g+2]);
            cm1[g] = fmaxf(fmaxf(v1[g], v1[g+1]), v1[g+2]);
        }
        if (tt >= 2){
            int yl = ysub*4 + tt - 2;           // 0..7
#pragma unroll
            for (int g = 0; g < 4; g++){
                float m0 = fmaxf(fmaxf(cA0[g], cB0[g]), cm0[g]);
                float m1 = fmaxf(fmaxf(cA1[g], cB1[g]), cm1[g]);
                *(unsigned*)&tile[(g*8 + yl)*256 + cpair*2] =
                    (unsigned)f2bf(m0) | ((unsigned)f2bf(m1) << 16);
            }
        }
#pragma unroll
        for (int g = 0; g < 4; g++){
            cA0[g] = cB0[g]; cB0[g] = cm0[g];
            cA1[g] = cB1[g]; cB1[g] = cm1[g];
        }
    }
    __syncthreads();

    int c = t;
#pragma unroll
    for (int g = 0; g < 4; g++){
        float* dst = out + ((size_t)b*258 + c)*GXY + (size_t)(gx0+g)*GYd + gy0;
        const unsigned short* srcl = &tile[g*8*256 + c];
#pragma unroll
        for (int y = 0; y < 8; y += 4){
            float4 o4;
            o4.x = bf2f(srcl[(y+0)*256]);
            o4.y = bf2f(srcl[(y+1)*256]);
            o4.z = bf2f(srcl[(y+2)*256]);
            o4.w = bf2f(srcl[(y+3)*256]);
            *(float4*)(dst + y) = o4;
        }
    }
}

// ---------- residual channels ----------
__global__ __launch_bounds__(256)
void k_res(const unsigned* __restrict__ pres, float* __restrict__ out){
    int idx = blockIdx.x*256 + threadIdx.x;
    const int total = NBd*2*GXY;
    if (idx >= total) return;
    int gy = idx % GYd;
    int t  = idx / GYd;
    int gx = t % GXd;  t /= GXd;
    int r  = t & 1;
    int b  = t >> 1;
    unsigned u = pres[idx];
    float f = u ? unmapf(u) : 0.f;
    out[(((size_t)b*258 + 256 + r)*GXd + gx)*GYd + gy] = f;
}

extern "C" void kernel_launch(void* const* d_in, const int* in_sizes, int n_in,
                              void* d_out, int out_size, void* d_ws, size_t ws_size,
                              hipStream_t stream){
    (void)n_in; (void)out_size; (void)ws_size;
    const float* fea   = (const float*)d_in[0];
    const int*   ind   = (const int*)  d_in[1];
    const float* bn0_g = (const float*)d_in[2];
    const float* bn0_b = (const float*)d_in[3];
    const float* w1    = (const float*)d_in[4];
    const float* b1    = (const float*)d_in[5];
    const float* bn1_g = (const float*)d_in[6];
    const float* bn1_b = (const float*)d_in[7];
    const float* w2    = (const float*)d_in[8];
    const float* b2    = (const float*)d_in[9];
    const float* bn2_g = (const float*)d_in[10];
    const float* bn2_b = (const float*)d_in[11];
    const float* w3    = (const float*)d_in[12];
    const float* b3    = (const float*)d_in[13];
    const float* bn3_g = (const float*)d_in[14];
    const float* bn3_b = (const float*)d_in[15];
    const float* w4    = (const float*)d_in[16];
    const float* b4    = (const float*)d_in[17];

    int n = in_sizes[0] / 11;
    float invN = 1.0f / (float)n;

    // ---- ws layout ----
    const size_t Z4_B     = (size_t)240000*256*2;       // 122,880,000
    const size_t POOL_B   = (size_t)NCELL*256*2;        // 176,947,200
    const size_t PRES_B   = (size_t)NBd*2*GXY*4;        //   5,529,600
    const size_t CNT_B    = (size_t)NCELL*4;            //   2,764,800
    const size_t STAT_B   = 960*4;
    const size_t GCTR_B   = 256;

    char* base = (char*)d_ws;
    unsigned short* z4     = (unsigned short*)base;
    unsigned short* pooled = (unsigned short*)(base + Z4_B);
    // z1/z2/z3 alias the pooled region (dead before k_gather writes it)
    float*          z1     = (float*)(base + Z4_B);
    float*          z2     = (float*)(base + Z4_B + 30720000);
    unsigned short* z3     = (unsigned short*)(base + Z4_B + 92160000);
    unsigned* pres  = (unsigned*)(base + Z4_B + POOL_B);
    unsigned* cnt   = (unsigned*)((char*)pres + PRES_B);
    float*    stats = (float*)((char*)cnt + CNT_B);
    unsigned* gctr  = (unsigned*)((char*)stats + STAT_B);
    unsigned* off   = (unsigned*)((char*)gctr + GCTR_B);
    unsigned* list  = (unsigned*)((char*)off + CNT_B);
    unsigned* rank  = (unsigned*)((char*)list + (size_t)240000*4);

    float* sum0 = stats;       float* sq0 = stats + 16;
    float* sum1 = stats + 32;  float* sq1 = stats + 64;
    float* sum2 = stats + 96;  float* sq2 = stats + 160;
    float* sum3 = stats + 224; float* sq3 = stats + 352;
    float* a0 = stats + 480;   float* c0 = stats + 496;
    float* a1 = stats + 512;   float* c1 = stats + 544;
    float* a2 = stats + 576;   float* c2 = stats + 640;
    float* a3 = stats + 704;   float* c3 = stats + 832;

    hipMemsetAsync(pres, 0, PRES_B + CNT_B + STAT_B + GCTR_B, stream);

    int nb = (n + 255) / 256;
    int nb64 = (n + 63) / 64;
    k_stats0<<<nb, 256, 0, stream>>>(fea, sum0, sq0, n);
    k_fin<<<1, 128, 0, stream>>>(sum0, sq0, bn0_g, bn0_b, a0, c0, 9,  invN);
    k_l1<<<nb, 256, 0, stream>>>(fea, ind, w1, b1, a0, c0, z1, pres, cnt, rank, sum1, sq1, n);
    k_fin<<<1, 128, 0, stream>>>(sum1, sq1, bn1_g, bn1_b, a1, c1, 32, invN);
    k_l2<<<nb64, 256, 0, stream>>>(z1, w2, b2, a1, c1, z2, sum2, sq2, n);
    k_fin<<<1, 128, 0, stream>>>(sum2, sq2, bn2_g, bn2_b, a2, c2, 64, invN);
    k_l3<<<nb64, 256, 0, stream>>>(z2, w3, b3, a2, c2, z3, sum3, sq3, n);
    k_fin<<<1, 128, 0, stream>>>(sum3, sq3, bn3_g, bn3_b, a3, c3, 128, invN);

    k_off <<<(NCELL + 1023)/1024, 256, 0, stream>>>(cnt, off, gctr);
    k_fill<<<nb, 256, 0, stream>>>(ind, rank, off, list, n);

    k_l4<<<nb64, 256, 0, stream>>>(z3, list, w4, b4, a3, c3, z4, n);

    k_gather<<<2048, 256, 0, stream>>>(cnt, off, z4, pooled);

    k_maxpool<<<dim3(45, 120, 2), 256, 0, stream>>>(pooled, (float*)d_out);
    k_res<<<(NBd*2*GXY + 255) / 256, 256, 0, stream>>>(pres, (float*)d_out);
}

// Round 13
// 787.597 us; speedup vs baseline: 1.0113x; 1.0113x over previous
//
#include <hip/hip_runtime.h>
#include <cstdint>
#include <cstddef>

#define GXd 480
#define GYd 360
#define NBd 2
#define GXY (480*360)
#define NCELL (NBd*GXY)
#define EPSBN 1e-5f

typedef float  f32x4  __attribute__((ext_vector_type(4)));
typedef short  bf16x8 __attribute__((ext_vector_type(8)));

// ---------- order-preserving float <-> uint map (residual atomics only) ----------
__device__ __forceinline__ unsigned mapf(float f){
    unsigned u = __float_as_uint(f);
    return (u & 0x80000000u) ? ~u : (u | 0x80000000u);
}
__device__ __forceinline__ float unmapf(unsigned m){
    return (m & 0x80000000u) ? __uint_as_float(m ^ 0x80000000u)
                             : __uint_as_float(~m);
}

// ---------- bf16 helpers (RTN-even) ----------
__device__ __forceinline__ unsigned short f2bf(float f){
    unsigned u = __float_as_uint(f);
    unsigned r = (u + 0x7FFFu + ((u >> 16) & 1u)) >> 16;
    return (unsigned short)r;
}
__device__ __forceinline__ float bf2f(unsigned short s){
    return __uint_as_float(((unsigned)s) << 16);
}

// ---------- dense layer helper ----------
template<int DIN, int DOUT>
__device__ __forceinline__ void dense(const float (&in)[DIN], float (&out)[DOUT],
                                      const float* __restrict__ w,
                                      const float* __restrict__ b){
#pragma unroll
    for (int j = 0; j < DOUT; j++) out[j] = b[j];
#pragma unroll
    for (int d = 0; d < DIN; d++){
        float v = in[d];
#pragma unroll
        for (int j = 0; j < DOUT; j++) out[j] = fmaf(v, w[d*DOUT + j], out[j]);
    }
}

// ---------- block-level sum/sumsq reduction ----------
template<int D>
__device__ __forceinline__ void reduce_stats(const float (&h)[D], bool valid,
                                             float* __restrict__ gsum,
                                             float* __restrict__ gsq){
    __shared__ float ssum[D];
    __shared__ float ssq[D];
    int tid = threadIdx.x;
    for (int t = tid; t < D; t += 256){ ssum[t] = 0.f; ssq[t] = 0.f; }
    __syncthreads();
#pragma unroll
    for (int j = 0; j < D; j++){
        float v = valid ? h[j] : 0.f;
        float s = v * v;
#pragma unroll
        for (int o = 32; o > 0; o >>= 1){
            v += __shfl_down(v, o, 64);
            s += __shfl_down(s, o, 64);
        }
        if ((tid & 63) == 0){
            atomicAdd(&ssum[j], v);
            atomicAdd(&ssq[j], s);
        }
    }
    __syncthreads();
    for (int t = tid; t < D; t += 256){
        atomicAdd(&gsum[t], ssum[t]);
        atomicAdd(&gsq[t], ssq[t]);
    }
}

// ---------- stats of raw input columns 0..8 ----------
__global__ __launch_bounds__(256)
void k_stats0(const float* __restrict__ fea, float* gsum, float* gsq, int n){
    int i = blockIdx.x*256 + threadIdx.x;
    bool valid = i < n;
    int i2 = valid ? i : 0;
    float x[9];
#pragma unroll
    for (int d = 0; d < 9; d++) x[d] = fea[(size_t)i2*11 + d];
    reduce_stats<9>(x, valid, gsum, gsq);
}

// ---------- finalize BN ----------
__global__ void k_fin(const float* __restrict__ sum, const float* __restrict__ sq,
                      const float* __restrict__ g, const float* __restrict__ bb,
                      float* __restrict__ a_out, float* __restrict__ c_out,
                      int D, float invN){
    int t = threadIdx.x;
    if (t < D){
        float mu  = sum[t] * invN;
        float var = fmaf(-mu, mu, sq[t] * invN);
        float rs  = rsqrtf(var + EPSBN);
        float a   = rs * g[t];
        a_out[t] = a;
        c_out[t] = fmaf(-mu, a, bb[t]);
    }
}

// ---------- layer1: bn0 -> 9x32; z1; stats; voxel count+rank; res atomics ----------
__global__ __launch_bounds__(256)
void k_l1(const float* __restrict__ fea, const int* __restrict__ ind,
          const float* __restrict__ w1, const float* __restrict__ b1,
          const float* __restrict__ a0, const float* __restrict__ c0,
          float* __restrict__ z1, unsigned* __restrict__ pres,
          unsigned* __restrict__ cnt, unsigned* __restrict__ rank,
          float* gsum, float* gsq, int n){
    int i = blockIdx.x*256 + threadIdx.x;
    bool valid = i < n;
    int i2 = valid ? i : 0;
    float x[9];
#pragma unroll
    for (int d = 0; d < 9; d++) x[d] = fmaf(fea[(size_t)i2*11 + d], a0[d], c0[d]);
    float h[32];
    dense<9,32>(x, h, w1, b1);
    if (valid){
        float4* dst = (float4*)(z1 + (size_t)i*32);
#pragma unroll
        for (int q = 0; q < 8; q++)
            dst[q] = make_float4(h[q*4], h[q*4+1], h[q*4+2], h[q*4+3]);
        float r0 = fea[(size_t)i*11 + 9];
        float r1 = fea[(size_t)i*11 + 10];
        int bb = ind[(size_t)i*3 + 0];
        int gx = ind[(size_t)i*3 + 1];
        int gy = ind[(size_t)i*3 + 2];
        unsigned vox = ((unsigned)bb*GXd + (unsigned)gx)*GYd + (unsigned)gy;
        rank[i] = atomicAdd(&cnt[vox], 1u);
        size_t rbase = (size_t)bb*2*GXY + (size_t)gx*GYd + gy;
        atomicMax(pres + rbase,       mapf(r0));
        atomicMax(pres + rbase + GXY, mapf(r1));
    }
    reduce_stats<32>(h, valid, gsum, gsq);
}

// ---------- layer2 via MFMA: z2[n x 64] = bn1relu(z1)[n x 32] @ w2 ----------
__global__ __launch_bounds__(256)
void k_l2(const float* __restrict__ z1,
          const float* __restrict__ w2, const float* __restrict__ b2,
          const float* __restrict__ a1, const float* __restrict__ c1,
          float* __restrict__ z2, float* gsum, float* gsq, int n){
    __shared__ short w2t[64*40];             // 5120 B
    __shared__ float ssum[64], ssq[64];
    int tid = threadIdx.x;
    if (tid < 64){ ssum[tid] = 0.f; ssq[tid] = 0.f; }
    for (int e = tid; e < 2048; e += 256){
        int k = e >> 6, c = e & 63;
        w2t[c*40 + k] = (short)f2bf(w2[k*64 + c]);
    }
    __syncthreads();

    int lane = tid & 63, wid = tid >> 6;
    int l15 = lane & 15, lg = lane >> 4;
    int p0 = blockIdx.x*64 + wid*16;
    int prow = p0 + l15;
    int prow2 = prow < n ? prow : (n - 1);
    const float* zrow = z1 + (size_t)prow2*32;

    int kbase = lg*8;
    float4 v0 = *(const float4*)(zrow + kbase);
    float4 v1 = *(const float4*)(zrow + kbase + 4);
    float4 av0 = *(const float4*)(a1 + kbase);
    float4 av1 = *(const float4*)(a1 + kbase + 4);
    float4 cv0 = *(const float4*)(c1 + kbase);
    float4 cv1 = *(const float4*)(c1 + kbase + 4);
    bf16x8 af;
    af[0] = (short)f2bf(fmaxf(fmaf(v0.x, av0.x, cv0.x), 0.f));
    af[1] = (short)f2bf(fmaxf(fmaf(v0.y, av0.y, cv0.y), 0.f));
    af[2] = (short)f2bf(fmaxf(fmaf(v0.z, av0.z, cv0.z), 0.f));
    af[3] = (short)f2bf(fmaxf(fmaf(v0.w, av0.w, cv0.w), 0.f));
    af[4] = (short)f2bf(fmaxf(fmaf(v1.x, av1.x, cv1.x), 0.f));
    af[5] = (short)f2bf(fmaxf(fmaf(v1.y, av1.y, cv1.y), 0.f));
    af[6] = (short)f2bf(fmaxf(fmaf(v1.z, av1.z, cv1.z), 0.f));
    af[7] = (short)f2bf(fmaxf(fmaf(v1.w, av1.w, cv1.w), 0.f));

    f32x4 acc[4];
#pragma unroll
    for (int t = 0; t < 4; t++){
        float bv = b2[t*16 + l15];
        acc[t] = (f32x4){bv, bv, bv, bv};
    }
#pragma unroll
    for (int t = 0; t < 4; t++){
        bf16x8 bf = *(const bf16x8*)&w2t[(t*16 + l15)*40 + kbase];
        acc[t] = __builtin_amdgcn_mfma_f32_16x16x32_bf16(af, bf, acc[t], 0, 0, 0);
    }

#pragma unroll
    for (int t = 0; t < 4; t++){
        int c = t*16 + l15;
        float s = 0.f, q = 0.f;
#pragma unroll
        for (int r = 0; r < 4; r++){
            int pr = p0 + lg*4 + r;
            float v = acc[t][r];
            if (pr < n){
                z2[(size_t)pr*64 + c] = v;
                s += v; q += v*v;
            }
        }
        s += __shfl_xor(s, 16, 64);  q += __shfl_xor(q, 16, 64);
        s += __shfl_xor(s, 32, 64);  q += __shfl_xor(q, 32, 64);
        if (lg == 0){ atomicAdd(&ssum[c], s); atomicAdd(&ssq[c], q); }
    }
    __syncthreads();
    if (tid < 64){ atomicAdd(gsum + tid, ssum[tid]); atomicAdd(gsq + tid, ssq[tid]); }
}

// ---------- layer3 via MFMA: z3[n x 128] = bn2relu(z2)[n x 64] @ w3 (bf16 out) ----------
__global__ __launch_bounds__(256)
void k_l3(const float* __restrict__ z2,
          const float* __restrict__ w3, const float* __restrict__ b3,
          const float* __restrict__ a2, const float* __restrict__ c2,
          unsigned short* __restrict__ z3, float* gsum, float* gsq, int n){
    __shared__ short w3t[128*72];            // 18432 B, [c][k] stride 72
    __shared__ float ssum[128], ssq[128];
    int tid = threadIdx.x;
    if (tid < 128){ ssum[tid] = 0.f; ssq[tid] = 0.f; }
    for (int e = tid; e < 8192; e += 256){
        int k = e >> 7, c = e & 127;
        w3t[c*72 + k] = (short)f2bf(w3[k*128 + c]);
    }
    __syncthreads();

    int lane = tid & 63, wid = tid >> 6;
    int l15 = lane & 15, lg = lane >> 4;
    int p0 = blockIdx.x*64 + wid*16;
    int prow = p0 + l15;
    int prow2 = prow < n ? prow : (n - 1);
    const float* zrow = z2 + (size_t)prow2*64;

    f32x4 acc[8];
#pragma unroll
    for (int t = 0; t < 8; t++){
        float bv = b3[t*16 + l15];
        acc[t] = (f32x4){bv, bv, bv, bv};
    }

#pragma unroll
    for (int ks = 0; ks < 2; ks++){
        int kbase = ks*32 + lg*8;
        float4 v0 = *(const float4*)(zrow + kbase);
        float4 v1 = *(const float4*)(zrow + kbase + 4);
        float4 av0 = *(const float4*)(a2 + kbase);
        float4 av1 = *(const float4*)(a2 + kbase + 4);
        float4 cv0 = *(const float4*)(c2 + kbase);
        float4 cv1 = *(const float4*)(c2 + kbase + 4);
        bf16x8 af;
        af[0] = (short)f2bf(fmaxf(fmaf(v0.x, av0.x, cv0.x), 0.f));
        af[1] = (short)f2bf(fmaxf(fmaf(v0.y, av0.y, cv0.y), 0.f));
        af[2] = (short)f2bf(fmaxf(fmaf(v0.z, av0.z, cv0.z), 0.f));
        af[3] = (short)f2bf(fmaxf(fmaf(v0.w, av0.w, cv0.w), 0.f));
        af[4] = (short)f2bf(fmaxf(fmaf(v1.x, av1.x, cv1.x), 0.f));
        af[5] = (short)f2bf(fmaxf(fmaf(v1.y, av1.y, cv1.y), 0.f));
        af[6] = (short)f2bf(fmaxf(fmaf(v1.z, av1.z, cv1.z), 0.f));
        af[7] = (short)f2bf(fmaxf(fmaf(v1.w, av1.w, cv1.w), 0.f));
#pragma unroll
        for (int t = 0; t < 8; t++){
            bf16x8 bf = *(const bf16x8*)&w3t[(t*16 + l15)*72 + kbase];
            acc[t] = __builtin_amdgcn_mfma_f32_16x16x32_bf16(af, bf, acc[t], 0, 0, 0);
        }
    }

#pragma unroll
    for (int t = 0; t < 8; t++){
        int c = t*16 + l15;
        float s = 0.f, q = 0.f;
#pragma unroll
        for (int r = 0; r < 4; r++){
            int pr = p0 + lg*4 + r;
            unsigned short rb = f2bf(acc[t][r]);
            float rv = bf2f(rb);
            if (pr < n){
                z3[(size_t)pr*128 + c] = rb;
                s += rv; q += rv*rv;
            }
        }
        s += __shfl_xor(s, 16, 64);  q += __shfl_xor(q, 16, 64);
        s += __shfl_xor(s, 32, 64);  q += __shfl_xor(q, 32, 64);
        if (lg == 0){ atomicAdd(&ssum[c], s); atomicAdd(&ssq[c], q); }
    }
    __syncthreads();
    if (tid < 128){ atomicAdd(gsum + tid, ssum[tid]); atomicAdd(gsq + tid, ssq[tid]); }
}

// ---------- exclusive scan of cnt via block tickets ----------
__global__ __launch_bounds__(256)
void k_off(const unsigned* __restrict__ cnt, unsigned* __restrict__ off,
           unsigned* __restrict__ gctr){
    __shared__ unsigned wtot[4];
    __shared__ unsigned wbase[4];
    int t = threadIdx.x;
    int lane = t & 63, w = t >> 6;
    int base = blockIdx.x * 1024 + t * 4;
    bool ok = base < NCELL;
    unsigned c0 = 0, c1 = 0, c2 = 0, c3 = 0;
    if (ok){ c0 = cnt[base]; c1 = cnt[base+1]; c2 = cnt[base+2]; c3 = cnt[base+3]; }
    unsigned tot = c0 + c1 + c2 + c3;
    unsigned incl = tot;
#pragma unroll
    for (int o = 1; o < 64; o <<= 1){
        unsigned v = __shfl_up(incl, o, 64);
        if (lane >= o) incl += v;
    }
    if (lane == 63) wtot[w] = incl;
    __syncthreads();
    if (t == 0){
        unsigned bt = wtot[0] + wtot[1] + wtot[2] + wtot[3];
        unsigned gb = atomicAdd(gctr, bt);
        unsigned s = 0;
#pragma unroll
        for (int q = 0; q < 4; q++){ wbase[q] = gb + s; s += wtot[q]; }
    }
    __syncthreads();
    if (ok){
        unsigned tb = wbase[w] + incl - tot;
        off[base]   = tb;
        off[base+1] = tb + c0;
        off[base+2] = tb + c0 + c1;
        off[base+3] = tb + c0 + c1 + c2;
    }
}

// ---------- fill per-cell point lists ----------
__global__ __launch_bounds__(256)
void k_fill(const int* __restrict__ ind, const unsigned* __restrict__ rank,
            const unsigned* __restrict__ off, unsigned* __restrict__ list, int n){
    int i = blockIdx.x*256 + threadIdx.x;
    if (i >= n) return;
    int bb = ind[(size_t)i*3], gx = ind[(size_t)i*3+1], gy = ind[(size_t)i*3+2];
    unsigned vox = ((unsigned)bb*GXd + (unsigned)gx)*GYd + (unsigned)gy;
    list[off[vox] + rank[i]] = (unsigned)i;
}

// ---------- layer4 via MFMA, SORTED output: z4[sorted_pos] = bn3relu(z3[list[pos]]) @ w4 ----------
__global__ __launch_bounds__(256)
void k_l4(const unsigned short* __restrict__ z3, const unsigned* __restrict__ list,
          const float* __restrict__ w4, const float* __restrict__ b4,
          const float* __restrict__ a3, const float* __restrict__ c3,
          unsigned short* __restrict__ z4, int n){
    __shared__ short w4t[256*128];           // 64 KB: bf16 w4^T [c][k], swizzled
    int tid = threadIdx.x;
    for (int e = tid; e < 16384; e += 256){
        int k2 = e >> 8;
        int c  = e & 255;
        unsigned lo = f2bf(w4[(size_t)(2*k2)*256 + c]);
        unsigned hi = f2bf(w4[(size_t)(2*k2+1)*256 + c]);
        int addr = (c*256 + k2*4) ^ ((c & 7) << 4);
        *(unsigned*)((char*)w4t + addr) = lo | (hi << 16);
    }
    __syncthreads();

    int lane = tid & 63, wid = tid >> 6;
    int l15 = lane & 15, lg = lane >> 4;
    int p0 = blockIdx.x*64 + wid*16;
    int prow = p0 + l15;
    int prow2 = prow < n ? prow : (n - 1);
    int srow = (int)list[prow2];             // original point id (sorted by cell)
    const unsigned short* zrow = z3 + (size_t)srow*128;

    f32x4 acc[16];
#pragma unroll
    for (int t = 0; t < 16; t++){
        float bv = b4[t*16 + l15];
        acc[t] = (f32x4){bv, bv, bv, bv};
    }

#pragma unroll
    for (int ks = 0; ks < 4; ks++){
        int kbase = ks*32 + lg*8;
        uint4 ua = *(const uint4*)(zrow + kbase);
        float4 av0 = *(const float4*)(a3 + kbase);
        float4 av1 = *(const float4*)(a3 + kbase + 4);
        float4 cv0 = *(const float4*)(c3 + kbase);
        float4 cv1 = *(const float4*)(c3 + kbase + 4);
        bf16x8 af;
        af[0] = (short)f2bf(fmaxf(fmaf(bf2f((unsigned short)(ua.x & 0xFFFFu)), av0.x, cv0.x), 0.f));
        af[1] = (short)f2bf(fmaxf(fmaf(bf2f((unsigned short)(ua.x >> 16)),     av0.y, cv0.y), 0.f));
        af[2] = (short)f2bf(fmaxf(fmaf(bf2f((unsigned short)(ua.y & 0xFFFFu)), av0.z, cv0.z), 0.f));
        af[3] = (short)f2bf(fmaxf(fmaf(bf2f((unsigned short)(ua.y >> 16)),     av0.w, cv0.w), 0.f));
        af[4] = (short)f2bf(fmaxf(fmaf(bf2f((unsigned short)(ua.z & 0xFFFFu)), av1.x, cv1.x), 0.f));
        af[5] = (short)f2bf(fmaxf(fmaf(bf2f((unsigned short)(ua.z >> 16)),     av1.y, cv1.y), 0.f));
        af[6] = (short)f2bf(fmaxf(fmaf(bf2f((unsigned short)(ua.w & 0xFFFFu)), av1.z, cv1.z), 0.f));
        af[7] = (short)f2bf(fmaxf(fmaf(bf2f((unsigned short)(ua.w >> 16)),     av1.w, cv1.w), 0.f));
#pragma unroll
        for (int t = 0; t < 16; t++){
            int c = t*16 + l15;
            int addr = (c*256 + kbase*2) ^ ((c & 7) << 4);
            bf16x8 bf = *(const bf16x8*)((const char*)w4t + addr);
            acc[t] = __builtin_amdgcn_mfma_f32_16x16x32_bf16(af, bf, acc[t], 0, 0, 0);
        }
    }

#pragma unroll
    for (int t = 0; t < 16; t++){
#pragma unroll
        for (int r = 0; r < 4; r++){
            int pr = p0 + lg*4 + r;
            if (pr < n)
                z4[(size_t)pr*256 + t*16 + l15] = f2bf(acc[t][r]);
        }
    }
}

// ---------- gather-max: streaming — cell's rows are contiguous in sorted z4 ----------
__global__ __launch_bounds__(256)
void k_gather(const unsigned* __restrict__ cnt, const unsigned* __restrict__ off,
              const unsigned short* __restrict__ z4,
              unsigned short* __restrict__ pooled){
    int lane = threadIdx.x & 63;
    int wid  = blockIdx.x*4 + (threadIdx.x >> 6);
    int wstride = gridDim.x * 4;
    for (int cell = wid; cell < NCELL; cell += wstride){
        unsigned cn = cnt[cell];
        unsigned o  = off[cell];
        float m0 = -__builtin_inff(), m1 = m0, m2 = m0, m3 = m0;
        for (unsigned p = 0; p < cn; p++){
            uint2 u = *(const uint2*)(z4 + (size_t)(o + p)*256 + lane*4);
            m0 = fmaxf(m0, __uint_as_float(u.x << 16));
            m1 = fmaxf(m1, __uint_as_float(u.x & 0xFFFF0000u));
            m2 = fmaxf(m2, __uint_as_float(u.y << 16));
            m3 = fmaxf(m3, __uint_as_float(u.y & 0xFFFF0000u));
        }
        if (cn == 0){ m0 = m1 = m2 = m3 = 0.f; }
        unsigned p0 = (__float_as_uint(m0) >> 16) | (__float_as_uint(m1) & 0xFFFF0000u);
        unsigned p1 = (__float_as_uint(m2) >> 16) | (__float_as_uint(m3) & 0xFFFF0000u);
        *(uint2*)(pooled + (size_t)cell*256 + lane*4) = make_uint2(p0, p1);
    }
}

// ---------- 3x3 maxpool: 4gx x 8gy tile (16 KB, 8 blk/CU) + 4ch/thread uint2 loads ----------
// Phase 1: wave-uniform ysub = tid>>6 (2 output rows/wave, 4-step rolling loop);
// lane = channel-quad -> uint2 loads, 512 B/wave/instr. 24 independent loads/thread.
// Phase 2: c = tid, float4 planar stores (full-line fills). 360 = 45*8, no tail.
__global__ __launch_bounds__(256)
void k_maxpool(const unsigned short* __restrict__ pooled, float* __restrict__ out){
    __shared__ unsigned short tile[4*8*256];    // [g][yl][c] bf16 = 16 KB
    int t = threadIdx.x;
    int c4   = t & 63;                          // channels 4*c4 .. 4*c4+3
    int ysub = t >> 6;                          // 0..3: output rows [ysub*2, ysub*2+2)
    int gy0 = blockIdx.x * 8;
    int gx0 = blockIdx.y * 4;
    int b   = blockIdx.z;
    const unsigned short* base = pooled + (size_t)b*GXY*256 + c4*4;

    float cA[4][4], cB[4][4];                   // [ch][g] rolling window
#pragma unroll
    for (int ch = 0; ch < 4; ch++)
#pragma unroll
        for (int g = 0; g < 4; g++){ cA[ch][g] = 0.f; cB[ch][g] = 0.f; }
    int yb = gy0 + ysub*2;
    for (int tt = 0; tt < 4; tt++){
        int yy = yb - 1 + tt;
        bool yok = (unsigned)yy < (unsigned)GYd;
        float v[4][6];
#pragma unroll
        for (int r = 0; r < 6; r++){
            int xx = gx0 - 1 + r;
            float u0 = -__builtin_inff(), u1 = u0, u2 = u0, u3 = u0;
            if (yok && (unsigned)xx < (unsigned)GXd){
                uint2 u = *(const uint2*)(base + ((size_t)xx*GYd + yy)*256);
                u0 = bf2f((unsigned short)(u.x & 0xFFFFu));
                u1 = bf2f((unsigned short)(u.x >> 16));
                u2 = bf2f((unsigned short)(u.y & 0xFFFFu));
                u3 = bf2f((unsigned short)(u.y >> 16));
            }
            v[0][r] = u0; v[1][r] = u1; v[2][r] = u2; v[3][r] = u3;
        }
        float cm[4][4];
#pragma unroll
        for (int ch = 0; ch < 4; ch++)
#pragma unroll
            for (int g = 0; g < 4; g++)
                cm[ch][g] = fmaxf(fmaxf(v[ch][g], v[ch][g+1]), v[ch][g+2]);
        if (tt >= 2){
            int yl = ysub*2 + tt - 2;           // 0..7
#pragma unroll
            for (int g = 0; g < 4; g++){
                unsigned lo = (unsigned)f2bf(fmaxf(fmaxf(cA[0][g], cB[0][g]), cm[0][g]))
                            | ((unsigned)f2bf(fmaxf(fmaxf(cA[1][g], cB[1][g]), cm[1][g])) << 16);
                unsigned hi = (unsigned)f2bf(fmaxf(fmaxf(cA[2][g], cB[2][g]), cm[2][g]))
                            | ((unsigned)f2bf(fmaxf(fmaxf(cA[3][g], cB[3][g]), cm[3][g])) << 16);
                *(uint2*)&tile[(g*8 + yl)*256 + c4*4] = make_uint2(lo, hi);
            }
        }
#pragma unroll
        for (int ch = 0; ch < 4; ch++)
#pragma unroll
            for (int g = 0; g < 4; g++){ cA[ch][g] = cB[ch][g]; cB[ch][g] = cm[ch][g]; }
    }
    __syncthreads();

    int c = t;
#pragma unroll
    for (int g = 0; g < 4; g++){
        float* dst = out + ((size_t)b*258 + c)*GXY + (size_t)(gx0+g)*GYd + gy0;
        const unsigned short* srcl = &tile[g*8*256 + c];
#pragma unroll
        for (int y = 0; y < 8; y += 4){
            float4 o4;
            o4.x = bf2f(srcl[(y+0)*256]);
            o4.y = bf2f(srcl[(y+1)*256]);
            o4.z = bf2f(srcl[(y+2)*256]);
            o4.w = bf2f(srcl[(y+3)*256]);
            *(float4*)(dst + y) = o4;
        }
    }
}

// ---------- residual channels ----------
__global__ __launch_bounds__(256)
void k_res(const unsigned* __restrict__ pres, float* __restrict__ out){
    int idx = blockIdx.x*256 + threadIdx.x;
    const int total = NBd*2*GXY;
    if (idx >= total) return;
    int gy = idx % GYd;
    int t  = idx / GYd;
    int gx = t % GXd;  t /= GXd;
    int r  = t & 1;
    int b  = t >> 1;
    unsigned u = pres[idx];
    float f = u ? unmapf(u) : 0.f;
    out[(((size_t)b*258 + 256 + r)*GXd + gx)*GYd + gy] = f;
}

extern "C" void kernel_launch(void* const* d_in, const int* in_sizes, int n_in,
                              void* d_out, int out_size, void* d_ws, size_t ws_size,
                              hipStream_t stream){
    (void)n_in; (void)out_size; (void)ws_size;
    const float* fea   = (const float*)d_in[0];
    const int*   ind   = (const int*)  d_in[1];
    const float* bn0_g = (const float*)d_in[2];
    const float* bn0_b = (const float*)d_in[3];
    const float* w1    = (const float*)d_in[4];
    const float* b1    = (const float*)d_in[5];
    const float* bn1_g = (const float*)d_in[6];
    const float* bn1_b = (const float*)d_in[7];
    const float* w2    = (const float*)d_in[8];
    const float* b2    = (const float*)d_in[9];
    const float* bn2_g = (const float*)d_in[10];
    const float* bn2_b = (const float*)d_in[11];
    const float* w3    = (const float*)d_in[12];
    const float* b3    = (const float*)d_in[13];
    const float* bn3_g = (const float*)d_in[14];
    const float* bn3_b = (const float*)d_in[15];
    const float* w4    = (const float*)d_in[16];
    const float* b4    = (const float*)d_in[17];

    int n = in_sizes[0] / 11;
    float invN = 1.0f / (float)n;

    // ---- ws layout ----
    const size_t Z4_B     = (size_t)240000*256*2;       // 122,880,000
    const size_t POOL_B   = (size_t)NCELL*256*2;        // 176,947,200
    const size_t PRES_B   = (size_t)NBd*2*GXY*4;        //   5,529,600
    const size_t CNT_B    = (size_t)NCELL*4;            //   2,764,800
    const size_t STAT_B   = 960*4;
    const size_t GCTR_B   = 256;

    char* base = (char*)d_ws;
    unsigned short* z4     = (unsigned short*)base;
    unsigned short* pooled = (unsigned short*)(base + Z4_B);
    // z1/z2/z3 alias the pooled region (dead before k_gather writes it)
    float*          z1     = (float*)(base + Z4_B);
    float*          z2     = (float*)(base + Z4_B + 30720000);
    unsigned short* z3     = (unsigned short*)(base + Z4_B + 92160000);
    unsigned* pres  = (unsigned*)(base + Z4_B + POOL_B);
    unsigned* cnt   = (unsigned*)((char*)pres + PRES_B);
    float*    stats = (float*)((char*)cnt + CNT_B);
    unsigned* gctr  = (unsigned*)((char*)stats + STAT_B);
    unsigned* off   = (unsigned*)((char*)gctr + GCTR_B);
    unsigned* list  = (unsigned*)((char*)off + CNT_B);
    unsigned* rank  = (unsigned*)((char*)list + (size_t)240000*4);

    float* sum0 = stats;       float* sq0 = stats + 16;
    float* sum1 = stats + 32;  float* sq1 = stats + 64;
    float* sum2 = stats + 96;  float* sq2 = stats + 160;
    float* sum3 = stats + 224; float* sq3 = stats + 352;
    float* a0 = stats + 480;   float* c0 = stats + 496;
    float* a1 = stats + 512;   float* c1 = stats + 544;
    float* a2 = stats + 576;   float* c2 = stats + 640;
    float* a3 = stats + 704;   float* c3 = stats + 832;

    hipMemsetAsync(pres, 0, PRES_B + CNT_B + STAT_B + GCTR_B, stream);

    int nb = (n + 255) / 256;
    int nb64 = (n + 63) / 64;
    k_stats0<<<nb, 256, 0, stream>>>(fea, sum0, sq0, n);
    k_fin<<<1, 128, 0, stream>>>(sum0, sq0, bn0_g, bn0_b, a0, c0, 9,  invN);
    k_l1<<<nb, 256, 0, stream>>>(fea, ind, w1, b1, a0, c0, z1, pres, cnt, rank, sum1, sq1, n);
    k_fin<<<1, 128, 0, stream>>>(sum1, sq1, bn1_g, bn1_b, a1, c1, 32, invN);
    k_l2<<<nb64, 256, 0, stream>>>(z1, w2, b2, a1, c1, z2, sum2, sq2, n);
    k_fin<<<1, 128, 0, stream>>>(sum2, sq2, bn2_g, bn2_b, a2, c2, 64, invN);
    k_l3<<<nb64, 256, 0, stream>>>(z2, w3, b3, a2, c2, z3, sum3, sq3, n);
    k_fin<<<1, 128, 0, stream>>>(sum3, sq3, bn3_g, bn3_b, a3, c3, 128, invN);

    k_off <<<(NCELL + 1023)/1024, 256, 0, stream>>>(cnt, off, gctr);
    k_fill<<<nb, 256, 0, stream>>>(ind, rank, off, list, n);

    k_l4<<<nb64, 256, 0, stream>>>(z3, list, w4, b4, a3, c3, z4, n);

    k_gather<<<2048, 256, 0, stream>>>(cnt, off, z4, pooled);

    k_maxpool<<<dim3(45, 120, 2), 256, 0, stream>>>(pooled, (float*)d_out);
    k_res<<<(NBd*2*GXY + 255) / 256, 256, 0, stream>>>(pres, (float*)d_out);
}

// Round 14
// 741.688 us; speedup vs baseline: 1.0739x; 1.0619x over previous
//
#include <hip/hip_runtime.h>
#include <cstdint>
#include <cstddef>

#define GXd 480
#define GYd 360
#define NBd 2
#define GXY (480*360)
#define NCELL (NBd*GXY)
#define EPSBN 1e-5f

typedef float  f32x4  __attribute__((ext_vector_type(4)));
typedef short  bf16x8 __attribute__((ext_vector_type(8)));

// ---------- order-preserving float <-> uint map (residual atomics only) ----------
__device__ __forceinline__ unsigned mapf(float f){
    unsigned u = __float_as_uint(f);
    return (u & 0x80000000u) ? ~u : (u | 0x80000000u);
}
__device__ __forceinline__ float unmapf(unsigned m){
    return (m & 0x80000000u) ? __uint_as_float(m ^ 0x80000000u)
                             : __uint_as_float(~m);
}

// ---------- bf16 helpers (RTN-even) ----------
__device__ __forceinline__ unsigned short f2bf(float f){
    unsigned u = __float_as_uint(f);
    unsigned r = (u + 0x7FFFu + ((u >> 16) & 1u)) >> 16;
    return (unsigned short)r;
}
__device__ __forceinline__ float bf2f(unsigned short s){
    return __uint_as_float(((unsigned)s) << 16);
}

// ---------- dense layer helper ----------
template<int DIN, int DOUT>
__device__ __forceinline__ void dense(const float (&in)[DIN], float (&out)[DOUT],
                                      const float* __restrict__ w,
                                      const float* __restrict__ b){
#pragma unroll
    for (int j = 0; j < DOUT; j++) out[j] = b[j];
#pragma unroll
    for (int d = 0; d < DIN; d++){
        float v = in[d];
#pragma unroll
        for (int j = 0; j < DOUT; j++) out[j] = fmaf(v, w[d*DOUT + j], out[j]);
    }
}

// ---------- block-level sum/sumsq reduction ----------
template<int D>
__device__ __forceinline__ void reduce_stats(const float (&h)[D], bool valid,
                                             float* __restrict__ gsum,
                                             float* __restrict__ gsq){
    __shared__ float ssum[D];
    __shared__ float ssq[D];
    int tid = threadIdx.x;
    for (int t = tid; t < D; t += 256){ ssum[t] = 0.f; ssq[t] = 0.f; }
    __syncthreads();
#pragma unroll
    for (int j = 0; j < D; j++){
        float v = valid ? h[j] : 0.f;
        float s = v * v;
#pragma unroll
        for (int o = 32; o > 0; o >>= 1){
            v += __shfl_down(v, o, 64);
            s += __shfl_down(s, o, 64);
        }
        if ((tid & 63) == 0){
            atomicAdd(&ssum[j], v);
            atomicAdd(&ssq[j], s);
        }
    }
    __syncthreads();
    for (int t = tid; t < D; t += 256){
        atomicAdd(&gsum[t], ssum[t]);
        atomicAdd(&gsq[t], ssq[t]);
    }
}

// ---------- stats of raw input columns 0..8 ----------
__global__ __launch_bounds__(256)
void k_stats0(const float* __restrict__ fea, float* gsum, float* gsq, int n){
    int i = blockIdx.x*256 + threadIdx.x;
    bool valid = i < n;
    int i2 = valid ? i : 0;
    float x[9];
#pragma unroll
    for (int d = 0; d < 9; d++) x[d] = fea[(size_t)i2*11 + d];
    reduce_stats<9>(x, valid, gsum, gsq);
}

// ---------- finalize BN ----------
__global__ void k_fin(const float* __restrict__ sum, const float* __restrict__ sq,
                      const float* __restrict__ g, const float* __restrict__ bb,
                      float* __restrict__ a_out, float* __restrict__ c_out,
                      int D, float invN){
    int t = threadIdx.x;
    if (t < D){
        float mu  = sum[t] * invN;
        float var = fmaf(-mu, mu, sq[t] * invN);
        float rs  = rsqrtf(var + EPSBN);
        float a   = rs * g[t];
        a_out[t] = a;
        c_out[t] = fmaf(-mu, a, bb[t]);
    }
}

// ---------- layer1: bn0 -> 9x32; z1; stats; voxel count+rank; res atomics ----------
__global__ __launch_bounds__(256)
void k_l1(const float* __restrict__ fea, const int* __restrict__ ind,
          const float* __restrict__ w1, const float* __restrict__ b1,
          const float* __restrict__ a0, const float* __restrict__ c0,
          float* __restrict__ z1, unsigned* __restrict__ pres,
          unsigned* __restrict__ cnt, unsigned* __restrict__ rank,
          float* gsum, float* gsq, int n){
    int i = blockIdx.x*256 + threadIdx.x;
    bool valid = i < n;
    int i2 = valid ? i : 0;
    float x[9];
#pragma unroll
    for (int d = 0; d < 9; d++) x[d] = fmaf(fea[(size_t)i2*11 + d], a0[d], c0[d]);
    float h[32];
    dense<9,32>(x, h, w1, b1);
    if (valid){
        float4* dst = (float4*)(z1 + (size_t)i*32);
#pragma unroll
        for (int q = 0; q < 8; q++)
            dst[q] = make_float4(h[q*4], h[q*4+1], h[q*4+2], h[q*4+3]);
        float r0 = fea[(size_t)i*11 + 9];
        float r1 = fea[(size_t)i*11 + 10];
        int bb = ind[(size_t)i*3 + 0];
        int gx = ind[(size_t)i*3 + 1];
        int gy = ind[(size_t)i*3 + 2];
        unsigned vox = ((unsigned)bb*GXd + (unsigned)gx)*GYd + (unsigned)gy;
        rank[i] = atomicAdd(&cnt[vox], 1u);
        size_t rbase = (size_t)bb*2*GXY + (size_t)gx*GYd + gy;
        atomicMax(pres + rbase,       mapf(r0));
        atomicMax(pres + rbase + GXY, mapf(r1));
    }
    reduce_stats<32>(h, valid, gsum, gsq);
}

// ---------- layer2 via MFMA: z2[n x 64] = bn1relu(z1)[n x 32] @ w2 ----------
__global__ __launch_bounds__(256)
void k_l2(const float* __restrict__ z1,
          const float* __restrict__ w2, const float* __restrict__ b2,
          const float* __restrict__ a1, const float* __restrict__ c1,
          float* __restrict__ z2, float* gsum, float* gsq, int n){
    __shared__ short w2t[64*40];             // 5120 B
    __shared__ float ssum[64], ssq[64];
    int tid = threadIdx.x;
    if (tid < 64){ ssum[tid] = 0.f; ssq[tid] = 0.f; }
    for (int e = tid; e < 2048; e += 256){
        int k = e >> 6, c = e & 63;
        w2t[c*40 + k] = (short)f2bf(w2[k*64 + c]);
    }
    __syncthreads();

    int lane = tid & 63, wid = tid >> 6;
    int l15 = lane & 15, lg = lane >> 4;
    int p0 = blockIdx.x*64 + wid*16;
    int prow = p0 + l15;
    int prow2 = prow < n ? prow : (n - 1);
    const float* zrow = z1 + (size_t)prow2*32;

    int kbase = lg*8;
    float4 v0 = *(const float4*)(zrow + kbase);
    float4 v1 = *(const float4*)(zrow + kbase + 4);
    float4 av0 = *(const float4*)(a1 + kbase);
    float4 av1 = *(const float4*)(a1 + kbase + 4);
    float4 cv0 = *(const float4*)(c1 + kbase);
    float4 cv1 = *(const float4*)(c1 + kbase + 4);
    bf16x8 af;
    af[0] = (short)f2bf(fmaxf(fmaf(v0.x, av0.x, cv0.x), 0.f));
    af[1] = (short)f2bf(fmaxf(fmaf(v0.y, av0.y, cv0.y), 0.f));
    af[2] = (short)f2bf(fmaxf(fmaf(v0.z, av0.z, cv0.z), 0.f));
    af[3] = (short)f2bf(fmaxf(fmaf(v0.w, av0.w, cv0.w), 0.f));
    af[4] = (short)f2bf(fmaxf(fmaf(v1.x, av1.x, cv1.x), 0.f));
    af[5] = (short)f2bf(fmaxf(fmaf(v1.y, av1.y, cv1.y), 0.f));
    af[6] = (short)f2bf(fmaxf(fmaf(v1.z, av1.z, cv1.z), 0.f));
    af[7] = (short)f2bf(fmaxf(fmaf(v1.w, av1.w, cv1.w), 0.f));

    f32x4 acc[4];
#pragma unroll
    for (int t = 0; t < 4; t++){
        float bv = b2[t*16 + l15];
        acc[t] = (f32x4){bv, bv, bv, bv};
    }
#pragma unroll
    for (int t = 0; t < 4; t++){
        bf16x8 bf = *(const bf16x8*)&w2t[(t*16 + l15)*40 + kbase];
        acc[t] = __builtin_amdgcn_mfma_f32_16x16x32_bf16(af, bf, acc[t], 0, 0, 0);
    }

#pragma unroll
    for (int t = 0; t < 4; t++){
        int c = t*16 + l15;
        float s = 0.f, q = 0.f;
#pragma unroll
        for (int r = 0; r < 4; r++){
            int pr = p0 + lg*4 + r;
            float v = acc[t][r];
            if (pr < n){
                z2[(size_t)pr*64 + c] = v;
                s += v; q += v*v;
            }
        }
        s += __shfl_xor(s, 16, 64);  q += __shfl_xor(q, 16, 64);
        s += __shfl_xor(s, 32, 64);  q += __shfl_xor(q, 32, 64);
        if (lg == 0){ atomicAdd(&ssum[c], s); atomicAdd(&ssq[c], q); }
    }
    __syncthreads();
    if (tid < 64){ atomicAdd(gsum + tid, ssum[tid]); atomicAdd(gsq + tid, ssq[tid]); }
}

// ---------- layer3 via MFMA: z3[n x 128] = bn2relu(z2)[n x 64] @ w3 (bf16 out) ----------
__global__ __launch_bounds__(256)
void k_l3(const float* __restrict__ z2,
          const float* __restrict__ w3, const float* __restrict__ b3,
          const float* __restrict__ a2, const float* __restrict__ c2,
          unsigned short* __restrict__ z3, float* gsum, float* gsq, int n){
    __shared__ short w3t[128*72];            // 18432 B, [c][k] stride 72
    __shared__ float ssum[128], ssq[128];
    int tid = threadIdx.x;
    if (tid < 128){ ssum[tid] = 0.f; ssq[tid] = 0.f; }
    for (int e = tid; e < 8192; e += 256){
        int k = e >> 7, c = e & 127;
        w3t[c*72 + k] = (short)f2bf(w3[k*128 + c]);
    }
    __syncthreads();

    int lane = tid & 63, wid = tid >> 6;
    int l15 = lane & 15, lg = lane >> 4;
    int p0 = blockIdx.x*64 + wid*16;
    int prow = p0 + l15;
    int prow2 = prow < n ? prow : (n - 1);
    const float* zrow = z2 + (size_t)prow2*64;

    f32x4 acc[8];
#pragma unroll
    for (int t = 0; t < 8; t++){
        float bv = b3[t*16 + l15];
        acc[t] = (f32x4){bv, bv, bv, bv};
    }

#pragma unroll
    for (int ks = 0; ks < 2; ks++){
        int kbase = ks*32 + lg*8;
        float4 v0 = *(const float4*)(zrow + kbase);
        float4 v1 = *(const float4*)(zrow + kbase + 4);
        float4 av0 = *(const float4*)(a2 + kbase);
        float4 av1 = *(const float4*)(a2 + kbase + 4);
        float4 cv0 = *(const float4*)(c2 + kbase);
        float4 cv1 = *(const float4*)(c2 + kbase + 4);
        bf16x8 af;
        af[0] = (short)f2bf(fmaxf(fmaf(v0.x, av0.x, cv0.x), 0.f));
        af[1] = (short)f2bf(fmaxf(fmaf(v0.y, av0.y, cv0.y), 0.f));
        af[2] = (short)f2bf(fmaxf(fmaf(v0.z, av0.z, cv0.z), 0.f));
        af[3] = (short)f2bf(fmaxf(fmaf(v0.w, av0.w, cv0.w), 0.f));
        af[4] = (short)f2bf(fmaxf(fmaf(v1.x, av1.x, cv1.x), 0.f));
        af[5] = (short)f2bf(fmaxf(fmaf(v1.y, av1.y, cv1.y), 0.f));
        af[6] = (short)f2bf(fmaxf(fmaf(v1.z, av1.z, cv1.z), 0.f));
        af[7] = (short)f2bf(fmaxf(fmaf(v1.w, av1.w, cv1.w), 0.f));
#pragma unroll
        for (int t = 0; t < 8; t++){
            bf16x8 bf = *(const bf16x8*)&w3t[(t*16 + l15)*72 + kbase];
            acc[t] = __builtin_amdgcn_mfma_f32_16x16x32_bf16(af, bf, acc[t], 0, 0, 0);
        }
    }

#pragma unroll
    for (int t = 0; t < 8; t++){
        int c = t*16 + l15;
        float s = 0.f, q = 0.f;
#pragma unroll
        for (int r = 0; r < 4; r++){
            int pr = p0 + lg*4 + r;
            unsigned short rb = f2bf(acc[t][r]);
            float rv = bf2f(rb);
            if (pr < n){
                z3[(size_t)pr*128 + c] = rb;
                s += rv; q += rv*rv;
            }
        }
        s += __shfl_xor(s, 16, 64);  q += __shfl_xor(q, 16, 64);
        s += __shfl_xor(s, 32, 64);  q += __shfl_xor(q, 32, 64);
        if (lg == 0){ atomicAdd(&ssum[c], s); atomicAdd(&ssq[c], q); }
    }
    __syncthreads();
    if (tid < 128){ atomicAdd(gsum + tid, ssum[tid]); atomicAdd(gsq + tid, ssq[tid]); }
}

// ---------- exclusive scan of cnt via block tickets ----------
__global__ __launch_bounds__(256)
void k_off(const unsigned* __restrict__ cnt, unsigned* __restrict__ off,
           unsigned* __restrict__ gctr){
    __shared__ unsigned wtot[4];
    __shared__ unsigned wbase[4];
    int t = threadIdx.x;
    int lane = t & 63, w = t >> 6;
    int base = blockIdx.x * 1024 + t * 4;
    bool ok = base < NCELL;
    unsigned c0 = 0, c1 = 0, c2 = 0, c3 = 0;
    if (ok){ c0 = cnt[base]; c1 = cnt[base+1]; c2 = cnt[base+2]; c3 = cnt[base+3]; }
    unsigned tot = c0 + c1 + c2 + c3;
    unsigned incl = tot;
#pragma unroll
    for (int o = 1; o < 64; o <<= 1){
        unsigned v = __shfl_up(incl, o, 64);
        if (lane >= o) incl += v;
    }
    if (lane == 63) wtot[w] = incl;
    __syncthreads();
    if (t == 0){
        unsigned bt = wtot[0] + wtot[1] + wtot[2] + wtot[3];
        unsigned gb = atomicAdd(gctr, bt);
        unsigned s = 0;
#pragma unroll
        for (int q = 0; q < 4; q++){ wbase[q] = gb + s; s += wtot[q]; }
    }
    __syncthreads();
    if (ok){
        unsigned tb = wbase[w] + incl - tot;
        off[base]   = tb;
        off[base+1] = tb + c0;
        off[base+2] = tb + c0 + c1;
        off[base+3] = tb + c0 + c1 + c2;
    }
}

// ---------- fill per-cell point lists ----------
__global__ __launch_bounds__(256)
void k_fill(const int* __restrict__ ind, const unsigned* __restrict__ rank,
            const unsigned* __restrict__ off, unsigned* __restrict__ list, int n){
    int i = blockIdx.x*256 + threadIdx.x;
    if (i >= n) return;
    int bb = ind[(size_t)i*3], gx = ind[(size_t)i*3+1], gy = ind[(size_t)i*3+2];
    unsigned vox = ((unsigned)bb*GXd + (unsigned)gx)*GYd + (unsigned)gy;
    list[off[vox] + rank[i]] = (unsigned)i;
}

// ---------- layer4 via MFMA, SORTED output: z4[sorted_pos] = bn3relu(z3[list[pos]]) @ w4 ----------
__global__ __launch_bounds__(256)
void k_l4(const unsigned short* __restrict__ z3, const unsigned* __restrict__ list,
          const float* __restrict__ w4, const float* __restrict__ b4,
          const float* __restrict__ a3, const float* __restrict__ c3,
          unsigned short* __restrict__ z4, int n){
    __shared__ short w4t[256*128];           // 64 KB: bf16 w4^T [c][k], swizzled
    int tid = threadIdx.x;
    for (int e = tid; e < 16384; e += 256){
        int k2 = e >> 8;
        int c  = e & 255;
        unsigned lo = f2bf(w4[(size_t)(2*k2)*256 + c]);
        unsigned hi = f2bf(w4[(size_t)(2*k2+1)*256 + c]);
        int addr = (c*256 + k2*4) ^ ((c & 7) << 4);
        *(unsigned*)((char*)w4t + addr) = lo | (hi << 16);
    }
    __syncthreads();

    int lane = tid & 63, wid = tid >> 6;
    int l15 = lane & 15, lg = lane >> 4;
    int p0 = blockIdx.x*64 + wid*16;
    int prow = p0 + l15;
    int prow2 = prow < n ? prow : (n - 1);
    int srow = (int)list[prow2];             // original point id (sorted by cell)
    const unsigned short* zrow = z3 + (size_t)srow*128;

    f32x4 acc[16];
#pragma unroll
    for (int t = 0; t < 16; t++){
        float bv = b4[t*16 + l15];
        acc[t] = (f32x4){bv, bv, bv, bv};
    }

#pragma unroll
    for (int ks = 0; ks < 4; ks++){
        int kbase = ks*32 + lg*8;
        uint4 ua = *(const uint4*)(zrow + kbase);
        float4 av0 = *(const float4*)(a3 + kbase);
        float4 av1 = *(const float4*)(a3 + kbase + 4);
        float4 cv0 = *(const float4*)(c3 + kbase);
        float4 cv1 = *(const float4*)(c3 + kbase + 4);
        bf16x8 af;
        af[0] = (short)f2bf(fmaxf(fmaf(bf2f((unsigned short)(ua.x & 0xFFFFu)), av0.x, cv0.x), 0.f));
        af[1] = (short)f2bf(fmaxf(fmaf(bf2f((unsigned short)(ua.x >> 16)),     av0.y, cv0.y), 0.f));
        af[2] = (short)f2bf(fmaxf(fmaf(bf2f((unsigned short)(ua.y & 0xFFFFu)), av0.z, cv0.z), 0.f));
        af[3] = (short)f2bf(fmaxf(fmaf(bf2f((unsigned short)(ua.y >> 16)),     av0.w, cv0.w), 0.f));
        af[4] = (short)f2bf(fmaxf(fmaf(bf2f((unsigned short)(ua.z & 0xFFFFu)), av1.x, cv1.x), 0.f));
        af[5] = (short)f2bf(fmaxf(fmaf(bf2f((unsigned short)(ua.z >> 16)),     av1.y, cv1.y), 0.f));
        af[6] = (short)f2bf(fmaxf(fmaf(bf2f((unsigned short)(ua.w & 0xFFFFu)), av1.z, cv1.z), 0.f));
        af[7] = (short)f2bf(fmaxf(fmaf(bf2f((unsigned short)(ua.w >> 16)),     av1.w, cv1.w), 0.f));
#pragma unroll
        for (int t = 0; t < 16; t++){
            int c = t*16 + l15;
            int addr = (c*256 + kbase*2) ^ ((c & 7) << 4);
            bf16x8 bf = *(const bf16x8*)((const char*)w4t + addr);
            acc[t] = __builtin_amdgcn_mfma_f32_16x16x32_bf16(af, bf, acc[t], 0, 0, 0);
        }
    }

#pragma unroll
    for (int t = 0; t < 16; t++){
#pragma unroll
        for (int r = 0; r < 4; r++){
            int pr = p0 + lg*4 + r;
            if (pr < n)
                z4[(size_t)pr*256 + t*16 + l15] = f2bf(acc[t][r]);
        }
    }
}

// ---------- gather-max: streaming — cell's rows are contiguous in sorted z4 ----------
__global__ __launch_bounds__(256)
void k_gather(const unsigned* __restrict__ cnt, const unsigned* __restrict__ off,
              const unsigned short* __restrict__ z4,
              unsigned short* __restrict__ pooled){
    int lane = threadIdx.x & 63;
    int wid  = blockIdx.x*4 + (threadIdx.x >> 6);
    int wstride = gridDim.x * 4;
    for (int cell = wid; cell < NCELL; cell += wstride){
        unsigned cn = cnt[cell];
        unsigned o  = off[cell];
        float m0 = -__builtin_inff(), m1 = m0, m2 = m0, m3 = m0;
        for (unsigned p = 0; p < cn; p++){
            uint2 u = *(const uint2*)(z4 + (size_t)(o + p)*256 + lane*4);
            m0 = fmaxf(m0, __uint_as_float(u.x << 16));
            m1 = fmaxf(m1, __uint_as_float(u.x & 0xFFFF0000u));
            m2 = fmaxf(m2, __uint_as_float(u.y << 16));
            m3 = fmaxf(m3, __uint_as_float(u.y & 0xFFFF0000u));
        }
        if (cn == 0){ m0 = m1 = m2 = m3 = 0.f; }
        unsigned p0 = (__float_as_uint(m0) >> 16) | (__float_as_uint(m1) & 0xFFFF0000u);
        unsigned p1 = (__float_as_uint(m2) >> 16) | (__float_as_uint(m3) & 0xFFFF0000u);
        *(uint2*)(pooled + (size_t)cell*256 + lane*4) = make_uint2(p0, p1);
    }
}

// ---------- 3x3 maxpool: 4gx x 16gy tile (32 KB) — full 64B-line planar writes,
// 4ch/thread uint2 loads, 4 waves x 4 output rows (6-step rolling chains) ----------
__global__ __launch_bounds__(256)
void k_maxpool(const unsigned short* __restrict__ pooled, float* __restrict__ out){
    __shared__ unsigned short tile[4*16*256];   // [g][yl][c] bf16 = 32 KB
    int t = threadIdx.x;
    int c4   = t & 63;                          // channels 4*c4 .. 4*c4+3
    int ysub = t >> 6;                          // wave id: output rows [ysub*4, ysub*4+4)
    int gy0 = blockIdx.x * 16;
    int gx0 = blockIdx.y * 4;
    int b   = blockIdx.z;
    int ymax = GYd - gy0; if (ymax > 16) ymax = 16;   // 16 or 8
    const unsigned short* base = pooled + (size_t)b*GXY*256 + c4*4;

    float cA[4][4], cB[4][4];                   // [ch][g] rolling window
#pragma unroll
    for (int ch = 0; ch < 4; ch++)
#pragma unroll
        for (int g = 0; g < 4; g++){ cA[ch][g] = 0.f; cB[ch][g] = 0.f; }
    int yb = gy0 + ysub*4;
    for (int tt = 0; tt < 6; tt++){
        int yy = yb - 1 + tt;
        bool yok = (unsigned)yy < (unsigned)GYd;
        float v[4][6];
#pragma unroll
        for (int r = 0; r < 6; r++){
            int xx = gx0 - 1 + r;
            float u0 = -__builtin_inff(), u1 = u0, u2 = u0, u3 = u0;
            if (yok && (unsigned)xx < (unsigned)GXd){
                uint2 u = *(const uint2*)(base + ((size_t)xx*GYd + yy)*256);
                u0 = bf2f((unsigned short)(u.x & 0xFFFFu));
                u1 = bf2f((unsigned short)(u.x >> 16));
                u2 = bf2f((unsigned short)(u.y & 0xFFFFu));
                u3 = bf2f((unsigned short)(u.y >> 16));
            }
            v[0][r] = u0; v[1][r] = u1; v[2][r] = u2; v[3][r] = u3;
        }
        float cm[4][4];
#pragma unroll
        for (int ch = 0; ch < 4; ch++)
#pragma unroll
            for (int g = 0; g < 4; g++)
                cm[ch][g] = fmaxf(fmaxf(v[ch][g], v[ch][g+1]), v[ch][g+2]);
        if (tt >= 2){
            int yl = ysub*4 + tt - 2;           // 0..15
            if (yl < ymax){
#pragma unroll
                for (int g = 0; g < 4; g++){
                    unsigned lo = (unsigned)f2bf(fmaxf(fmaxf(cA[0][g], cB[0][g]), cm[0][g]))
                                | ((unsigned)f2bf(fmaxf(fmaxf(cA[1][g], cB[1][g]), cm[1][g])) << 16);
                    unsigned hi = (unsigned)f2bf(fmaxf(fmaxf(cA[2][g], cB[2][g]), cm[2][g]))
                                | ((unsigned)f2bf(fmaxf(fmaxf(cA[3][g], cB[3][g]), cm[3][g])) << 16);
                    *(uint2*)&tile[(g*16 + yl)*256 + c4*4] = make_uint2(lo, hi);
                }
            }
        }
#pragma unroll
        for (int ch = 0; ch < 4; ch++)
#pragma unroll
            for (int g = 0; g < 4; g++){ cA[ch][g] = cB[ch][g]; cB[ch][g] = cm[ch][g]; }
    }
    __syncthreads();

    int c = t;
#pragma unroll 1
    for (int g = 0; g < 4; g++){
        float* dst = out + ((size_t)b*258 + c)*GXY + (size_t)(gx0+g)*GYd + gy0;
        const unsigned short* srcl = &tile[g*16*256 + c];
#pragma unroll 1
        for (int y = 0; y < ymax; y += 4){
            float4 o4;
            o4.x = bf2f(srcl[(y+0)*256]);
            o4.y = bf2f(srcl[(y+1)*256]);
            o4.z = bf2f(srcl[(y+2)*256]);
            o4.w = bf2f(srcl[(y+3)*256]);
            *(float4*)(dst + y) = o4;
        }
    }
}

// ---------- residual channels ----------
__global__ __launch_bounds__(256)
void k_res(const unsigned* __restrict__ pres, float* __restrict__ out){
    int idx = blockIdx.x*256 + threadIdx.x;
    const int total = NBd*2*GXY;
    if (idx >= total) return;
    int gy = idx % GYd;
    int t  = idx / GYd;
    int gx = t % GXd;  t /= GXd;
    int r  = t & 1;
    int b  = t >> 1;
    unsigned u = pres[idx];
    float f = u ? unmapf(u) : 0.f;
    out[(((size_t)b*258 + 256 + r)*GXd + gx)*GYd + gy] = f;
}

extern "C" void kernel_launch(void* const* d_in, const int* in_sizes, int n_in,
                              void* d_out, int out_size, void* d_ws, size_t ws_size,
                              hipStream_t stream){
    (void)n_in; (void)out_size; (void)ws_size;
    const float* fea   = (const float*)d_in[0];
    const int*   ind   = (const int*)  d_in[1];
    const float* bn0_g = (const float*)d_in[2];
    const float* bn0_b = (const float*)d_in[3];
    const float* w1    = (const float*)d_in[4];
    const float* b1    = (const float*)d_in[5];
    const float* bn1_g = (const float*)d_in[6];
    const float* bn1_b = (const float*)d_in[7];
    const float* w2    = (const float*)d_in[8];
    const float* b2    = (const float*)d_in[9];
    const float* bn2_g = (const float*)d_in[10];
    const float* bn2_b = (const float*)d_in[11];
    const float* w3    = (const float*)d_in[12];
    const float* b3    = (const float*)d_in[13];
    const float* bn3_g = (const float*)d_in[14];
    const float* bn3_b = (const float*)d_in[15];
    const float* w4    = (const float*)d_in[16];
    const float* b4    = (const float*)d_in[17];

    int n = in_sizes[0] / 11;
    float invN = 1.0f / (float)n;

    // ---- ws layout ----
    const size_t Z4_B     = (size_t)240000*256*2;       // 122,880,000
    const size_t POOL_B   = (size_t)NCELL*256*2;        // 176,947,200
    const size_t PRES_B   = (size_t)NBd*2*GXY*4;        //   5,529,600
    const size_t CNT_B    = (size_t)NCELL*4;            //   2,764,800
    const size_t STAT_B   = 960*4;
    const size_t GCTR_B   = 256;

    char* base = (char*)d_ws;
    unsigned short* z4     = (unsigned short*)base;
    unsigned short* pooled = (unsigned short*)(base + Z4_B);
    // z1/z2/z3 alias the pooled region (dead before k_gather writes it)
    float*          z1     = (float*)(base + Z4_B);
    float*          z2     = (float*)(base + Z4_B + 30720000);
    unsigned short* z3     = (unsigned short*)(base + Z4_B + 92160000);
    unsigned* pres  = (unsigned*)(base + Z4_B + POOL_B);
    unsigned* cnt   = (unsigned*)((char*)pres + PRES_B);
    float*    stats = (float*)((char*)cnt + CNT_B);
    unsigned* gctr  = (unsigned*)((char*)stats + STAT_B);
    unsigned* off   = (unsigned*)((char*)gctr + GCTR_B);
    unsigned* list  = (unsigned*)((char*)off + CNT_B);
    unsigned* rank  = (unsigned*)((char*)list + (size_t)240000*4);

    float* sum0 = stats;       float* sq0 = stats + 16;
    float* sum1 = stats + 32;  float* sq1 = stats + 64;
    float* sum2 = stats + 96;  float* sq2 = stats + 160;
    float* sum3 = stats + 224; float* sq3 = stats + 352;
    float* a0 = stats + 480;   float* c0 = stats + 496;
    float* a1 = stats + 512;   float* c1 = stats + 544;
    float* a2 = stats + 576;   float* c2 = stats + 640;
    float* a3 = stats + 704;   float* c3 = stats + 832;

    hipMemsetAsync(pres, 0, PRES_B + CNT_B + STAT_B + GCTR_B, stream);

    int nb = (n + 255) / 256;
    int nb64 = (n + 63) / 64;
    k_stats0<<<nb, 256, 0, stream>>>(fea, sum0, sq0, n);
    k_fin<<<1, 128, 0, stream>>>(sum0, sq0, bn0_g, bn0_b, a0, c0, 9,  invN);
    k_l1<<<nb, 256, 0, stream>>>(fea, ind, w1, b1, a0, c0, z1, pres, cnt, rank, sum1, sq1, n);
    k_fin<<<1, 128, 0, stream>>>(sum1, sq1, bn1_g, bn1_b, a1, c1, 32, invN);
    k_l2<<<nb64, 256, 0, stream>>>(z1, w2, b2, a1, c1, z2, sum2, sq2, n);
    k_fin<<<1, 128, 0, stream>>>(sum2, sq2, bn2_g, bn2_b, a2, c2, 64, invN);
    k_l3<<<nb64, 256, 0, stream>>>(z2, w3, b3, a2, c2, z3, sum3, sq3, n);
    k_fin<<<1, 128, 0, stream>>>(sum3, sq3, bn3_g, bn3_b, a3, c3, 128, invN);

    k_off <<<(NCELL + 1023)/1024, 256, 0, stream>>>(cnt, off, gctr);
    k_fill<<<nb, 256, 0, stream>>>(ind, rank, off, list, n);

    k_l4<<<nb64, 256, 0, stream>>>(z3, list, w4, b4, a3, c3, z4, n);

    k_gather<<<2048, 256, 0, stream>>>(cnt, off, z4, pooled);

    k_maxpool<<<dim3(23, 120, 2), 256, 0, stream>>>(pooled, (float*)d_out);
    k_res<<<(NBd*2*GXY + 255) / 256, 256, 0, stream>>>(pres, (float*)d_out);
}

// Round 15
// 734.720 us; speedup vs baseline: 1.0841x; 1.0095x over previous
//
#include <hip/hip_runtime.h>
#include <cstdint>
#include <cstddef>

#define GXd 480
#define GYd 360
#define NBd 2
#define GXY (480*360)
#define NCELL (NBd*GXY)
#define EPSBN 1e-5f

typedef float  f32x4  __attribute__((ext_vector_type(4)));
typedef short  bf16x8 __attribute__((ext_vector_type(8)));

// ---------- order-preserving float <-> uint map (residual atomics only) ----------
__device__ __forceinline__ unsigned mapf(float f){
    unsigned u = __float_as_uint(f);
    return (u & 0x80000000u) ? ~u : (u | 0x80000000u);
}
__device__ __forceinline__ float unmapf(unsigned m){
    return (m & 0x80000000u) ? __uint_as_float(m ^ 0x80000000u)
                             : __uint_as_float(~m);
}

// ---------- bf16 helpers (RTN-even) ----------
__device__ __forceinline__ unsigned short f2bf(float f){
    unsigned u = __float_as_uint(f);
    unsigned r = (u + 0x7FFFu + ((u >> 16) & 1u)) >> 16;
    return (unsigned short)r;
}
__device__ __forceinline__ float bf2f(unsigned short s){
    return __uint_as_float(((unsigned)s) << 16);
}

// ---------- dense layer helper ----------
template<int DIN, int DOUT>
__device__ __forceinline__ void dense(const float (&in)[DIN], float (&out)[DOUT],
                                      const float* __restrict__ w,
                                      const float* __restrict__ b){
#pragma unroll
    for (int j = 0; j < DOUT; j++) out[j] = b[j];
#pragma unroll
    for (int d = 0; d < DIN; d++){
        float v = in[d];
#pragma unroll
        for (int j = 0; j < DOUT; j++) out[j] = fmaf(v, w[d*DOUT + j], out[j]);
    }
}

// ---------- block-level sum/sumsq reduction ----------
template<int D>
__device__ __forceinline__ void reduce_stats(const float (&h)[D], bool valid,
                                             float* __restrict__ gsum,
                                             float* __restrict__ gsq){
    __shared__ float ssum[D];
    __shared__ float ssq[D];
    int tid = threadIdx.x;
    for (int t = tid; t < D; t += 256){ ssum[t] = 0.f; ssq[t] = 0.f; }
    __syncthreads();
#pragma unroll
    for (int j = 0; j < D; j++){
        float v = valid ? h[j] : 0.f;
        float s = v * v;
#pragma unroll
        for (int o = 32; o > 0; o >>= 1){
            v += __shfl_down(v, o, 64);
            s += __shfl_down(s, o, 64);
        }
        if ((tid & 63) == 0){
            atomicAdd(&ssum[j], v);
            atomicAdd(&ssq[j], s);
        }
    }
    __syncthreads();
    for (int t = tid; t < D; t += 256){
        atomicAdd(&gsum[t], ssum[t]);
        atomicAdd(&gsq[t], ssq[t]);
    }
}

// ---------- stats of raw input columns 0..8 ----------
__global__ __launch_bounds__(256)
void k_stats0(const float* __restrict__ fea, float* gsum, float* gsq, int n){
    int i = blockIdx.x*256 + threadIdx.x;
    bool valid = i < n;
    int i2 = valid ? i : 0;
    float x[9];
#pragma unroll
    for (int d = 0; d < 9; d++) x[d] = fea[(size_t)i2*11 + d];
    reduce_stats<9>(x, valid, gsum, gsq);
}

// ---------- finalize BN ----------
__global__ void k_fin(const float* __restrict__ sum, const float* __restrict__ sq,
                      const float* __restrict__ g, const float* __restrict__ bb,
                      float* __restrict__ a_out, float* __restrict__ c_out,
                      int D, float invN){
    int t = threadIdx.x;
    if (t < D){
        float mu  = sum[t] * invN;
        float var = fmaf(-mu, mu, sq[t] * invN);
        float rs  = rsqrtf(var + EPSBN);
        float a   = rs * g[t];
        a_out[t] = a;
        c_out[t] = fmaf(-mu, a, bb[t]);
    }
}

// ---------- layer1: bn0 -> 9x32; z1; stats; voxel count+rank; res atomics ----------
__global__ __launch_bounds__(256)
void k_l1(const float* __restrict__ fea, const int* __restrict__ ind,
          const float* __restrict__ w1, const float* __restrict__ b1,
          const float* __restrict__ a0, const float* __restrict__ c0,
          float* __restrict__ z1, unsigned* __restrict__ pres,
          unsigned* __restrict__ cnt, unsigned* __restrict__ rank,
          float* gsum, float* gsq, int n){
    int i = blockIdx.x*256 + threadIdx.x;
    bool valid = i < n;
    int i2 = valid ? i : 0;
    float x[9];
#pragma unroll
    for (int d = 0; d < 9; d++) x[d] = fmaf(fea[(size_t)i2*11 + d], a0[d], c0[d]);
    float h[32];
    dense<9,32>(x, h, w1, b1);
    if (valid){
        float4* dst = (float4*)(z1 + (size_t)i*32);
#pragma unroll
        for (int q = 0; q < 8; q++)
            dst[q] = make_float4(h[q*4], h[q*4+1], h[q*4+2], h[q*4+3]);
        float r0 = fea[(size_t)i*11 + 9];
        float r1 = fea[(size_t)i*11 + 10];
        int bb = ind[(size_t)i*3 + 0];
        int gx = ind[(size_t)i*3 + 1];
        int gy = ind[(size_t)i*3 + 2];
        unsigned vox = ((unsigned)bb*GXd + (unsigned)gx)*GYd + (unsigned)gy;
        rank[i] = atomicAdd(&cnt[vox], 1u);
        size_t rbase = (size_t)bb*2*GXY + (size_t)gx*GYd + gy;
        atomicMax(pres + rbase,       mapf(r0));
        atomicMax(pres + rbase + GXY, mapf(r1));
    }
    reduce_stats<32>(h, valid, gsum, gsq);
}

// ---------- layer2 via MFMA: z2[n x 64] = bn1relu(z1)[n x 32] @ w2 ----------
__global__ __launch_bounds__(256)
void k_l2(const float* __restrict__ z1,
          const float* __restrict__ w2, const float* __restrict__ b2,
          const float* __restrict__ a1, const float* __restrict__ c1,
          float* __restrict__ z2, float* gsum, float* gsq, int n){
    __shared__ short w2t[64*40];             // 5120 B
    __shared__ float ssum[64], ssq[64];
    int tid = threadIdx.x;
    if (tid < 64){ ssum[tid] = 0.f; ssq[tid] = 0.f; }
    for (int e = tid; e < 2048; e += 256){
        int k = e >> 6, c = e & 63;
        w2t[c*40 + k] = (short)f2bf(w2[k*64 + c]);
    }
    __syncthreads();

    int lane = tid & 63, wid = tid >> 6;
    int l15 = lane & 15, lg = lane >> 4;
    int p0 = blockIdx.x*64 + wid*16;
    int prow = p0 + l15;
    int prow2 = prow < n ? prow : (n - 1);
    const float* zrow = z1 + (size_t)prow2*32;

    int kbase = lg*8;
    float4 v0 = *(const float4*)(zrow + kbase);
    float4 v1 = *(const float4*)(zrow + kbase + 4);
    float4 av0 = *(const float4*)(a1 + kbase);
    float4 av1 = *(const float4*)(a1 + kbase + 4);
    float4 cv0 = *(const float4*)(c1 + kbase);
    float4 cv1 = *(const float4*)(c1 + kbase + 4);
    bf16x8 af;
    af[0] = (short)f2bf(fmaxf(fmaf(v0.x, av0.x, cv0.x), 0.f));
    af[1] = (short)f2bf(fmaxf(fmaf(v0.y, av0.y, cv0.y), 0.f));
    af[2] = (short)f2bf(fmaxf(fmaf(v0.z, av0.z, cv0.z), 0.f));
    af[3] = (short)f2bf(fmaxf(fmaf(v0.w, av0.w, cv0.w), 0.f));
    af[4] = (short)f2bf(fmaxf(fmaf(v1.x, av1.x, cv1.x), 0.f));
    af[5] = (short)f2bf(fmaxf(fmaf(v1.y, av1.y, cv1.y), 0.f));
    af[6] = (short)f2bf(fmaxf(fmaf(v1.z, av1.z, cv1.z), 0.f));
    af[7] = (short)f2bf(fmaxf(fmaf(v1.w, av1.w, cv1.w), 0.f));

    f32x4 acc[4];
#pragma unroll
    for (int t = 0; t < 4; t++){
        float bv = b2[t*16 + l15];
        acc[t] = (f32x4){bv, bv, bv, bv};
    }
#pragma unroll
    for (int t = 0; t < 4; t++){
        bf16x8 bf = *(const bf16x8*)&w2t[(t*16 + l15)*40 + kbase];
        acc[t] = __builtin_amdgcn_mfma_f32_16x16x32_bf16(af, bf, acc[t], 0, 0, 0);
    }

#pragma unroll
    for (int t = 0; t < 4; t++){
        int c = t*16 + l15;
        float s = 0.f, q = 0.f;
#pragma unroll
        for (int r = 0; r < 4; r++){
            int pr = p0 + lg*4 + r;
            float v = acc[t][r];
            if (pr < n){
                z2[(size_t)pr*64 + c] = v;
                s += v; q += v*v;
            }
        }
        s += __shfl_xor(s, 16, 64);  q += __shfl_xor(q, 16, 64);
        s += __shfl_xor(s, 32, 64);  q += __shfl_xor(q, 32, 64);
        if (lg == 0){ atomicAdd(&ssum[c], s); atomicAdd(&ssq[c], q); }
    }
    __syncthreads();
    if (tid < 64){ atomicAdd(gsum + tid, ssum[tid]); atomicAdd(gsq + tid, ssq[tid]); }
}

// ---------- layer3 via MFMA: z3[n x 128] = bn2relu(z2)[n x 64] @ w3 (bf16 out) ----------
__global__ __launch_bounds__(256)
void k_l3(const float* __restrict__ z2,
          const float* __restrict__ w3, const float* __restrict__ b3,
          const float* __restrict__ a2, const float* __restrict__ c2,
          unsigned short* __restrict__ z3, float* gsum, float* gsq, int n){
    __shared__ short w3t[128*72];            // 18432 B, [c][k] stride 72
    __shared__ float ssum[128], ssq[128];
    int tid = threadIdx.x;
    if (tid < 128){ ssum[tid] = 0.f; ssq[tid] = 0.f; }
    for (int e = tid; e < 8192; e += 256){
        int k = e >> 7, c = e & 127;
        w3t[c*72 + k] = (short)f2bf(w3[k*128 + c]);
    }
    __syncthreads();

    int lane = tid & 63, wid = tid >> 6;
    int l15 = lane & 15, lg = lane >> 4;
    int p0 = blockIdx.x*64 + wid*16;
    int prow = p0 + l15;
    int prow2 = prow < n ? prow : (n - 1);
    const float* zrow = z2 + (size_t)prow2*64;

    f32x4 acc[8];
#pragma unroll
    for (int t = 0; t < 8; t++){
        float bv = b3[t*16 + l15];
        acc[t] = (f32x4){bv, bv, bv, bv};
    }

#pragma unroll
    for (int ks = 0; ks < 2; ks++){
        int kbase = ks*32 + lg*8;
        float4 v0 = *(const float4*)(zrow + kbase);
        float4 v1 = *(const float4*)(zrow + kbase + 4);
        float4 av0 = *(const float4*)(a2 + kbase);
        float4 av1 = *(const float4*)(a2 + kbase + 4);
        float4 cv0 = *(const float4*)(c2 + kbase);
        float4 cv1 = *(const float4*)(c2 + kbase + 4);
        bf16x8 af;
        af[0] = (short)f2bf(fmaxf(fmaf(v0.x, av0.x, cv0.x), 0.f));
        af[1] = (short)f2bf(fmaxf(fmaf(v0.y, av0.y, cv0.y), 0.f));
        af[2] = (short)f2bf(fmaxf(fmaf(v0.z, av0.z, cv0.z), 0.f));
        af[3] = (short)f2bf(fmaxf(fmaf(v0.w, av0.w, cv0.w), 0.f));
        af[4] = (short)f2bf(fmaxf(fmaf(v1.x, av1.x, cv1.x), 0.f));
        af[5] = (short)f2bf(fmaxf(fmaf(v1.y, av1.y, cv1.y), 0.f));
        af[6] = (short)f2bf(fmaxf(fmaf(v1.z, av1.z, cv1.z), 0.f));
        af[7] = (short)f2bf(fmaxf(fmaf(v1.w, av1.w, cv1.w), 0.f));
#pragma unroll
        for (int t = 0; t < 8; t++){
            bf16x8 bf = *(const bf16x8*)&w3t[(t*16 + l15)*72 + kbase];
            acc[t] = __builtin_amdgcn_mfma_f32_16x16x32_bf16(af, bf, acc[t], 0, 0, 0);
        }
    }

#pragma unroll
    for (int t = 0; t < 8; t++){
        int c = t*16 + l15;
        float s = 0.f, q = 0.f;
#pragma unroll
        for (int r = 0; r < 4; r++){
            int pr = p0 + lg*4 + r;
            unsigned short rb = f2bf(acc[t][r]);
            float rv = bf2f(rb);
            if (pr < n){
                z3[(size_t)pr*128 + c] = rb;
                s += rv; q += rv*rv;
            }
        }
        s += __shfl_xor(s, 16, 64);  q += __shfl_xor(q, 16, 64);
        s += __shfl_xor(s, 32, 64);  q += __shfl_xor(q, 32, 64);
        if (lg == 0){ atomicAdd(&ssum[c], s); atomicAdd(&ssq[c], q); }
    }
    __syncthreads();
    if (tid < 128){ atomicAdd(gsum + tid, ssum[tid]); atomicAdd(gsq + tid, ssq[tid]); }
}

// ---------- exclusive scan of cnt via block tickets ----------
__global__ __launch_bounds__(256)
void k_off(const unsigned* __restrict__ cnt, unsigned* __restrict__ off,
           unsigned* __restrict__ gctr){
    __shared__ unsigned wtot[4];
    __shared__ unsigned wbase[4];
    int t = threadIdx.x;
    int lane = t & 63, w = t >> 6;
    int base = blockIdx.x * 1024 + t * 4;
    bool ok = base < NCELL;
    unsigned c0 = 0, c1 = 0, c2 = 0, c3 = 0;
    if (ok){ c0 = cnt[base]; c1 = cnt[base+1]; c2 = cnt[base+2]; c3 = cnt[base+3]; }
    unsigned tot = c0 + c1 + c2 + c3;
    unsigned incl = tot;
#pragma unroll
    for (int o = 1; o < 64; o <<= 1){
        unsigned v = __shfl_up(incl, o, 64);
        if (lane >= o) incl += v;
    }
    if (lane == 63) wtot[w] = incl;
    __syncthreads();
    if (t == 0){
        unsigned bt = wtot[0] + wtot[1] + wtot[2] + wtot[3];
        unsigned gb = atomicAdd(gctr, bt);
        unsigned s = 0;
#pragma unroll
        for (int q = 0; q < 4; q++){ wbase[q] = gb + s; s += wtot[q]; }
    }
    __syncthreads();
    if (ok){
        unsigned tb = wbase[w] + incl - tot;
        off[base]   = tb;
        off[base+1] = tb + c0;
        off[base+2] = tb + c0 + c1;
        off[base+3] = tb + c0 + c1 + c2;
    }
}

// ---------- fill per-cell point lists ----------
__global__ __launch_bounds__(256)
void k_fill(const int* __restrict__ ind, const unsigned* __restrict__ rank,
            const unsigned* __restrict__ off, unsigned* __restrict__ list, int n){
    int i = blockIdx.x*256 + threadIdx.x;
    if (i >= n) return;
    int bb = ind[(size_t)i*3], gx = ind[(size_t)i*3+1], gy = ind[(size_t)i*3+2];
    unsigned vox = ((unsigned)bb*GXd + (unsigned)gx)*GYd + (unsigned)gy;
    list[off[vox] + rank[i]] = (unsigned)i;
}

// ---------- layer4 via MFMA, SORTED output: z4[sorted_pos] = bn3relu(z3[list[pos]]) @ w4 ----------
__global__ __launch_bounds__(256)
void k_l4(const unsigned short* __restrict__ z3, const unsigned* __restrict__ list,
          const float* __restrict__ w4, const float* __restrict__ b4,
          const float* __restrict__ a3, const float* __restrict__ c3,
          unsigned short* __restrict__ z4, int n){
    __shared__ short w4t[256*128];           // 64 KB: bf16 w4^T [c][k], swizzled
    int tid = threadIdx.x;
    for (int e = tid; e < 16384; e += 256){
        int k2 = e >> 8;
        int c  = e & 255;
        unsigned lo = f2bf(w4[(size_t)(2*k2)*256 + c]);
        unsigned hi = f2bf(w4[(size_t)(2*k2+1)*256 + c]);
        int addr = (c*256 + k2*4) ^ ((c & 7) << 4);
        *(unsigned*)((char*)w4t + addr) = lo | (hi << 16);
    }
    __syncthreads();

    int lane = tid & 63, wid = tid >> 6;
    int l15 = lane & 15, lg = lane >> 4;
    int p0 = blockIdx.x*64 + wid*16;
    int prow = p0 + l15;
    int prow2 = prow < n ? prow : (n - 1);
    int srow = (int)list[prow2];             // original point id (sorted by cell)
    const unsigned short* zrow = z3 + (size_t)srow*128;

    f32x4 acc[16];
#pragma unroll
    for (int t = 0; t < 16; t++){
        float bv = b4[t*16 + l15];
        acc[t] = (f32x4){bv, bv, bv, bv};
    }

#pragma unroll
    for (int ks = 0; ks < 4; ks++){
        int kbase = ks*32 + lg*8;
        uint4 ua = *(const uint4*)(zrow + kbase);
        float4 av0 = *(const float4*)(a3 + kbase);
        float4 av1 = *(const float4*)(a3 + kbase + 4);
        float4 cv0 = *(const float4*)(c3 + kbase);
        float4 cv1 = *(const float4*)(c3 + kbase + 4);
        bf16x8 af;
        af[0] = (short)f2bf(fmaxf(fmaf(bf2f((unsigned short)(ua.x & 0xFFFFu)), av0.x, cv0.x), 0.f));
        af[1] = (short)f2bf(fmaxf(fmaf(bf2f((unsigned short)(ua.x >> 16)),     av0.y, cv0.y), 0.f));
        af[2] = (short)f2bf(fmaxf(fmaf(bf2f((unsigned short)(ua.y & 0xFFFFu)), av0.z, cv0.z), 0.f));
        af[3] = (short)f2bf(fmaxf(fmaf(bf2f((unsigned short)(ua.y >> 16)),     av0.w, cv0.w), 0.f));
        af[4] = (short)f2bf(fmaxf(fmaf(bf2f((unsigned short)(ua.z & 0xFFFFu)), av1.x, cv1.x), 0.f));
        af[5] = (short)f2bf(fmaxf(fmaf(bf2f((unsigned short)(ua.z >> 16)),     av1.y, cv1.y), 0.f));
        af[6] = (short)f2bf(fmaxf(fmaf(bf2f((unsigned short)(ua.w & 0xFFFFu)), av1.z, cv1.z), 0.f));
        af[7] = (short)f2bf(fmaxf(fmaf(bf2f((unsigned short)(ua.w >> 16)),     av1.w, cv1.w), 0.f));
#pragma unroll
        for (int t = 0; t < 16; t++){
            int c = t*16 + l15;
            int addr = (c*256 + kbase*2) ^ ((c & 7) << 4);
            bf16x8 bf = *(const bf16x8*)((const char*)w4t + addr);
            acc[t] = __builtin_amdgcn_mfma_f32_16x16x32_bf16(af, bf, acc[t], 0, 0, 0);
        }
    }

#pragma unroll
    for (int t = 0; t < 16; t++){
#pragma unroll
        for (int r = 0; r < 4; r++){
            int pr = p0 + lg*4 + r;
            if (pr < n)
                z4[(size_t)pr*256 + t*16 + l15] = f2bf(acc[t][r]);
        }
    }
}

// ---------- FUSED gather-max + 3x3 maxpool ----------
// Stage: per-cell 256-ch max from sorted z4 for the 6x18 halo (wave-per-cell,
// 2 cells in flight; out-of-grid -> -inf, empty -> 0). Phase 2: rolling 3x3
// max from LDS (fully unrolled, static indices), planar float4 full-line writes.
#define NOCELL 0xFFFFFFFFu
__global__ __launch_bounds__(256)
void k_gpool(const unsigned* __restrict__ cnt, const unsigned* __restrict__ off,
             const unsigned short* __restrict__ z4, float* __restrict__ out){
    __shared__ unsigned short cm[6*18*256];   // 55296 B: [xx][ty][c] cell maxes
    __shared__ unsigned cno[216];             // [e]{cnt,off}
    int t = threadIdx.x;
    int gy0 = blockIdx.x * 16;
    int gx0 = blockIdx.y * 4;
    int b   = blockIdx.z;

    // stage cnt/off for the 108 halo cells
    for (int e = t; e < 108; e += 256){
        int xx = e / 18, ty = e % 18;
        int gxx = gx0 - 1 + xx, gyy = gy0 - 1 + ty;
        unsigned c = NOCELL, o = 0;
        if ((unsigned)gxx < (unsigned)GXd && (unsigned)gyy < (unsigned)GYd){
            unsigned cell = ((unsigned)b*GXd + gxx)*GYd + gyy;
            c = cnt[cell]; o = off[cell];
        }
        cno[e*2]   = c;
        cno[e*2+1] = o;
    }
    __syncthreads();

    int lane = t & 63, wid = t >> 6;
    const float NEGINF = -__builtin_inff();
    for (int e = wid; e < 108; e += 8){
        int e1 = e + 4;
        bool h1 = e1 < 108;
        unsigned cn0 = cno[e*2],  o0 = cno[e*2+1];
        unsigned cn1 = h1 ? cno[e1*2] : NOCELL;
        unsigned o1  = h1 ? cno[e1*2+1] : 0;
        unsigned n0 = (cn0 == NOCELL) ? 0u : cn0;
        unsigned n1 = (cn1 == NOCELL) ? 0u : cn1;
        float a0 = NEGINF, a1 = NEGINF, a2 = NEGINF, a3 = NEGINF;
        float d0 = NEGINF, d1 = NEGINF, d2 = NEGINF, d3 = NEGINF;
        unsigned nm = n0 > n1 ? n0 : n1;
        for (unsigned p = 0; p < nm; p++){
            if (p < n0){
                uint2 u = *(const uint2*)(z4 + (size_t)(o0 + p)*256 + lane*4);
                a0 = fmaxf(a0, bf2f((unsigned short)(u.x & 0xFFFFu)));
                a1 = fmaxf(a1, bf2f((unsigned short)(u.x >> 16)));
                a2 = fmaxf(a2, bf2f((unsigned short)(u.y & 0xFFFFu)));
                a3 = fmaxf(a3, bf2f((unsigned short)(u.y >> 16)));
            }
            if (p < n1){
                uint2 u = *(const uint2*)(z4 + (size_t)(o1 + p)*256 + lane*4);
                d0 = fmaxf(d0, bf2f((unsigned short)(u.x & 0xFFFFu)));
                d1 = fmaxf(d1, bf2f((unsigned short)(u.x >> 16)));
                d2 = fmaxf(d2, bf2f((unsigned short)(u.y & 0xFFFFu)));
                d3 = fmaxf(d3, bf2f((unsigned short)(u.y >> 16)));
            }
        }
        if (cn0 == 0u){ a0 = a1 = a2 = a3 = 0.f; }
        {
            unsigned lo = (unsigned)f2bf(a0) | ((unsigned)f2bf(a1) << 16);
            unsigned hi = (unsigned)f2bf(a2) | ((unsigned)f2bf(a3) << 16);
            *(uint2*)&cm[e*256 + lane*4] = make_uint2(lo, hi);
        }
        if (h1){
            if (cn1 == 0u){ d0 = d1 = d2 = d3 = 0.f; }
            unsigned lo = (unsigned)f2bf(d0) | ((unsigned)f2bf(d1) << 16);
            unsigned hi = (unsigned)f2bf(d2) | ((unsigned)f2bf(d3) << 16);
            *(uint2*)&cm[e1*256 + lane*4] = make_uint2(lo, hi);
        }
    }
    __syncthreads();

    // phase 2: c = t; rolling 3x3 from LDS, write planar float4 runs
    int c = t;
    int ymax = GYd - gy0; if (ymax > 16) ymax = 16;    // 16 or 8 (both %4==0)
    float rA[4], rB[4];
    float ob[4][4];
#pragma unroll
    for (int g = 0; g < 4; g++){ rA[g] = 0.f; rB[g] = 0.f; }
#pragma unroll
    for (int ty = 0; ty < 18; ty++){
        float v[6];
#pragma unroll
        for (int xx = 0; xx < 6; xx++)
            v[xx] = bf2f(cm[(xx*18 + ty)*256 + c]);
        float c3[4];
#pragma unroll
        for (int g = 0; g < 4; g++)
            c3[g] = fmaxf(fmaxf(v[g], v[g+1]), v[g+2]);
        if (ty >= 2){
            int yl = ty - 2;
#pragma unroll
            for (int g = 0; g < 4; g++)
                ob[g][yl & 3] = fmaxf(fmaxf(rA[g], rB[g]), c3[g]);
            if ((yl & 3) == 3){
                int y0 = yl - 3;
                if (y0 < ymax){
#pragma unroll
                    for (int g = 0; g < 4; g++){
                        float* dst = out + ((size_t)b*258 + c)*GXY
                                   + (size_t)(gx0+g)*GYd + gy0 + y0;
                        *(float4*)dst = make_float4(ob[g][0], ob[g][1], ob[g][2], ob[g][3]);
                    }
                }
            }
        }
#pragma unroll
        for (int g = 0; g < 4; g++){ rA[g] = rB[g]; rB[g] = c3[g]; }
    }
}

// ---------- residual channels ----------
__global__ __launch_bounds__(256)
void k_res(const unsigned* __restrict__ pres, float* __restrict__ out){
    int idx = blockIdx.x*256 + threadIdx.x;
    const int total = NBd*2*GXY;
    if (idx >= total) return;
    int gy = idx % GYd;
    int t  = idx / GYd;
    int gx = t % GXd;  t /= GXd;
    int r  = t & 1;
    int b  = t >> 1;
    unsigned u = pres[idx];
    float f = u ? unmapf(u) : 0.f;
    out[(((size_t)b*258 + 256 + r)*GXd + gx)*GYd + gy] = f;
}

extern "C" void kernel_launch(void* const* d_in, const int* in_sizes, int n_in,
                              void* d_out, int out_size, void* d_ws, size_t ws_size,
                              hipStream_t stream){
    (void)n_in; (void)out_size; (void)ws_size;
    const float* fea   = (const float*)d_in[0];
    const int*   ind   = (const int*)  d_in[1];
    const float* bn0_g = (const float*)d_in[2];
    const float* bn0_b = (const float*)d_in[3];
    const float* w1    = (const float*)d_in[4];
    const float* b1    = (const float*)d_in[5];
    const float* bn1_g = (const float*)d_in[6];
    const float* bn1_b = (const float*)d_in[7];
    const float* w2    = (const float*)d_in[8];
    const float* b2    = (const float*)d_in[9];
    const float* bn2_g = (const float*)d_in[10];
    const float* bn2_b = (const float*)d_in[11];
    const float* w3    = (const float*)d_in[12];
    const float* b3    = (const float*)d_in[13];
    const float* bn3_g = (const float*)d_in[14];
    const float* bn3_b = (const float*)d_in[15];
    const float* w4    = (const float*)d_in[16];
    const float* b4    = (const float*)d_in[17];

    int n = in_sizes[0] / 11;
    float invN = 1.0f / (float)n;

    // ---- ws layout ----
    const size_t Z4_B     = (size_t)240000*256*2;       // 122,880,000
    const size_t POOL_B   = (size_t)NCELL*256*2;        // 176,947,200 (z1/z2/z3 arena)
    const size_t PRES_B   = (size_t)NBd*2*GXY*4;        //   5,529,600
    const size_t CNT_B    = (size_t)NCELL*4;            //   2,764,800
    const size_t STAT_B   = 960*4;
    const size_t GCTR_B   = 256;

    char* base = (char*)d_ws;
    unsigned short* z4 = (unsigned short*)base;
    float*          z1 = (float*)(base + Z4_B);
    float*          z2 = (float*)(base + Z4_B + 30720000);
    unsigned short* z3 = (unsigned short*)(base + Z4_B + 92160000);
    unsigned* pres  = (unsigned*)(base + Z4_B + POOL_B);
    unsigned* cnt   = (unsigned*)((char*)pres + PRES_B);
    float*    stats = (float*)((char*)cnt + CNT_B);
    unsigned* gctr  = (unsigned*)((char*)stats + STAT_B);
    unsigned* off   = (unsigned*)((char*)gctr + GCTR_B);
    unsigned* list  = (unsigned*)((char*)off + CNT_B);
    unsigned* rank  = (unsigned*)((char*)list + (size_t)240000*4);

    float* sum0 = stats;       float* sq0 = stats + 16;
    float* sum1 = stats + 32;  float* sq1 = stats + 64;
    float* sum2 = stats + 96;  float* sq2 = stats + 160;
    float* sum3 = stats + 224; float* sq3 = stats + 352;
    float* a0 = stats + 480;   float* c0 = stats + 496;
    float* a1 = stats + 512;   float* c1 = stats + 544;
    float* a2 = stats + 576;   float* c2 = stats + 640;
    float* a3 = stats + 704;   float* c3 = stats + 832;

    hipMemsetAsync(pres, 0, PRES_B + CNT_B + STAT_B + GCTR_B, stream);

    int nb = (n + 255) / 256;
    int nb64 = (n + 63) / 64;
    k_stats0<<<nb, 256, 0, stream>>>(fea, sum0, sq0, n);
    k_fin<<<1, 128, 0, stream>>>(sum0, sq0, bn0_g, bn0_b, a0, c0, 9,  invN);
    k_l1<<<nb, 256, 0, stream>>>(fea, ind, w1, b1, a0, c0, z1, pres, cnt, rank, sum1, sq1, n);
    k_fin<<<1, 128, 0, stream>>>(sum1, sq1, bn1_g, bn1_b, a1, c1, 32, invN);
    k_l2<<<nb64, 256, 0, stream>>>(z1, w2, b2, a1, c1, z2, sum2, sq2, n);
    k_fin<<<1, 128, 0, stream>>>(sum2, sq2, bn2_g, bn2_b, a2, c2, 64, invN);
    k_l3<<<nb64, 256, 0, stream>>>(z2, w3, b3, a2, c2, z3, sum3, sq3, n);
    k_fin<<<1, 128, 0, stream>>>(sum3, sq3, bn3_g, bn3_b, a3, c3, 128, invN);

    k_off <<<(NCELL + 1023)/1024, 256, 0, stream>>>(cnt, off, gctr);
    k_fill<<<nb, 256, 0, stream>>>(ind, rank, off, list, n);

    k_l4<<<nb64, 256, 0, stream>>>(z3, list, w4, b4, a3, c3, z4, n);

    k_gpool<<<dim3(23, 120, 2), 256, 0, stream>>>(cnt, off, z4, (float*)d_out);

    k_res<<<(NBd*2*GXY + 255) / 256, 256, 0, stream>>>(pres, (float*)d_out);
}

// Round 16
// 693.539 us; speedup vs baseline: 1.1484x; 1.0594x over previous
//
#include <hip/hip_runtime.h>
#include <cstdint>
#include <cstddef>

#define GXd 480
#define GYd 360
#define NBd 2
#define GXY (480*360)
#define NCELL (NBd*GXY)
#define EPSBN 1e-5f

typedef float  f32x4  __attribute__((ext_vector_type(4)));
typedef short  bf16x8 __attribute__((ext_vector_type(8)));

// ---------- order-preserving float <-> uint map (residual atomics only) ----------
__device__ __forceinline__ unsigned mapf(float f){
    unsigned u = __float_as_uint(f);
    return (u & 0x80000000u) ? ~u : (u | 0x80000000u);
}
__device__ __forceinline__ float unmapf(unsigned m){
    return (m & 0x80000000u) ? __uint_as_float(m ^ 0x80000000u)
                             : __uint_as_float(~m);
}

// ---------- bf16 helpers (RTN-even) ----------
__device__ __forceinline__ unsigned short f2bf(float f){
    unsigned u = __float_as_uint(f);
    unsigned r = (u + 0x7FFFu + ((u >> 16) & 1u)) >> 16;
    return (unsigned short)r;
}
__device__ __forceinline__ float bf2f(unsigned short s){
    return __uint_as_float(((unsigned)s) << 16);
}

// ---------- dense layer helper ----------
template<int DIN, int DOUT>
__device__ __forceinline__ void dense(const float (&in)[DIN], float (&out)[DOUT],
                                      const float* __restrict__ w,
                                      const float* __restrict__ b){
#pragma unroll
    for (int j = 0; j < DOUT; j++) out[j] = b[j];
#pragma unroll
    for (int d = 0; d < DIN; d++){
        float v = in[d];
#pragma unroll
        for (int j = 0; j < DOUT; j++) out[j] = fmaf(v, w[d*DOUT + j], out[j]);
    }
}

// ---------- block-level sum/sumsq reduction ----------
template<int D>
__device__ __forceinline__ void reduce_stats(const float (&h)[D], bool valid,
                                             float* __restrict__ gsum,
                                             float* __restrict__ gsq){
    __shared__ float ssum[D];
    __shared__ float ssq[D];
    int tid = threadIdx.x;
    for (int t = tid; t < D; t += 256){ ssum[t] = 0.f; ssq[t] = 0.f; }
    __syncthreads();
#pragma unroll
    for (int j = 0; j < D; j++){
        float v = valid ? h[j] : 0.f;
        float s = v * v;
#pragma unroll
        for (int o = 32; o > 0; o >>= 1){
            v += __shfl_down(v, o, 64);
            s += __shfl_down(s, o, 64);
        }
        if ((tid & 63) == 0){
            atomicAdd(&ssum[j], v);
            atomicAdd(&ssq[j], s);
        }
    }
    __syncthreads();
    for (int t = tid; t < D; t += 256){
        atomicAdd(&gsum[t], ssum[t]);
        atomicAdd(&gsq[t], ssq[t]);
    }
}

// ---------- stats of raw input columns 0..8 ----------
__global__ __launch_bounds__(256)
void k_stats0(const float* __restrict__ fea, float* gsum, float* gsq, int n){
    int i = blockIdx.x*256 + threadIdx.x;
    bool valid = i < n;
    int i2 = valid ? i : 0;
    float x[9];
#pragma unroll
    for (int d = 0; d < 9; d++) x[d] = fea[(size_t)i2*11 + d];
    reduce_stats<9>(x, valid, gsum, gsq);
}

// ---------- finalize BN ----------
__global__ void k_fin(const float* __restrict__ sum, const float* __restrict__ sq,
                      const float* __restrict__ g, const float* __restrict__ bb,
                      float* __restrict__ a_out, float* __restrict__ c_out,
                      int D, float invN){
    int t = threadIdx.x;
    if (t < D){
        float mu  = sum[t] * invN;
        float var = fmaf(-mu, mu, sq[t] * invN);
        float rs  = rsqrtf(var + EPSBN);
        float a   = rs * g[t];
        a_out[t] = a;
        c_out[t] = fmaf(-mu, a, bb[t]);
    }
}

// ---------- layer1: bn0 -> 9x32; z1; stats; voxel count+rank; res atomics ----------
__global__ __launch_bounds__(256)
void k_l1(const float* __restrict__ fea, const int* __restrict__ ind,
          const float* __restrict__ w1, const float* __restrict__ b1,
          const float* __restrict__ a0, const float* __restrict__ c0,
          float* __restrict__ z1, unsigned* __restrict__ pres,
          unsigned* __restrict__ cnt, unsigned* __restrict__ rank,
          float* gsum, float* gsq, int n){
    int i = blockIdx.x*256 + threadIdx.x;
    bool valid = i < n;
    int i2 = valid ? i : 0;
    float x[9];
#pragma unroll
    for (int d = 0; d < 9; d++) x[d] = fmaf(fea[(size_t)i2*11 + d], a0[d], c0[d]);
    float h[32];
    dense<9,32>(x, h, w1, b1);
    if (valid){
        float4* dst = (float4*)(z1 + (size_t)i*32);
#pragma unroll
        for (int q = 0; q < 8; q++)
            dst[q] = make_float4(h[q*4], h[q*4+1], h[q*4+2], h[q*4+3]);
        float r0 = fea[(size_t)i*11 + 9];
        float r1 = fea[(size_t)i*11 + 10];
        int bb = ind[(size_t)i*3 + 0];
        int gx = ind[(size_t)i*3 + 1];
        int gy = ind[(size_t)i*3 + 2];
        unsigned vox = ((unsigned)bb*GXd + (unsigned)gx)*GYd + (unsigned)gy;
        rank[i] = atomicAdd(&cnt[vox], 1u);
        size_t rbase = (size_t)bb*2*GXY + (size_t)gx*GYd + gy;
        atomicMax(pres + rbase,       mapf(r0));
        atomicMax(pres + rbase + GXY, mapf(r1));
    }
    reduce_stats<32>(h, valid, gsum, gsq);
}

// ---------- layer2 via MFMA: z2[n x 64] = bn1relu(z1)[n x 32] @ w2 ----------
__global__ __launch_bounds__(256)
void k_l2(const float* __restrict__ z1,
          const float* __restrict__ w2, const float* __restrict__ b2,
          const float* __restrict__ a1, const float* __restrict__ c1,
          float* __restrict__ z2, float* gsum, float* gsq, int n){
    __shared__ short w2t[64*40];             // 5120 B
    __shared__ float ssum[64], ssq[64];
    int tid = threadIdx.x;
    if (tid < 64){ ssum[tid] = 0.f; ssq[tid] = 0.f; }
    for (int e = tid; e < 2048; e += 256){
        int k = e >> 6, c = e & 63;
        w2t[c*40 + k] = (short)f2bf(w2[k*64 + c]);
    }
    __syncthreads();

    int lane = tid & 63, wid = tid >> 6;
    int l15 = lane & 15, lg = lane >> 4;
    int p0 = blockIdx.x*64 + wid*16;
    int prow = p0 + l15;
    int prow2 = prow < n ? prow : (n - 1);
    const float* zrow = z1 + (size_t)prow2*32;

    int kbase = lg*8;
    float4 v0 = *(const float4*)(zrow + kbase);
    float4 v1 = *(const float4*)(zrow + kbase + 4);
    float4 av0 = *(const float4*)(a1 + kbase);
    float4 av1 = *(const float4*)(a1 + kbase + 4);
    float4 cv0 = *(const float4*)(c1 + kbase);
    float4 cv1 = *(const float4*)(c1 + kbase + 4);
    bf16x8 af;
    af[0] = (short)f2bf(fmaxf(fmaf(v0.x, av0.x, cv0.x), 0.f));
    af[1] = (short)f2bf(fmaxf(fmaf(v0.y, av0.y, cv0.y), 0.f));
    af[2] = (short)f2bf(fmaxf(fmaf(v0.z, av0.z, cv0.z), 0.f));
    af[3] = (short)f2bf(fmaxf(fmaf(v0.w, av0.w, cv0.w), 0.f));
    af[4] = (short)f2bf(fmaxf(fmaf(v1.x, av1.x, cv1.x), 0.f));
    af[5] = (short)f2bf(fmaxf(fmaf(v1.y, av1.y, cv1.y), 0.f));
    af[6] = (short)f2bf(fmaxf(fmaf(v1.z, av1.z, cv1.z), 0.f));
    af[7] = (short)f2bf(fmaxf(fmaf(v1.w, av1.w, cv1.w), 0.f));

    f32x4 acc[4];
#pragma unroll
    for (int t = 0; t < 4; t++){
        float bv = b2[t*16 + l15];
        acc[t] = (f32x4){bv, bv, bv, bv};
    }
#pragma unroll
    for (int t = 0; t < 4; t++){
        bf16x8 bf = *(const bf16x8*)&w2t[(t*16 + l15)*40 + kbase];
        acc[t] = __builtin_amdgcn_mfma_f32_16x16x32_bf16(af, bf, acc[t], 0, 0, 0);
    }

#pragma unroll
    for (int t = 0; t < 4; t++){
        int c = t*16 + l15;
        float s = 0.f, q = 0.f;
#pragma unroll
        for (int r = 0; r < 4; r++){
            int pr = p0 + lg*4 + r;
            float v = acc[t][r];
            if (pr < n){
                z2[(size_t)pr*64 + c] = v;
                s += v; q += v*v;
            }
        }
        s += __shfl_xor(s, 16, 64);  q += __shfl_xor(q, 16, 64);
        s += __shfl_xor(s, 32, 64);  q += __shfl_xor(q, 32, 64);
        if (lg == 0){ atomicAdd(&ssum[c], s); atomicAdd(&ssq[c], q); }
    }
    __syncthreads();
    if (tid < 64){ atomicAdd(gsum + tid, ssum[tid]); atomicAdd(gsq + tid, ssq[tid]); }
}

// ---------- layer3 via MFMA: z3[n x 128] = bn2relu(z2)[n x 64] @ w3 (bf16 out) ----------
__global__ __launch_bounds__(256)
void k_l3(const float* __restrict__ z2,
          const float* __restrict__ w3, const float* __restrict__ b3,
          const float* __restrict__ a2, const float* __restrict__ c2,
          unsigned short* __restrict__ z3, float* gsum, float* gsq, int n){
    __shared__ short w3t[128*72];            // 18432 B, [c][k] stride 72
    __shared__ float ssum[128], ssq[128];
    int tid = threadIdx.x;
    if (tid < 128){ ssum[tid] = 0.f; ssq[tid] = 0.f; }
    for (int e = tid; e < 8192; e += 256){
        int k = e >> 7, c = e & 127;
        w3t[c*72 + k] = (short)f2bf(w3[k*128 + c]);
    }
    __syncthreads();

    int lane = tid & 63, wid = tid >> 6;
    int l15 = lane & 15, lg = lane >> 4;
    int p0 = blockIdx.x*64 + wid*16;
    int prow = p0 + l15;
    int prow2 = prow < n ? prow : (n - 1);
    const float* zrow = z2 + (size_t)prow2*64;

    f32x4 acc[8];
#pragma unroll
    for (int t = 0; t < 8; t++){
        float bv = b3[t*16 + l15];
        acc[t] = (f32x4){bv, bv, bv, bv};
    }

#pragma unroll
    for (int ks = 0; ks < 2; ks++){
        int kbase = ks*32 + lg*8;
        float4 v0 = *(const float4*)(zrow + kbase);
        float4 v1 = *(const float4*)(zrow + kbase + 4);
        float4 av0 = *(const float4*)(a2 + kbase);
        float4 av1 = *(const float4*)(a2 + kbase + 4);
        float4 cv0 = *(const float4*)(c2 + kbase);
        float4 cv1 = *(const float4*)(c2 + kbase + 4);
        bf16x8 af;
        af[0] = (short)f2bf(fmaxf(fmaf(v0.x, av0.x, cv0.x), 0.f));
        af[1] = (short)f2bf(fmaxf(fmaf(v0.y, av0.y, cv0.y), 0.f));
        af[2] = (short)f2bf(fmaxf(fmaf(v0.z, av0.z, cv0.z), 0.f));
        af[3] = (short)f2bf(fmaxf(fmaf(v0.w, av0.w, cv0.w), 0.f));
        af[4] = (short)f2bf(fmaxf(fmaf(v1.x, av1.x, cv1.x), 0.f));
        af[5] = (short)f2bf(fmaxf(fmaf(v1.y, av1.y, cv1.y), 0.f));
        af[6] = (short)f2bf(fmaxf(fmaf(v1.z, av1.z, cv1.z), 0.f));
        af[7] = (short)f2bf(fmaxf(fmaf(v1.w, av1.w, cv1.w), 0.f));
#pragma unroll
        for (int t = 0; t < 8; t++){
            bf16x8 bf = *(const bf16x8*)&w3t[(t*16 + l15)*72 + kbase];
            acc[t] = __builtin_amdgcn_mfma_f32_16x16x32_bf16(af, bf, acc[t], 0, 0, 0);
        }
    }

#pragma unroll
    for (int t = 0; t < 8; t++){
        int c = t*16 + l15;
        float s = 0.f, q = 0.f;
#pragma unroll
        for (int r = 0; r < 4; r++){
            int pr = p0 + lg*4 + r;
            unsigned short rb = f2bf(acc[t][r]);
            float rv = bf2f(rb);
            if (pr < n){
                z3[(size_t)pr*128 + c] = rb;
                s += rv; q += rv*rv;
            }
        }
        s += __shfl_xor(s, 16, 64);  q += __shfl_xor(q, 16, 64);
        s += __shfl_xor(s, 32, 64);  q += __shfl_xor(q, 32, 64);
        if (lg == 0){ atomicAdd(&ssum[c], s); atomicAdd(&ssq[c], q); }
    }
    __syncthreads();
    if (tid < 128){ atomicAdd(gsum + tid, ssum[tid]); atomicAdd(gsq + tid, ssq[tid]); }
}

// ---------- exclusive scan of cnt via block tickets ----------
__global__ __launch_bounds__(256)
void k_off(const unsigned* __restrict__ cnt, unsigned* __restrict__ off,
           unsigned* __restrict__ gctr){
    __shared__ unsigned wtot[4];
    __shared__ unsigned wbase[4];
    int t = threadIdx.x;
    int lane = t & 63, w = t >> 6;
    int base = blockIdx.x * 1024 + t * 4;
    bool ok = base < NCELL;
    unsigned c0 = 0, c1 = 0, c2 = 0, c3 = 0;
    if (ok){ c0 = cnt[base]; c1 = cnt[base+1]; c2 = cnt[base+2]; c3 = cnt[base+3]; }
    unsigned tot = c0 + c1 + c2 + c3;
    unsigned incl = tot;
#pragma unroll
    for (int o = 1; o < 64; o <<= 1){
        unsigned v = __shfl_up(incl, o, 64);
        if (lane >= o) incl += v;
    }
    if (lane == 63) wtot[w] = incl;
    __syncthreads();
    if (t == 0){
        unsigned bt = wtot[0] + wtot[1] + wtot[2] + wtot[3];
        unsigned gb = atomicAdd(gctr, bt);
        unsigned s = 0;
#pragma unroll
        for (int q = 0; q < 4; q++){ wbase[q] = gb + s; s += wtot[q]; }
    }
    __syncthreads();
    if (ok){
        unsigned tb = wbase[w] + incl - tot;
        off[base]   = tb;
        off[base+1] = tb + c0;
        off[base+2] = tb + c0 + c1;
        off[base+3] = tb + c0 + c1 + c2;
    }
}

// ---------- fill per-cell point lists ----------
__global__ __launch_bounds__(256)
void k_fill(const int* __restrict__ ind, const unsigned* __restrict__ rank,
            const unsigned* __restrict__ off, unsigned* __restrict__ list, int n){
    int i = blockIdx.x*256 + threadIdx.x;
    if (i >= n) return;
    int bb = ind[(size_t)i*3], gx = ind[(size_t)i*3+1], gy = ind[(size_t)i*3+2];
    unsigned vox = ((unsigned)bb*GXd + (unsigned)gx)*GYd + (unsigned)gy;
    list[off[vox] + rank[i]] = (unsigned)i;
}

// ---------- layer4 via MFMA, SORTED output: z4[sorted_pos] = bn3relu(z3[list[pos]]) @ w4 ----------
__global__ __launch_bounds__(256)
void k_l4(const unsigned short* __restrict__ z3, const unsigned* __restrict__ list,
          const float* __restrict__ w4, const float* __restrict__ b4,
          const float* __restrict__ a3, const float* __restrict__ c3,
          unsigned short* __restrict__ z4, int n){
    __shared__ short w4t[256*128];           // 64 KB: bf16 w4^T [c][k], swizzled
    int tid = threadIdx.x;
    for (int e = tid; e < 16384; e += 256){
        int k2 = e >> 8;
        int c  = e & 255;
        unsigned lo = f2bf(w4[(size_t)(2*k2)*256 + c]);
        unsigned hi = f2bf(w4[(size_t)(2*k2+1)*256 + c]);
        int addr = (c*256 + k2*4) ^ ((c & 7) << 4);
        *(unsigned*)((char*)w4t + addr) = lo | (hi << 16);
    }
    __syncthreads();

    int lane = tid & 63, wid = tid >> 6;
    int l15 = lane & 15, lg = lane >> 4;
    int p0 = blockIdx.x*64 + wid*16;
    int prow = p0 + l15;
    int prow2 = prow < n ? prow : (n - 1);
    int srow = (int)list[prow2];             // original point id (sorted by cell)
    const unsigned short* zrow = z3 + (size_t)srow*128;

    f32x4 acc[16];
#pragma unroll
    for (int t = 0; t < 16; t++){
        float bv = b4[t*16 + l15];
        acc[t] = (f32x4){bv, bv, bv, bv};
    }

#pragma unroll
    for (int ks = 0; ks < 4; ks++){
        int kbase = ks*32 + lg*8;
        uint4 ua = *(const uint4*)(zrow + kbase);
        float4 av0 = *(const float4*)(a3 + kbase);
        float4 av1 = *(const float4*)(a3 + kbase + 4);
        float4 cv0 = *(const float4*)(c3 + kbase);
        float4 cv1 = *(const float4*)(c3 + kbase + 4);
        bf16x8 af;
        af[0] = (short)f2bf(fmaxf(fmaf(bf2f((unsigned short)(ua.x & 0xFFFFu)), av0.x, cv0.x), 0.f));
        af[1] = (short)f2bf(fmaxf(fmaf(bf2f((unsigned short)(ua.x >> 16)),     av0.y, cv0.y), 0.f));
        af[2] = (short)f2bf(fmaxf(fmaf(bf2f((unsigned short)(ua.y & 0xFFFFu)), av0.z, cv0.z), 0.f));
        af[3] = (short)f2bf(fmaxf(fmaf(bf2f((unsigned short)(ua.y >> 16)),     av0.w, cv0.w), 0.f));
        af[4] = (short)f2bf(fmaxf(fmaf(bf2f((unsigned short)(ua.z & 0xFFFFu)), av1.x, cv1.x), 0.f));
        af[5] = (short)f2bf(fmaxf(fmaf(bf2f((unsigned short)(ua.z >> 16)),     av1.y, cv1.y), 0.f));
        af[6] = (short)f2bf(fmaxf(fmaf(bf2f((unsigned short)(ua.w & 0xFFFFu)), av1.z, cv1.z), 0.f));
        af[7] = (short)f2bf(fmaxf(fmaf(bf2f((unsigned short)(ua.w >> 16)),     av1.w, cv1.w), 0.f));
#pragma unroll
        for (int t = 0; t < 16; t++){
            int c = t*16 + l15;
            int addr = (c*256 + kbase*2) ^ ((c & 7) << 4);
            bf16x8 bf = *(const bf16x8*)((const char*)w4t + addr);
            acc[t] = __builtin_amdgcn_mfma_f32_16x16x32_bf16(af, bf, acc[t], 0, 0, 0);
        }
    }

#pragma unroll
    for (int t = 0; t < 16; t++){
#pragma unroll
        for (int r = 0; r < 4; r++){
            int pr = p0 + lg*4 + r;
            if (pr < n)
                z4[(size_t)pr*256 + t*16 + l15] = f2bf(acc[t][r]);
        }
    }
}

// ---------- FUSED gather-max + 3x3 maxpool (register-buffered full-line writes) ----------
#define NOCELL 0xFFFFFFFFu
__global__ __launch_bounds__(256)
void k_gpool(const unsigned* __restrict__ cnt, const unsigned* __restrict__ off,
             const unsigned short* __restrict__ z4, float* __restrict__ out){
    __shared__ unsigned short cm[6*18*256];   // 55296 B: [xx][ty][c] cell maxes
    __shared__ unsigned cno[216];             // [e]{cnt,off}
    int t = threadIdx.x;
    int gy0 = blockIdx.x * 16;
    int gx0 = blockIdx.y * 4;
    int b   = blockIdx.z;

    // stage cnt/off for the 108 halo cells
    for (int e = t; e < 108; e += 256){
        int xx = e / 18, ty = e % 18;
        int gxx = gx0 - 1 + xx, gyy = gy0 - 1 + ty;
        unsigned c = NOCELL, o = 0;
        if ((unsigned)gxx < (unsigned)GXd && (unsigned)gyy < (unsigned)GYd){
            unsigned cell = ((unsigned)b*GXd + gxx)*GYd + gyy;
            c = cnt[cell]; o = off[cell];
        }
        cno[e*2]   = c;
        cno[e*2+1] = o;
    }
    __syncthreads();

    int lane = t & 63, wid = t >> 6;
    const float NEGINF = -__builtin_inff();
    for (int e = wid; e < 108; e += 8){
        int e1 = e + 4;
        bool h1 = e1 < 108;
        unsigned cn0 = cno[e*2],  o0 = cno[e*2+1];
        unsigned cn1 = h1 ? cno[e1*2] : NOCELL;
        unsigned o1  = h1 ? cno[e1*2+1] : 0;
        unsigned n0 = (cn0 == NOCELL) ? 0u : cn0;
        unsigned n1 = (cn1 == NOCELL) ? 0u : cn1;
        float a0 = NEGINF, a1 = NEGINF, a2 = NEGINF, a3 = NEGINF;
        float d0 = NEGINF, d1 = NEGINF, d2 = NEGINF, d3 = NEGINF;
        unsigned nm = n0 > n1 ? n0 : n1;
        for (unsigned p = 0; p < nm; p++){
            if (p < n0){
                uint2 u = *(const uint2*)(z4 + (size_t)(o0 + p)*256 + lane*4);
                a0 = fmaxf(a0, bf2f((unsigned short)(u.x & 0xFFFFu)));
                a1 = fmaxf(a1, bf2f((unsigned short)(u.x >> 16)));
                a2 = fmaxf(a2, bf2f((unsigned short)(u.y & 0xFFFFu)));
                a3 = fmaxf(a3, bf2f((unsigned short)(u.y >> 16)));
            }
            if (p < n1){
                uint2 u = *(const uint2*)(z4 + (size_t)(o1 + p)*256 + lane*4);
                d0 = fmaxf(d0, bf2f((unsigned short)(u.x & 0xFFFFu)));
                d1 = fmaxf(d1, bf2f((unsigned short)(u.x >> 16)));
                d2 = fmaxf(d2, bf2f((unsigned short)(u.y & 0xFFFFu)));
                d3 = fmaxf(d3, bf2f((unsigned short)(u.y >> 16)));
            }
        }
        if (cn0 == 0u){ a0 = a1 = a2 = a3 = 0.f; }
        {
            unsigned lo = (unsigned)f2bf(a0) | ((unsigned)f2bf(a1) << 16);
            unsigned hi = (unsigned)f2bf(a2) | ((unsigned)f2bf(a3) << 16);
            *(uint2*)&cm[e*256 + lane*4] = make_uint2(lo, hi);
        }
        if (h1){
            if (cn1 == 0u){ d0 = d1 = d2 = d3 = 0.f; }
            unsigned lo = (unsigned)f2bf(d0) | ((unsigned)f2bf(d1) << 16);
            unsigned hi = (unsigned)f2bf(d2) | ((unsigned)f2bf(d3) << 16);
            *(uint2*)&cm[e1*256 + lane*4] = make_uint2(lo, hi);
        }
    }
    __syncthreads();

    // phase 2: c = t; rolling 3x3 from LDS into register buffer ob[4][16],
    // then 4 consecutive float4 stores per line (full-line fills).
    int c = t;
    int ymax = GYd - gy0; if (ymax > 16) ymax = 16;    // 16 or 8 (both %4==0)
    float rA[4], rB[4];
    float ob[4][16];
#pragma unroll
    for (int g = 0; g < 4; g++){ rA[g] = 0.f; rB[g] = 0.f; }
#pragma unroll
    for (int ty = 0; ty < 18; ty++){
        float v[6];
#pragma unroll
        for (int xx = 0; xx < 6; xx++)
            v[xx] = bf2f(cm[(xx*18 + ty)*256 + c]);
        float c3[4];
#pragma unroll
        for (int g = 0; g < 4; g++)
            c3[g] = fmaxf(fmaxf(v[g], v[g+1]), v[g+2]);
        if (ty >= 2){
#pragma unroll
            for (int g = 0; g < 4; g++)
                ob[g][ty - 2] = fmaxf(fmaxf(rA[g], rB[g]), c3[g]);
        }
#pragma unroll
        for (int g = 0; g < 4; g++){ rA[g] = rB[g]; rB[g] = c3[g]; }
    }
    int qmax = ymax >> 2;                     // 4 or 2
#pragma unroll
    for (int g = 0; g < 4; g++){
        float* dst = out + ((size_t)b*258 + c)*GXY + (size_t)(gx0+g)*GYd + gy0;
#pragma unroll
        for (int q = 0; q < 4; q++){
            if (q < qmax)
                *(float4*)(dst + q*4) = make_float4(ob[g][q*4+0], ob[g][q*4+1],
                                                    ob[g][q*4+2], ob[g][q*4+3]);
        }
    }
}

// ---------- residual channels ----------
__global__ __launch_bounds__(256)
void k_res(const unsigned* __restrict__ pres, float* __restrict__ out){
    int idx = blockIdx.x*256 + threadIdx.x;
    const int total = NBd*2*GXY;
    if (idx >= total) return;
    int gy = idx % GYd;
    int t  = idx / GYd;
    int gx = t % GXd;  t /= GXd;
    int r  = t & 1;
    int b  = t >> 1;
    unsigned u = pres[idx];
    float f = u ? unmapf(u) : 0.f;
    out[(((size_t)b*258 + 256 + r)*GXd + gx)*GYd + gy] = f;
}

extern "C" void kernel_launch(void* const* d_in, const int* in_sizes, int n_in,
                              void* d_out, int out_size, void* d_ws, size_t ws_size,
                              hipStream_t stream){
    (void)n_in; (void)out_size; (void)ws_size;
    const float* fea   = (const float*)d_in[0];
    const int*   ind   = (const int*)  d_in[1];
    const float* bn0_g = (const float*)d_in[2];
    const float* bn0_b = (const float*)d_in[3];
    const float* w1    = (const float*)d_in[4];
    const float* b1    = (const float*)d_in[5];
    const float* bn1_g = (const float*)d_in[6];
    const float* bn1_b = (const float*)d_in[7];
    const float* w2    = (const float*)d_in[8];
    const float* b2    = (const float*)d_in[9];
    const float* bn2_g = (const float*)d_in[10];
    const float* bn2_b = (const float*)d_in[11];
    const float* w3    = (const float*)d_in[12];
    const float* b3    = (const float*)d_in[13];
    const float* bn3_g = (const float*)d_in[14];
    const float* bn3_b = (const float*)d_in[15];
    const float* w4    = (const float*)d_in[16];
    const float* b4    = (const float*)d_in[17];

    int n = in_sizes[0] / 11;
    float invN = 1.0f / (float)n;

    // ---- ws layout ----
    const size_t Z4_B     = (size_t)240000*256*2;       // 122,880,000
    const size_t POOL_B   = (size_t)NCELL*256*2;        // 176,947,200 (z1/z2/z3 arena)
    const size_t PRES_B   = (size_t)NBd*2*GXY*4;        //   5,529,600
    const size_t CNT_B    = (size_t)NCELL*4;            //   2,764,800
    const size_t STAT_B   = 960*4;
    const size_t GCTR_B   = 256;

    char* base = (char*)d_ws;
    unsigned short* z4 = (unsigned short*)base;
    float*          z1 = (float*)(base + Z4_B);
    float*          z2 = (float*)(base + Z4_B + 30720000);
    unsigned short* z3 = (unsigned short*)(base + Z4_B + 92160000);
    unsigned* pres  = (unsigned*)(base + Z4_B + POOL_B);
    unsigned* cnt   = (unsigned*)((char*)pres + PRES_B);
    float*    stats = (float*)((char*)cnt + CNT_B);
    unsigned* gctr  = (unsigned*)((char*)stats + STAT_B);
    unsigned* off   = (unsigned*)((char*)gctr + GCTR_B);
    unsigned* list  = (unsigned*)((char*)off + CNT_B);
    unsigned* rank  = (unsigned*)((char*)list + (size_t)240000*4);

    float* sum0 = stats;       float* sq0 = stats + 16;
    float* sum1 = stats + 32;  float* sq1 = stats + 64;
    float* sum2 = stats + 96;  float* sq2 = stats + 160;
    float* sum3 = stats + 224; float* sq3 = stats + 352;
    float* a0 = stats + 480;   float* c0 = stats + 496;
    float* a1 = stats + 512;   float* c1 = stats + 544;
    float* a2 = stats + 576;   float* c2 = stats + 640;
    float* a3 = stats + 704;   float* c3 = stats + 832;

    hipMemsetAsync(pres, 0, PRES_B + CNT_B + STAT_B + GCTR_B, stream);

    int nb = (n + 255) / 256;
    int nb64 = (n + 63) / 64;
    k_stats0<<<nb, 256, 0, stream>>>(fea, sum0, sq0, n);
    k_fin<<<1, 128, 0, stream>>>(sum0, sq0, bn0_g, bn0_b, a0, c0, 9,  invN);
    k_l1<<<nb, 256, 0, stream>>>(fea, ind, w1, b1, a0, c0, z1, pres, cnt, rank, sum1, sq1, n);
    k_fin<<<1, 128, 0, stream>>>(sum1, sq1, bn1_g, bn1_b, a1, c1, 32, invN);
    k_l2<<<nb64, 256, 0, stream>>>(z1, w2, b2, a1, c1, z2, sum2, sq2, n);
    k_fin<<<1, 128, 0, stream>>>(sum2, sq2, bn2_g, bn2_b, a2, c2, 64, invN);
    k_l3<<<nb64, 256, 0, stream>>>(z2, w3, b3, a2, c2, z3, sum3, sq3, n);
    k_fin<<<1, 128, 0, stream>>>(sum3, sq3, bn3_g, bn3_b, a3, c3, 128, invN);

    k_off <<<(NCELL + 1023)/1024, 256, 0, stream>>>(cnt, off, gctr);
    k_fill<<<nb, 256, 0, stream>>>(ind, rank, off, list, n);

    k_l4<<<nb64, 256, 0, stream>>>(z3, list, w4, b4, a3, c3, z4, n);

    k_gpool<<<dim3(23, 120, 2), 256, 0, stream>>>(cnt, off, z4, (float*)d_out);

    k_res<<<(NBd*2*GXY + 255) / 256, 256, 0, stream>>>(pres, (float*)d_out);
}

// Round 17
// 685.140 us; speedup vs baseline: 1.1625x; 1.0123x over previous
//
#include <hip/hip_runtime.h>
#include <cstdint>
#include <cstddef>

#define GXd 480
#define GYd 360
#define NBd 2
#define GXY (480*360)
#define NCELL (NBd*GXY)
#define EPSBN 1e-5f

typedef float  f32x4  __attribute__((ext_vector_type(4)));
typedef short  bf16x8 __attribute__((ext_vector_type(8)));

// ---------- order-preserving float <-> uint map (residual atomics only) ----------
__device__ __forceinline__ unsigned mapf(float f){
    unsigned u = __float_as_uint(f);
    return (u & 0x80000000u) ? ~u : (u | 0x80000000u);
}
__device__ __forceinline__ float unmapf(unsigned m){
    return (m & 0x80000000u) ? __uint_as_float(m ^ 0x80000000u)
                             : __uint_as_float(~m);
}

// ---------- bf16 helpers (RTN-even) ----------
__device__ __forceinline__ unsigned short f2bf(float f){
    unsigned u = __float_as_uint(f);
    unsigned r = (u + 0x7FFFu + ((u >> 16) & 1u)) >> 16;
    return (unsigned short)r;
}
__device__ __forceinline__ float bf2f(unsigned short s){
    return __uint_as_float(((unsigned)s) << 16);
}

// ---------- dense layer helper ----------
template<int DIN, int DOUT>
__device__ __forceinline__ void dense(const float (&in)[DIN], float (&out)[DOUT],
                                      const float* __restrict__ w,
                                      const float* __restrict__ b){
#pragma unroll
    for (int j = 0; j < DOUT; j++) out[j] = b[j];
#pragma unroll
    for (int d = 0; d < DIN; d++){
        float v = in[d];
#pragma unroll
        for (int j = 0; j < DOUT; j++) out[j] = fmaf(v, w[d*DOUT + j], out[j]);
    }
}

// ---------- block-level sum/sumsq reduction ----------
template<int D>
__device__ __forceinline__ void reduce_stats(const float (&h)[D], bool valid,
                                             float* __restrict__ gsum,
                                             float* __restrict__ gsq){
    __shared__ float ssum[D];
    __shared__ float ssq[D];
    int tid = threadIdx.x;
    for (int t = tid; t < D; t += 256){ ssum[t] = 0.f; ssq[t] = 0.f; }
    __syncthreads();
#pragma unroll
    for (int j = 0; j < D; j++){
        float v = valid ? h[j] : 0.f;
        float s = v * v;
#pragma unroll
        for (int o = 32; o > 0; o >>= 1){
            v += __shfl_down(v, o, 64);
            s += __shfl_down(s, o, 64);
        }
        if ((tid & 63) == 0){
            atomicAdd(&ssum[j], v);
            atomicAdd(&ssq[j], s);
        }
    }
    __syncthreads();
    for (int t = tid; t < D; t += 256){
        atomicAdd(&gsum[t], ssum[t]);
        atomicAdd(&gsq[t], ssq[t]);
    }
}

// ---------- stats of raw input columns 0..8 ----------
__global__ __launch_bounds__(256)
void k_stats0(const float* __restrict__ fea, float* gsum, float* gsq, int n){
    int i = blockIdx.x*256 + threadIdx.x;
    bool valid = i < n;
    int i2 = valid ? i : 0;
    float x[9];
#pragma unroll
    for (int d = 0; d < 9; d++) x[d] = fea[(size_t)i2*11 + d];
    reduce_stats<9>(x, valid, gsum, gsq);
}

// ---------- finalize BN ----------
__global__ void k_fin(const float* __restrict__ sum, const float* __restrict__ sq,
                      const float* __restrict__ g, const float* __restrict__ bb,
                      float* __restrict__ a_out, float* __restrict__ c_out,
                      int D, float invN){
    int t = threadIdx.x;
    if (t < D){
        float mu  = sum[t] * invN;
        float var = fmaf(-mu, mu, sq[t] * invN);
        float rs  = rsqrtf(var + EPSBN);
        float a   = rs * g[t];
        a_out[t] = a;
        c_out[t] = fmaf(-mu, a, bb[t]);
    }
}

// ---------- layer1: bn0 -> 9x32; z1; stats; voxel count+rank; res atomics ----------
__global__ __launch_bounds__(256)
void k_l1(const float* __restrict__ fea, const int* __restrict__ ind,
          const float* __restrict__ w1, const float* __restrict__ b1,
          const float* __restrict__ a0, const float* __restrict__ c0,
          float* __restrict__ z1, unsigned* __restrict__ pres,
          unsigned* __restrict__ cnt, unsigned* __restrict__ rank,
          float* gsum, float* gsq, int n){
    int i = blockIdx.x*256 + threadIdx.x;
    bool valid = i < n;
    int i2 = valid ? i : 0;
    float x[9];
#pragma unroll
    for (int d = 0; d < 9; d++) x[d] = fmaf(fea[(size_t)i2*11 + d], a0[d], c0[d]);
    float h[32];
    dense<9,32>(x, h, w1, b1);
    if (valid){
        float4* dst = (float4*)(z1 + (size_t)i*32);
#pragma unroll
        for (int q = 0; q < 8; q++)
            dst[q] = make_float4(h[q*4], h[q*4+1], h[q*4+2], h[q*4+3]);
        float r0 = fea[(size_t)i*11 + 9];
        float r1 = fea[(size_t)i*11 + 10];
        int bb = ind[(size_t)i*3 + 0];
        int gx = ind[(size_t)i*3 + 1];
        int gy = ind[(size_t)i*3 + 2];
        unsigned vox = ((unsigned)bb*GXd + (unsigned)gx)*GYd + (unsigned)gy;
        rank[i] = atomicAdd(&cnt[vox], 1u);
        size_t rbase = (size_t)bb*2*GXY + (size_t)gx*GYd + gy;
        atomicMax(pres + rbase,       mapf(r0));
        atomicMax(pres + rbase + GXY, mapf(r1));
    }
    reduce_stats<32>(h, valid, gsum, gsq);
}

// ---------- layer2 via MFMA: z2[n x 64] = bn1relu(z1)[n x 32] @ w2 ----------
__global__ __launch_bounds__(256)
void k_l2(const float* __restrict__ z1,
          const float* __restrict__ w2, const float* __restrict__ b2,
          const float* __restrict__ a1, const float* __restrict__ c1,
          float* __restrict__ z2, float* gsum, float* gsq, int n){
    __shared__ short w2t[64*40];             // 5120 B
    __shared__ float ssum[64], ssq[64];
    int tid = threadIdx.x;
    if (tid < 64){ ssum[tid] = 0.f; ssq[tid] = 0.f; }
    for (int e = tid; e < 2048; e += 256){
        int k = e >> 6, c = e & 63;
        w2t[c*40 + k] = (short)f2bf(w2[k*64 + c]);
    }
    __syncthreads();

    int lane = tid & 63, wid = tid >> 6;
    int l15 = lane & 15, lg = lane >> 4;
    int p0 = blockIdx.x*64 + wid*16;
    int prow = p0 + l15;
    int prow2 = prow < n ? prow : (n - 1);
    const float* zrow = z1 + (size_t)prow2*32;

    int kbase = lg*8;
    float4 v0 = *(const float4*)(zrow + kbase);
    float4 v1 = *(const float4*)(zrow + kbase + 4);
    float4 av0 = *(const float4*)(a1 + kbase);
    float4 av1 = *(const float4*)(a1 + kbase + 4);
    float4 cv0 = *(const float4*)(c1 + kbase);
    float4 cv1 = *(const float4*)(c1 + kbase + 4);
    bf16x8 af;
    af[0] = (short)f2bf(fmaxf(fmaf(v0.x, av0.x, cv0.x), 0.f));
    af[1] = (short)f2bf(fmaxf(fmaf(v0.y, av0.y, cv0.y), 0.f));
    af[2] = (short)f2bf(fmaxf(fmaf(v0.z, av0.z, cv0.z), 0.f));
    af[3] = (short)f2bf(fmaxf(fmaf(v0.w, av0.w, cv0.w), 0.f));
    af[4] = (short)f2bf(fmaxf(fmaf(v1.x, av1.x, cv1.x), 0.f));
    af[5] = (short)f2bf(fmaxf(fmaf(v1.y, av1.y, cv1.y), 0.f));
    af[6] = (short)f2bf(fmaxf(fmaf(v1.z, av1.z, cv1.z), 0.f));
    af[7] = (short)f2bf(fmaxf(fmaf(v1.w, av1.w, cv1.w), 0.f));

    f32x4 acc[4];
#pragma unroll
    for (int t = 0; t < 4; t++){
        float bv = b2[t*16 + l15];
        acc[t] = (f32x4){bv, bv, bv, bv};
    }
#pragma unroll
    for (int t = 0; t < 4; t++){
        bf16x8 bf = *(const bf16x8*)&w2t[(t*16 + l15)*40 + kbase];
        acc[t] = __builtin_amdgcn_mfma_f32_16x16x32_bf16(af, bf, acc[t], 0, 0, 0);
    }

#pragma unroll
    for (int t = 0; t < 4; t++){
        int c = t*16 + l15;
        float s = 0.f, q = 0.f;
#pragma unroll
        for (int r = 0; r < 4; r++){
            int pr = p0 + lg*4 + r;
            float v = acc[t][r];
            if (pr < n){
                z2[(size_t)pr*64 + c] = v;
                s += v; q += v*v;
            }
        }
        s += __shfl_xor(s, 16, 64);  q += __shfl_xor(q, 16, 64);
        s += __shfl_xor(s, 32, 64);  q += __shfl_xor(q, 32, 64);
        if (lg == 0){ atomicAdd(&ssum[c], s); atomicAdd(&ssq[c], q); }
    }
    __syncthreads();
    if (tid < 64){ atomicAdd(gsum + tid, ssum[tid]); atomicAdd(gsq + tid, ssq[tid]); }
}

// ---------- layer3 via MFMA: z3[n x 128] = bn2relu(z2)[n x 64] @ w3 (bf16 out) ----------
__global__ __launch_bounds__(256)
void k_l3(const float* __restrict__ z2,
          const float* __restrict__ w3, const float* __restrict__ b3,
          const float* __restrict__ a2, const float* __restrict__ c2,
          unsigned short* __restrict__ z3, float* gsum, float* gsq, int n){
    __shared__ short w3t[128*72];            // 18432 B, [c][k] stride 72
    __shared__ float ssum[128], ssq[128];
    int tid = threadIdx.x;
    if (tid < 128){ ssum[tid] = 0.f; ssq[tid] = 0.f; }
    for (int e = tid; e < 8192; e += 256){
        int k = e >> 7, c = e & 127;
        w3t[c*72 + k] = (short)f2bf(w3[k*128 + c]);
    }
    __syncthreads();

    int lane = tid & 63, wid = tid >> 6;
    int l15 = lane & 15, lg = lane >> 4;
    int p0 = blockIdx.x*64 + wid*16;
    int prow = p0 + l15;
    int prow2 = prow < n ? prow : (n - 1);
    const float* zrow = z2 + (size_t)prow2*64;

    f32x4 acc[8];
#pragma unroll
    for (int t = 0; t < 8; t++){
        float bv = b3[t*16 + l15];
        acc[t] = (f32x4){bv, bv, bv, bv};
    }

#pragma unroll
    for (int ks = 0; ks < 2; ks++){
        int kbase = ks*32 + lg*8;
        float4 v0 = *(const float4*)(zrow + kbase);
        float4 v1 = *(const float4*)(zrow + kbase + 4);
        float4 av0 = *(const float4*)(a2 + kbase);
        float4 av1 = *(const float4*)(a2 + kbase + 4);
        float4 cv0 = *(const float4*)(c2 + kbase);
        float4 cv1 = *(const float4*)(c2 + kbase + 4);
        bf16x8 af;
        af[0] = (short)f2bf(fmaxf(fmaf(v0.x, av0.x, cv0.x), 0.f));
        af[1] = (short)f2bf(fmaxf(fmaf(v0.y, av0.y, cv0.y), 0.f));
        af[2] = (short)f2bf(fmaxf(fmaf(v0.z, av0.z, cv0.z), 0.f));
        af[3] = (short)f2bf(fmaxf(fmaf(v0.w, av0.w, cv0.w), 0.f));
        af[4] = (short)f2bf(fmaxf(fmaf(v1.x, av1.x, cv1.x), 0.f));
        af[5] = (short)f2bf(fmaxf(fmaf(v1.y, av1.y, cv1.y), 0.f));
        af[6] = (short)f2bf(fmaxf(fmaf(v1.z, av1.z, cv1.z), 0.f));
        af[7] = (short)f2bf(fmaxf(fmaf(v1.w, av1.w, cv1.w), 0.f));
#pragma unroll
        for (int t = 0; t < 8; t++){
            bf16x8 bf = *(const bf16x8*)&w3t[(t*16 + l15)*72 + kbase];
            acc[t] = __builtin_amdgcn_mfma_f32_16x16x32_bf16(af, bf, acc[t], 0, 0, 0);
        }
    }

#pragma unroll
    for (int t = 0; t < 8; t++){
        int c = t*16 + l15;
        float s = 0.f, q = 0.f;
#pragma unroll
        for (int r = 0; r < 4; r++){
            int pr = p0 + lg*4 + r;
            unsigned short rb = f2bf(acc[t][r]);
            float rv = bf2f(rb);
            if (pr < n){
                z3[(size_t)pr*128 + c] = rb;
                s += rv; q += rv*rv;
            }
        }
        s += __shfl_xor(s, 16, 64);  q += __shfl_xor(q, 16, 64);
        s += __shfl_xor(s, 32, 64);  q += __shfl_xor(q, 32, 64);
        if (lg == 0){ atomicAdd(&ssum[c], s); atomicAdd(&ssq[c], q); }
    }
    __syncthreads();
    if (tid < 128){ atomicAdd(gsum + tid, ssum[tid]); atomicAdd(gsq + tid, ssq[tid]); }
}

// ---------- exclusive scan of cnt via block tickets ----------
__global__ __launch_bounds__(256)
void k_off(const unsigned* __restrict__ cnt, unsigned* __restrict__ off,
           unsigned* __restrict__ gctr){
    __shared__ unsigned wtot[4];
    __shared__ unsigned wbase[4];
    int t = threadIdx.x;
    int lane = t & 63, w = t >> 6;
    int base = blockIdx.x * 1024 + t * 4;
    bool ok = base < NCELL;
    unsigned c0 = 0, c1 = 0, c2 = 0, c3 = 0;
    if (ok){ c0 = cnt[base]; c1 = cnt[base+1]; c2 = cnt[base+2]; c3 = cnt[base+3]; }
    unsigned tot = c0 + c1 + c2 + c3;
    unsigned incl = tot;
#pragma unroll
    for (int o = 1; o < 64; o <<= 1){
        unsigned v = __shfl_up(incl, o, 64);
        if (lane >= o) incl += v;
    }
    if (lane == 63) wtot[w] = incl;
    __syncthreads();
    if (t == 0){
        unsigned bt = wtot[0] + wtot[1] + wtot[2] + wtot[3];
        unsigned gb = atomicAdd(gctr, bt);
        unsigned s = 0;
#pragma unroll
        for (int q = 0; q < 4; q++){ wbase[q] = gb + s; s += wtot[q]; }
    }
    __syncthreads();
    if (ok){
        unsigned tb = wbase[w] + incl - tot;
        off[base]   = tb;
        off[base+1] = tb + c0;
        off[base+2] = tb + c0 + c1;
        off[base+3] = tb + c0 + c1 + c2;
    }
}

// ---------- fill per-cell point lists ----------
__global__ __launch_bounds__(256)
void k_fill(const int* __restrict__ ind, const unsigned* __restrict__ rank,
            const unsigned* __restrict__ off, unsigned* __restrict__ list, int n){
    int i = blockIdx.x*256 + threadIdx.x;
    if (i >= n) return;
    int bb = ind[(size_t)i*3], gx = ind[(size_t)i*3+1], gy = ind[(size_t)i*3+2];
    unsigned vox = ((unsigned)bb*GXd + (unsigned)gx)*GYd + (unsigned)gy;
    list[off[vox] + rank[i]] = (unsigned)i;
}

// ---------- layer4 via MFMA, SORTED output: z4[sorted_pos] = bn3relu(z3[list[pos]]) @ w4 ----------
__global__ __launch_bounds__(256)
void k_l4(const unsigned short* __restrict__ z3, const unsigned* __restrict__ list,
          const float* __restrict__ w4, const float* __restrict__ b4,
          const float* __restrict__ a3, const float* __restrict__ c3,
          unsigned short* __restrict__ z4, int n){
    __shared__ short w4t[256*128];           // 64 KB: bf16 w4^T [c][k], swizzled
    int tid = threadIdx.x;
    for (int e = tid; e < 16384; e += 256){
        int k2 = e >> 8;
        int c  = e & 255;
        unsigned lo = f2bf(w4[(size_t)(2*k2)*256 + c]);
        unsigned hi = f2bf(w4[(size_t)(2*k2+1)*256 + c]);
        int addr = (c*256 + k2*4) ^ ((c & 7) << 4);
        *(unsigned*)((char*)w4t + addr) = lo | (hi << 16);
    }
    __syncthreads();

    int lane = tid & 63, wid = tid >> 6;
    int l15 = lane & 15, lg = lane >> 4;
    int p0 = blockIdx.x*64 + wid*16;
    int prow = p0 + l15;
    int prow2 = prow < n ? prow : (n - 1);
    int srow = (int)list[prow2];             // original point id (sorted by cell)
    const unsigned short* zrow = z3 + (size_t)srow*128;

    f32x4 acc[16];
#pragma unroll
    for (int t = 0; t < 16; t++){
        float bv = b4[t*16 + l15];
        acc[t] = (f32x4){bv, bv, bv, bv};
    }

#pragma unroll
    for (int ks = 0; ks < 4; ks++){
        int kbase = ks*32 + lg*8;
        uint4 ua = *(const uint4*)(zrow + kbase);
        float4 av0 = *(const float4*)(a3 + kbase);
        float4 av1 = *(const float4*)(a3 + kbase + 4);
        float4 cv0 = *(const float4*)(c3 + kbase);
        float4 cv1 = *(const float4*)(c3 + kbase + 4);
        bf16x8 af;
        af[0] = (short)f2bf(fmaxf(fmaf(bf2f((unsigned short)(ua.x & 0xFFFFu)), av0.x, cv0.x), 0.f));
        af[1] = (short)f2bf(fmaxf(fmaf(bf2f((unsigned short)(ua.x >> 16)),     av0.y, cv0.y), 0.f));
        af[2] = (short)f2bf(fmaxf(fmaf(bf2f((unsigned short)(ua.y & 0xFFFFu)), av0.z, cv0.z), 0.f));
        af[3] = (short)f2bf(fmaxf(fmaf(bf2f((unsigned short)(ua.y >> 16)),     av0.w, cv0.w), 0.f));
        af[4] = (short)f2bf(fmaxf(fmaf(bf2f((unsigned short)(ua.z & 0xFFFFu)), av1.x, cv1.x), 0.f));
        af[5] = (short)f2bf(fmaxf(fmaf(bf2f((unsigned short)(ua.z >> 16)),     av1.y, cv1.y), 0.f));
        af[6] = (short)f2bf(fmaxf(fmaf(bf2f((unsigned short)(ua.w & 0xFFFFu)), av1.z, cv1.z), 0.f));
        af[7] = (short)f2bf(fmaxf(fmaf(bf2f((unsigned short)(ua.w >> 16)),     av1.w, cv1.w), 0.f));
#pragma unroll
        for (int t = 0; t < 16; t++){
            int c = t*16 + l15;
            int addr = (c*256 + kbase*2) ^ ((c & 7) << 4);
            bf16x8 bf = *(const bf16x8*)((const char*)w4t + addr);
            acc[t] = __builtin_amdgcn_mfma_f32_16x16x32_bf16(af, bf, acc[t], 0, 0, 0);
        }
    }

#pragma unroll
    for (int t = 0; t < 16; t++){
#pragma unroll
        for (int r = 0; r < 4; r++){
            int pr = p0 + lg*4 + r;
            if (pr < n)
                z4[(size_t)pr*256 + t*16 + l15] = f2bf(acc[t][r]);
        }
    }
}

// ---------- FUSED gather-max + 3x3 maxpool, CHANNEL-SPLIT (128 ch/block) ----------
// blockIdx.z = b*2 + chalf. LDS 27.6 KB -> ~5 blocks/CU. Staging: wave-per-cell,
// 4 cells in flight (4 independent uint-load chains, 1 KB/wave-step). Phase 2:
// thread=(c in 128, gpair in 2), register buffer ob[2][16], full-line writes.
#define NOCELL 0xFFFFFFFFu
__global__ __launch_bounds__(256)
void k_gpool(const unsigned* __restrict__ cnt, const unsigned* __restrict__ off,
             const unsigned short* __restrict__ z4, float* __restrict__ out){
    __shared__ unsigned short cm[6*18*128];   // 27648 B: [xx][ty][c] cell maxes
    __shared__ unsigned cno[216];             // [e]{cnt,off}
    int t = threadIdx.x;
    int gy0 = blockIdx.x * 16;
    int gx0 = blockIdx.y * 4;
    int bz  = blockIdx.z;
    int b   = bz >> 1;
    int ch0 = (bz & 1) * 128;

    // stage cnt/off for the 108 halo cells
    for (int e = t; e < 108; e += 256){
        int xx = e / 18, ty = e % 18;
        int gxx = gx0 - 1 + xx, gyy = gy0 - 1 + ty;
        unsigned c = NOCELL, o = 0;
        if ((unsigned)gxx < (unsigned)GXd && (unsigned)gyy < (unsigned)GYd){
            unsigned cell = ((unsigned)b*GXd + gxx)*GYd + gyy;
            c = cnt[cell]; o = off[cell];
        }
        cno[e*2]   = c;
        cno[e*2+1] = o;
    }
    __syncthreads();

    int lane = t & 63, wid = t >> 6;
    const float NEGINF = -__builtin_inff();
    for (int e = wid; e < 108; e += 16){
        unsigned cn_[4], o_[4], n_[4];
#pragma unroll
        for (int k = 0; k < 4; k++){
            int ek = e + k*4;
            bool hv = ek < 108;
            unsigned cc = hv ? cno[ek*2]   : NOCELL;
            unsigned oo = hv ? cno[ek*2+1] : 0;
            cn_[k] = cc;  o_[k] = oo;
            n_[k] = (cc == NOCELL) ? 0u : cc;
        }
        float m0[4], m1[4];
#pragma unroll
        for (int k = 0; k < 4; k++){ m0[k] = NEGINF; m1[k] = NEGINF; }
        unsigned nm = 0;
#pragma unroll
        for (int k = 0; k < 4; k++) nm = nm > n_[k] ? nm : n_[k];
        for (unsigned p = 0; p < nm; p++){
#pragma unroll
            for (int k = 0; k < 4; k++){
                if (p < n_[k]){
                    unsigned u = *(const unsigned*)(z4 + (size_t)(o_[k] + p)*256 + ch0 + lane*2);
                    m0[k] = fmaxf(m0[k], bf2f((unsigned short)(u & 0xFFFFu)));
                    m1[k] = fmaxf(m1[k], bf2f((unsigned short)(u >> 16)));
                }
            }
        }
#pragma unroll
        for (int k = 0; k < 4; k++){
            int ek = e + k*4;
            if (ek < 108){
                float a0 = m0[k], a1 = m1[k];
                if (cn_[k] == 0u){ a0 = 0.f; a1 = 0.f; }
                *(unsigned*)&cm[ek*128 + lane*2] =
                    (unsigned)f2bf(a0) | ((unsigned)f2bf(a1) << 16);
            }
        }
    }
    __syncthreads();

    // phase 2: thread = (c in 0..127, gpair); register buffer then full-line writes
    int c  = t & 127;
    int gp = t >> 7;                           // 0/1 -> g = gp*2 + {0,1}
    int ymax = GYd - gy0; if (ymax > 16) ymax = 16;   // 16 or 8
    float rA[2], rB[2];
    float ob[2][16];
#pragma unroll
    for (int gg = 0; gg < 2; gg++){ rA[gg] = 0.f; rB[gg] = 0.f; }
#pragma unroll
    for (int ty = 0; ty < 18; ty++){
        float v[6];
#pragma unroll
        for (int xx = 0; xx < 6; xx++)
            v[xx] = bf2f(cm[(xx*18 + ty)*128 + c]);
        float c3[2];
#pragma unroll
        for (int gg = 0; gg < 2; gg++){
            float va = (gp == 0) ? v[gg]     : v[gg+2];
            float vb = (gp == 0) ? v[gg+1]   : v[gg+3];
            float vc = (gp == 0) ? v[gg+2]   : v[gg+4];
            c3[gg] = fmaxf(fmaxf(va, vb), vc);
        }
        if (ty >= 2){
#pragma unroll
            for (int gg = 0; gg < 2; gg++)
                ob[gg][ty - 2] = fmaxf(fmaxf(rA[gg], rB[gg]), c3[gg]);
        }
#pragma unroll
        for (int gg = 0; gg < 2; gg++){ rA[gg] = rB[gg]; rB[gg] = c3[gg]; }
    }
    int qmax = ymax >> 2;                     // 4 or 2
#pragma unroll
    for (int gg = 0; gg < 2; gg++){
        int g = gp*2 + gg;
        float* dst = out + ((size_t)b*258 + ch0 + c)*GXY + (size_t)(gx0+g)*GYd + gy0;
#pragma unroll
        for (int q = 0; q < 4; q++){
            if (q < qmax)
                *(float4*)(dst + q*4) = make_float4(ob[gg][q*4+0], ob[gg][q*4+1],
                                                    ob[gg][q*4+2], ob[gg][q*4+3]);
        }
    }
}

// ---------- residual channels ----------
__global__ __launch_bounds__(256)
void k_res(const unsigned* __restrict__ pres, float* __restrict__ out){
    int idx = blockIdx.x*256 + threadIdx.x;
    const int total = NBd*2*GXY;
    if (idx >= total) return;
    int gy = idx % GYd;
    int t  = idx / GYd;
    int gx = t % GXd;  t /= GXd;
    int r  = t & 1;
    int b  = t >> 1;
    unsigned u = pres[idx];
    float f = u ? unmapf(u) : 0.f;
    out[(((size_t)b*258 + 256 + r)*GXd + gx)*GYd + gy] = f;
}

extern "C" void kernel_launch(void* const* d_in, const int* in_sizes, int n_in,
                              void* d_out, int out_size, void* d_ws, size_t ws_size,
                              hipStream_t stream){
    (void)n_in; (void)out_size; (void)ws_size;
    const float* fea   = (const float*)d_in[0];
    const int*   ind   = (const int*)  d_in[1];
    const float* bn0_g = (const float*)d_in[2];
    const float* bn0_b = (const float*)d_in[3];
    const float* w1    = (const float*)d_in[4];
    const float* b1    = (const float*)d_in[5];
    const float* bn1_g = (const float*)d_in[6];
    const float* bn1_b = (const float*)d_in[7];
    const float* w2    = (const float*)d_in[8];
    const float* b2    = (const float*)d_in[9];
    const float* bn2_g = (const float*)d_in[10];
    const float* bn2_b = (const float*)d_in[11];
    const float* w3    = (const float*)d_in[12];
    const float* b3    = (const float*)d_in[13];
    const float* bn3_g = (const float*)d_in[14];
    const float* bn3_b = (const float*)d_in[15];
    const float* w4    = (const float*)d_in[16];
    const float* b4    = (const float*)d_in[17];

    int n = in_sizes[0] / 11;
    float invN = 1.0f / (float)n;

    // ---- ws layout ----
    const size_t Z4_B     = (size_t)240000*256*2;       // 122,880,000
    const size_t POOL_B   = (size_t)NCELL*256*2;        // 176,947,200 (z1/z2/z3 arena)
    const size_t PRES_B   = (size_t)NBd*2*GXY*4;        //   5,529,600
    const size_t CNT_B    = (size_t)NCELL*4;            //   2,764,800
    const size_t STAT_B   = 960*4;
    const size_t GCTR_B   = 256;

    char* base = (char*)d_ws;
    unsigned short* z4 = (unsigned short*)base;
    float*          z1 = (float*)(base + Z4_B);
    float*          z2 = (float*)(base + Z4_B + 30720000);
    unsigned short* z3 = (unsigned short*)(base + Z4_B + 92160000);
    unsigned* pres  = (unsigned*)(base + Z4_B + POOL_B);
    unsigned* cnt   = (unsigned*)((char*)pres + PRES_B);
    float*    stats = (float*)((char*)cnt + CNT_B);
    unsigned* gctr  = (unsigned*)((char*)stats + STAT_B);
    unsigned* off   = (unsigned*)((char*)gctr + GCTR_B);
    unsigned* list  = (unsigned*)((char*)off + CNT_B);
    unsigned* rank  = (unsigned*)((char*)list + (size_t)240000*4);

    float* sum0 = stats;       float* sq0 = stats + 16;
    float* sum1 = stats + 32;  float* sq1 = stats + 64;
    float* sum2 = stats + 96;  float* sq2 = stats + 160;
    float* sum3 = stats + 224; float* sq3 = stats + 352;
    float* a0 = stats + 480;   float* c0 = stats + 496;
    float* a1 = stats + 512;   float* c1 = stats + 544;
    float* a2 = stats + 576;   float* c2 = stats + 640;
    float* a3 = stats + 704;   float* c3 = stats + 832;

    hipMemsetAsync(pres, 0, PRES_B + CNT_B + STAT_B + GCTR_B, stream);

    int nb = (n + 255) / 256;
    int nb64 = (n + 63) / 64;
    k_stats0<<<nb, 256, 0, stream>>>(fea, sum0, sq0, n);
    k_fin<<<1, 128, 0, stream>>>(sum0, sq0, bn0_g, bn0_b, a0, c0, 9,  invN);
    k_l1<<<nb, 256, 0, stream>>>(fea, ind, w1, b1, a0, c0, z1, pres, cnt, rank, sum1, sq1, n);
    k_fin<<<1, 128, 0, stream>>>(sum1, sq1, bn1_g, bn1_b, a1, c1, 32, invN);
    k_l2<<<nb64, 256, 0, stream>>>(z1, w2, b2, a1, c1, z2, sum2, sq2, n);
    k_fin<<<1, 128, 0, stream>>>(sum2, sq2, bn2_g, bn2_b, a2, c2, 64, invN);
    k_l3<<<nb64, 256, 0, stream>>>(z2, w3, b3, a2, c2, z3, sum3, sq3, n);
    k_fin<<<1, 128, 0, stream>>>(sum3, sq3, bn3_g, bn3_b, a3, c3, 128, invN);

    k_off <<<(NCELL + 1023)/1024, 256, 0, stream>>>(cnt, off, gctr);
    k_fill<<<nb, 256, 0, stream>>>(ind, rank, off, list, n);

    k_l4<<<nb64, 256, 0, stream>>>(z3, list, w4, b4, a3, c3, z4, n);

    k_gpool<<<dim3(23, 120, 4), 256, 0, stream>>>(cnt, off, z4, (float*)d_out);

    k_res<<<(NBd*2*GXY + 255) / 256, 256, 0, stream>>>(pres, (float*)d_out);
}

// Round 18
// 640.746 us; speedup vs baseline: 1.2431x; 1.0693x over previous
//
#include <hip/hip_runtime.h>
#include <cstdint>
#include <cstddef>

#define GXd 480
#define GYd 360
#define NBd 2
#define GXY (480*360)
#define NCELL (NBd*GXY)
#define EPSBN 1e-5f

typedef float  f32x4  __attribute__((ext_vector_type(4)));
typedef short  bf16x8 __attribute__((ext_vector_type(8)));

// ---------- order-preserving float <-> uint map (residual atomics only) ----------
__device__ __forceinline__ unsigned mapf(float f){
    unsigned u = __float_as_uint(f);
    return (u & 0x80000000u) ? ~u : (u | 0x80000000u);
}
__device__ __forceinline__ float unmapf(unsigned m){
    return (m & 0x80000000u) ? __uint_as_float(m ^ 0x80000000u)
                             : __uint_as_float(~m);
}

// ---------- bf16 helpers (RTN-even) ----------
__device__ __forceinline__ unsigned short f2bf(float f){
    unsigned u = __float_as_uint(f);
    unsigned r = (u + 0x7FFFu + ((u >> 16) & 1u)) >> 16;
    return (unsigned short)r;
}
__device__ __forceinline__ float bf2f(unsigned short s){
    return __uint_as_float(((unsigned)s) << 16);
}

// ---------- dense layer helper ----------
template<int DIN, int DOUT>
__device__ __forceinline__ void dense(const float (&in)[DIN], float (&out)[DOUT],
                                      const float* __restrict__ w,
                                      const float* __restrict__ b){
#pragma unroll
    for (int j = 0; j < DOUT; j++) out[j] = b[j];
#pragma unroll
    for (int d = 0; d < DIN; d++){
        float v = in[d];
#pragma unroll
        for (int j = 0; j < DOUT; j++) out[j] = fmaf(v, w[d*DOUT + j], out[j]);
    }
}

// ---------- block-level sum/sumsq reduction ----------
template<int D>
__device__ __forceinline__ void reduce_stats(const float (&h)[D], bool valid,
                                             float* __restrict__ gsum,
                                             float* __restrict__ gsq){
    __shared__ float ssum[D];
    __shared__ float ssq[D];
    int tid = threadIdx.x;
    for (int t = tid; t < D; t += 256){ ssum[t] = 0.f; ssq[t] = 0.f; }
    __syncthreads();
#pragma unroll
    for (int j = 0; j < D; j++){
        float v = valid ? h[j] : 0.f;
        float s = v * v;
#pragma unroll
        for (int o = 32; o > 0; o >>= 1){
            v += __shfl_down(v, o, 64);
            s += __shfl_down(s, o, 64);
        }
        if ((tid & 63) == 0){
            atomicAdd(&ssum[j], v);
            atomicAdd(&ssq[j], s);
        }
    }
    __syncthreads();
    for (int t = tid; t < D; t += 256){
        atomicAdd(&gsum[t], ssum[t]);
        atomicAdd(&gsq[t], ssq[t]);
    }
}

// ---------- stats of raw input columns 0..8 ----------
__global__ __launch_bounds__(256)
void k_stats0(const float* __restrict__ fea, float* gsum, float* gsq, int n){
    int i = blockIdx.x*256 + threadIdx.x;
    bool valid = i < n;
    int i2 = valid ? i : 0;
    float x[9];
#pragma unroll
    for (int d = 0; d < 9; d++) x[d] = fea[(size_t)i2*11 + d];
    reduce_stats<9>(x, valid, gsum, gsq);
}

// ---------- finalize BN ----------
__global__ void k_fin(const float* __restrict__ sum, const float* __restrict__ sq,
                      const float* __restrict__ g, const float* __restrict__ bb,
                      float* __restrict__ a_out, float* __restrict__ c_out,
                      int D, float invN){
    int t = threadIdx.x;
    if (t < D){
        float mu  = sum[t] * invN;
        float var = fmaf(-mu, mu, sq[t] * invN);
        float rs  = rsqrtf(var + EPSBN);
        float a   = rs * g[t];
        a_out[t] = a;
        c_out[t] = fmaf(-mu, a, bb[t]);
    }
}

// ---------- layer1: bn0 -> 9x32; z1; stats; voxel count+rank; res atomics ----------
__global__ __launch_bounds__(256)
void k_l1(const float* __restrict__ fea, const int* __restrict__ ind,
          const float* __restrict__ w1, const float* __restrict__ b1,
          const float* __restrict__ a0, const float* __restrict__ c0,
          float* __restrict__ z1, unsigned* __restrict__ pres,
          unsigned* __restrict__ cnt, unsigned* __restrict__ rank,
          float* gsum, float* gsq, int n){
    int i = blockIdx.x*256 + threadIdx.x;
    bool valid = i < n;
    int i2 = valid ? i : 0;
    float x[9];
#pragma unroll
    for (int d = 0; d < 9; d++) x[d] = fmaf(fea[(size_t)i2*11 + d], a0[d], c0[d]);
    float h[32];
    dense<9,32>(x, h, w1, b1);
    if (valid){
        float4* dst = (float4*)(z1 + (size_t)i*32);
#pragma unroll
        for (int q = 0; q < 8; q++)
            dst[q] = make_float4(h[q*4], h[q*4+1], h[q*4+2], h[q*4+3]);
        float r0 = fea[(size_t)i*11 + 9];
        float r1 = fea[(size_t)i*11 + 10];
        int bb = ind[(size_t)i*3 + 0];
        int gx = ind[(size_t)i*3 + 1];
        int gy = ind[(size_t)i*3 + 2];
        unsigned vox = ((unsigned)bb*GXd + (unsigned)gx)*GYd + (unsigned)gy;
        rank[i] = atomicAdd(&cnt[vox], 1u);
        size_t rbase = (size_t)bb*2*GXY + (size_t)gx*GYd + gy;
        atomicMax(pres + rbase,       mapf(r0));
        atomicMax(pres + rbase + GXY, mapf(r1));
    }
    reduce_stats<32>(h, valid, gsum, gsq);
}

// ---------- layer2 via MFMA: z2[n x 64] = bn1relu(z1)[n x 32] @ w2 ----------
__global__ __launch_bounds__(256)
void k_l2(const float* __restrict__ z1,
          const float* __restrict__ w2, const float* __restrict__ b2,
          const float* __restrict__ a1, const float* __restrict__ c1,
          float* __restrict__ z2, float* gsum, float* gsq, int n){
    __shared__ short w2t[64*40];             // 5120 B
    __shared__ float ssum[64], ssq[64];
    int tid = threadIdx.x;
    if (tid < 64){ ssum[tid] = 0.f; ssq[tid] = 0.f; }
    for (int e = tid; e < 2048; e += 256){
        int k = e >> 6, c = e & 63;
        w2t[c*40 + k] = (short)f2bf(w2[k*64 + c]);
    }
    __syncthreads();

    int lane = tid & 63, wid = tid >> 6;
    int l15 = lane & 15, lg = lane >> 4;
    int p0 = blockIdx.x*64 + wid*16;
    int prow = p0 + l15;
    int prow2 = prow < n ? prow : (n - 1);
    const float* zrow = z1 + (size_t)prow2*32;

    int kbase = lg*8;
    float4 v0 = *(const float4*)(zrow + kbase);
    float4 v1 = *(const float4*)(zrow + kbase + 4);
    float4 av0 = *(const float4*)(a1 + kbase);
    float4 av1 = *(const float4*)(a1 + kbase + 4);
    float4 cv0 = *(const float4*)(c1 + kbase);
    float4 cv1 = *(const float4*)(c1 + kbase + 4);
    bf16x8 af;
    af[0] = (short)f2bf(fmaxf(fmaf(v0.x, av0.x, cv0.x), 0.f));
    af[1] = (short)f2bf(fmaxf(fmaf(v0.y, av0.y, cv0.y), 0.f));
    af[2] = (short)f2bf(fmaxf(fmaf(v0.z, av0.z, cv0.z), 0.f));
    af[3] = (short)f2bf(fmaxf(fmaf(v0.w, av0.w, cv0.w), 0.f));
    af[4] = (short)f2bf(fmaxf(fmaf(v1.x, av1.x, cv1.x), 0.f));
    af[5] = (short)f2bf(fmaxf(fmaf(v1.y, av1.y, cv1.y), 0.f));
    af[6] = (short)f2bf(fmaxf(fmaf(v1.z, av1.z, cv1.z), 0.f));
    af[7] = (short)f2bf(fmaxf(fmaf(v1.w, av1.w, cv1.w), 0.f));

    f32x4 acc[4];
#pragma unroll
    for (int t = 0; t < 4; t++){
        float bv = b2[t*16 + l15];
        acc[t] = (f32x4){bv, bv, bv, bv};
    }
#pragma unroll
    for (int t = 0; t < 4; t++){
        bf16x8 bf = *(const bf16x8*)&w2t[(t*16 + l15)*40 + kbase];
        acc[t] = __builtin_amdgcn_mfma_f32_16x16x32_bf16(af, bf, acc[t], 0, 0, 0);
    }

#pragma unroll
    for (int t = 0; t < 4; t++){
        int c = t*16 + l15;
        float s = 0.f, q = 0.f;
#pragma unroll
        for (int r = 0; r < 4; r++){
            int pr = p0 + lg*4 + r;
            float v = acc[t][r];
            if (pr < n){
                z2[(size_t)pr*64 + c] = v;
                s += v; q += v*v;
            }
        }
        s += __shfl_xor(s, 16, 64);  q += __shfl_xor(q, 16, 64);
        s += __shfl_xor(s, 32, 64);  q += __shfl_xor(q, 32, 64);
        if (lg == 0){ atomicAdd(&ssum[c], s); atomicAdd(&ssq[c], q); }
    }
    __syncthreads();
    if (tid < 64){ atomicAdd(gsum + tid, ssum[tid]); atomicAdd(gsq + tid, ssq[tid]); }
}

// ---------- layer3 via MFMA: z3[n x 128] = bn2relu(z2)[n x 64] @ w3 (bf16 out) ----------
__global__ __launch_bounds__(256)
void k_l3(const float* __restrict__ z2,
          const float* __restrict__ w3, const float* __restrict__ b3,
          const float* __restrict__ a2, const float* __restrict__ c2,
          unsigned short* __restrict__ z3, float* gsum, float* gsq, int n){
    __shared__ short w3t[128*72];            // 18432 B, [c][k] stride 72
    __shared__ float ssum[128], ssq[128];
    int tid = threadIdx.x;
    if (tid < 128){ ssum[tid] = 0.f; ssq[tid] = 0.f; }
    for (int e = tid; e < 8192; e += 256){
        int k = e >> 7, c = e & 127;
        w3t[c*72 + k] = (short)f2bf(w3[k*128 + c]);
    }
    __syncthreads();

    int lane = tid & 63, wid = tid >> 6;
    int l15 = lane & 15, lg = lane >> 4;
    int p0 = blockIdx.x*64 + wid*16;
    int prow = p0 + l15;
    int prow2 = prow < n ? prow : (n - 1);
    const float* zrow = z2 + (size_t)prow2*64;

    f32x4 acc[8];
#pragma unroll
    for (int t = 0; t < 8; t++){
        float bv = b3[t*16 + l15];
        acc[t] = (f32x4){bv, bv, bv, bv};
    }

#pragma unroll
    for (int ks = 0; ks < 2; ks++){
        int kbase = ks*32 + lg*8;
        float4 v0 = *(const float4*)(zrow + kbase);
        float4 v1 = *(const float4*)(zrow + kbase + 4);
        float4 av0 = *(const float4*)(a2 + kbase);
        float4 av1 = *(const float4*)(a2 + kbase + 4);
        float4 cv0 = *(const float4*)(c2 + kbase);
        float4 cv1 = *(const float4*)(c2 + kbase + 4);
        bf16x8 af;
        af[0] = (short)f2bf(fmaxf(fmaf(v0.x, av0.x, cv0.x), 0.f));
        af[1] = (short)f2bf(fmaxf(fmaf(v0.y, av0.y, cv0.y), 0.f));
        af[2] = (short)f2bf(fmaxf(fmaf(v0.z, av0.z, cv0.z), 0.f));
        af[3] = (short)f2bf(fmaxf(fmaf(v0.w, av0.w, cv0.w), 0.f));
        af[4] = (short)f2bf(fmaxf(fmaf(v1.x, av1.x, cv1.x), 0.f));
        af[5] = (short)f2bf(fmaxf(fmaf(v1.y, av1.y, cv1.y), 0.f));
        af[6] = (short)f2bf(fmaxf(fmaf(v1.z, av1.z, cv1.z), 0.f));
        af[7] = (short)f2bf(fmaxf(fmaf(v1.w, av1.w, cv1.w), 0.f));
#pragma unroll
        for (int t = 0; t < 8; t++){
            bf16x8 bf = *(const bf16x8*)&w3t[(t*16 + l15)*72 + kbase];
            acc[t] = __builtin_amdgcn_mfma_f32_16x16x32_bf16(af, bf, acc[t], 0, 0, 0);
        }
    }

#pragma unroll
    for (int t = 0; t < 8; t++){
        int c = t*16 + l15;
        float s = 0.f, q = 0.f;
#pragma unroll
        for (int r = 0; r < 4; r++){
            int pr = p0 + lg*4 + r;
            unsigned short rb = f2bf(acc[t][r]);
            float rv = bf2f(rb);
            if (pr < n){
                z3[(size_t)pr*128 + c] = rb;
                s += rv; q += rv*rv;
            }
        }
        s += __shfl_xor(s, 16, 64);  q += __shfl_xor(q, 16, 64);
        s += __shfl_xor(s, 32, 64);  q += __shfl_xor(q, 32, 64);
        if (lg == 0){ atomicAdd(&ssum[c], s); atomicAdd(&ssq[c], q); }
    }
    __syncthreads();
    if (tid < 128){ atomicAdd(gsum + tid, ssum[tid]); atomicAdd(gsq + tid, ssq[tid]); }
}

// ---------- exclusive scan of cnt via block tickets ----------
__global__ __launch_bounds__(256)
void k_off(const unsigned* __restrict__ cnt, unsigned* __restrict__ off,
           unsigned* __restrict__ gctr){
    __shared__ unsigned wtot[4];
    __shared__ unsigned wbase[4];
    int t = threadIdx.x;
    int lane = t & 63, w = t >> 6;
    int base = blockIdx.x * 1024 + t * 4;
    bool ok = base < NCELL;
    unsigned c0 = 0, c1 = 0, c2 = 0, c3 = 0;
    if (ok){ c0 = cnt[base]; c1 = cnt[base+1]; c2 = cnt[base+2]; c3 = cnt[base+3]; }
    unsigned tot = c0 + c1 + c2 + c3;
    unsigned incl = tot;
#pragma unroll
    for (int o = 1; o < 64; o <<= 1){
        unsigned v = __shfl_up(incl, o, 64);
        if (lane >= o) incl += v;
    }
    if (lane == 63) wtot[w] = incl;
    __syncthreads();
    if (t == 0){
        unsigned bt = wtot[0] + wtot[1] + wtot[2] + wtot[3];
        unsigned gb = atomicAdd(gctr, bt);
        unsigned s = 0;
#pragma unroll
        for (int q = 0; q < 4; q++){ wbase[q] = gb + s; s += wtot[q]; }
    }
    __syncthreads();
    if (ok){
        unsigned tb = wbase[w] + incl - tot;
        off[base]   = tb;
        off[base+1] = tb + c0;
        off[base+2] = tb + c0 + c1;
        off[base+3] = tb + c0 + c1 + c2;
    }
}

// ---------- fill per-cell point lists ----------
__global__ __launch_bounds__(256)
void k_fill(const int* __restrict__ ind, const unsigned* __restrict__ rank,
            const unsigned* __restrict__ off, unsigned* __restrict__ list, int n){
    int i = blockIdx.x*256 + threadIdx.x;
    if (i >= n) return;
    int bb = ind[(size_t)i*3], gx = ind[(size_t)i*3+1], gy = ind[(size_t)i*3+2];
    unsigned vox = ((unsigned)bb*GXd + (unsigned)gx)*GYd + (unsigned)gy;
    list[off[vox] + rank[i]] = (unsigned)i;
}

// ---------- layer4 via MFMA, SORTED output: z4[sorted_pos] = bn3relu(z3[list[pos]]) @ w4 ----------
__global__ __launch_bounds__(256)
void k_l4(const unsigned short* __restrict__ z3, const unsigned* __restrict__ list,
          const float* __restrict__ w4, const float* __restrict__ b4,
          const float* __restrict__ a3, const float* __restrict__ c3,
          unsigned short* __restrict__ z4, int n){
    __shared__ short w4t[256*128];           // 64 KB: bf16 w4^T [c][k], swizzled
    int tid = threadIdx.x;
    for (int e = tid; e < 16384; e += 256){
        int k2 = e >> 8;
        int c  = e & 255;
        unsigned lo = f2bf(w4[(size_t)(2*k2)*256 + c]);
        unsigned hi = f2bf(w4[(size_t)(2*k2+1)*256 + c]);
        int addr = (c*256 + k2*4) ^ ((c & 7) << 4);
        *(unsigned*)((char*)w4t + addr) = lo | (hi << 16);
    }
    __syncthreads();

    int lane = tid & 63, wid = tid >> 6;
    int l15 = lane & 15, lg = lane >> 4;
    int p0 = blockIdx.x*64 + wid*16;
    int prow = p0 + l15;
    int prow2 = prow < n ? prow : (n - 1);
    int srow = (int)list[prow2];             // original point id (sorted by cell)
    const unsigned short* zrow = z3 + (size_t)srow*128;

    f32x4 acc[16];
#pragma unroll
    for (int t = 0; t < 16; t++){
        float bv = b4[t*16 + l15];
        acc[t] = (f32x4){bv, bv, bv, bv};
    }

#pragma unroll
    for (int ks = 0; ks < 4; ks++){
        int kbase = ks*32 + lg*8;
        uint4 ua = *(const uint4*)(zrow + kbase);
        float4 av0 = *(const float4*)(a3 + kbase);
        float4 av1 = *(const float4*)(a3 + kbase + 4);
        float4 cv0 = *(const float4*)(c3 + kbase);
        float4 cv1 = *(const float4*)(c3 + kbase + 4);
        bf16x8 af;
        af[0] = (short)f2bf(fmaxf(fmaf(bf2f((unsigned short)(ua.x & 0xFFFFu)), av0.x, cv0.x), 0.f));
        af[1] = (short)f2bf(fmaxf(fmaf(bf2f((unsigned short)(ua.x >> 16)),     av0.y, cv0.y), 0.f));
        af[2] = (short)f2bf(fmaxf(fmaf(bf2f((unsigned short)(ua.y & 0xFFFFu)), av0.z, cv0.z), 0.f));
        af[3] = (short)f2bf(fmaxf(fmaf(bf2f((unsigned short)(ua.y >> 16)),     av0.w, cv0.w), 0.f));
        af[4] = (short)f2bf(fmaxf(fmaf(bf2f((unsigned short)(ua.z & 0xFFFFu)), av1.x, cv1.x), 0.f));
        af[5] = (short)f2bf(fmaxf(fmaf(bf2f((unsigned short)(ua.z >> 16)),     av1.y, cv1.y), 0.f));
        af[6] = (short)f2bf(fmaxf(fmaf(bf2f((unsigned short)(ua.w & 0xFFFFu)), av1.z, cv1.z), 0.f));
        af[7] = (short)f2bf(fmaxf(fmaf(bf2f((unsigned short)(ua.w >> 16)),     av1.w, cv1.w), 0.f));
#pragma unroll
        for (int t = 0; t < 16; t++){
            int c = t*16 + l15;
            int addr = (c*256 + kbase*2) ^ ((c & 7) << 4);
            bf16x8 bf = *(const bf16x8*)((const char*)w4t + addr);
            acc[t] = __builtin_amdgcn_mfma_f32_16x16x32_bf16(af, bf, acc[t], 0, 0, 0);
        }
    }

#pragma unroll
    for (int t = 0; t < 16; t++){
#pragma unroll
        for (int r = 0; r < 4; r++){
            int pr = p0 + lg*4 + r;
            if (pr < n)
                z4[(size_t)pr*256 + t*16 + l15] = f2bf(acc[t][r]);
        }
    }
}

// ---------- FUSED gather-max + 3x3 maxpool, CHANNEL-SPLIT, line-coalesced writes ----------
// Phase 2c: lane=(row_sub,gy_quad) so one wave-store covers 16 FULL 64B lines.
#define NOCELL 0xFFFFFFFFu
#define OTS 132                               // out-tile stride (shorts), conflict-free
__global__ __launch_bounds__(256)
void k_gpool(const unsigned* __restrict__ cnt, const unsigned* __restrict__ off,
             const unsigned short* __restrict__ z4, float* __restrict__ out){
    __shared__ unsigned short cm[6*18*128];   // 27648 B: [xx][ty][c] cell maxes
    __shared__ unsigned cno[216];             // [e]{cnt,off}
    int t = threadIdx.x;
    int gy0 = blockIdx.x * 16;
    int gx0 = blockIdx.y * 4;
    int bz  = blockIdx.z;
    int b   = bz >> 1;
    int ch0 = (bz & 1) * 128;

    // stage cnt/off for the 108 halo cells
    for (int e = t; e < 108; e += 256){
        int xx = e / 18, ty = e % 18;
        int gxx = gx0 - 1 + xx, gyy = gy0 - 1 + ty;
        unsigned c = NOCELL, o = 0;
        if ((unsigned)gxx < (unsigned)GXd && (unsigned)gyy < (unsigned)GYd){
            unsigned cell = ((unsigned)b*GXd + gxx)*GYd + gyy;
            c = cnt[cell]; o = off[cell];
        }
        cno[e*2]   = c;
        cno[e*2+1] = o;
    }
    __syncthreads();

    int lane = t & 63, wid = t >> 6;
    const float NEGINF = -__builtin_inff();
    for (int e = wid; e < 108; e += 16){
        unsigned cn_[4], o_[4], n_[4];
#pragma unroll
        for (int k = 0; k < 4; k++){
            int ek = e + k*4;
            bool hv = ek < 108;
            unsigned cc = hv ? cno[ek*2]   : NOCELL;
            unsigned oo = hv ? cno[ek*2+1] : 0;
            cn_[k] = cc;  o_[k] = oo;
            n_[k] = (cc == NOCELL) ? 0u : cc;
        }
        float m0[4], m1[4];
#pragma unroll
        for (int k = 0; k < 4; k++){ m0[k] = NEGINF; m1[k] = NEGINF; }
        unsigned nm = 0;
#pragma unroll
        for (int k = 0; k < 4; k++) nm = nm > n_[k] ? nm : n_[k];
        for (unsigned p = 0; p < nm; p++){
#pragma unroll
            for (int k = 0; k < 4; k++){
                if (p < n_[k]){
                    unsigned u = *(const unsigned*)(z4 + (size_t)(o_[k] + p)*256 + ch0 + lane*2);
                    m0[k] = fmaxf(m0[k], bf2f((unsigned short)(u & 0xFFFFu)));
                    m1[k] = fmaxf(m1[k], bf2f((unsigned short)(u >> 16)));
                }
            }
        }
#pragma unroll
        for (int k = 0; k < 4; k++){
            int ek = e + k*4;
            if (ek < 108){
                float a0 = m0[k], a1 = m1[k];
                if (cn_[k] == 0u){ a0 = 0.f; a1 = 0.f; }
                *(unsigned*)&cm[ek*128 + lane*2] =
                    (unsigned)f2bf(a0) | ((unsigned)f2bf(a1) << 16);
            }
        }
    }
    __syncthreads();

    // phase 2a: rolling 3x3 max into registers
    int c  = t & 127;
    int gp = t >> 7;                           // 0/1 -> g = gp*2 + {0,1}
    int ymax = GYd - gy0; if (ymax > 16) ymax = 16;   // 16 or 8
    float rA[2], rB[2];
    float ob[2][16];
#pragma unroll
    for (int gg = 0; gg < 2; gg++){ rA[gg] = 0.f; rB[gg] = 0.f; }
#pragma unroll
    for (int ty = 0; ty < 18; ty++){
        float v[6];
#pragma unroll
        for (int xx = 0; xx < 6; xx++)
            v[xx] = bf2f(cm[(xx*18 + ty)*128 + c]);
        float c3[2];
#pragma unroll
        for (int gg = 0; gg < 2; gg++){
            float va = (gp == 0) ? v[gg]     : v[gg+2];
            float vb = (gp == 0) ? v[gg+1]   : v[gg+3];
            float vc = (gp == 0) ? v[gg+2]   : v[gg+4];
            c3[gg] = fmaxf(fmaxf(va, vb), vc);
        }
        if (ty >= 2){
#pragma unroll
            for (int gg = 0; gg < 2; gg++)
                ob[gg][ty - 2] = fmaxf(fmaxf(rA[gg], rB[gg]), c3[gg]);
        }
#pragma unroll
        for (int gg = 0; gg < 2; gg++){ rA[gg] = rB[gg]; rB[gg] = c3[gg]; }
    }
    __syncthreads();                           // all cm reads done -> reuse as out-tile

    // phase 2b: register buffer -> LDS out-tile [gx][yl][c] bf16 (lossless)
    unsigned short* ot = cm;                   // 4*16*OTS shorts = 16896 B <= cm
#pragma unroll
    for (int gg = 0; gg < 2; gg++){
        int g = gp*2 + gg;
#pragma unroll
        for (int yl = 0; yl < 16; yl++)
            ot[(g*16 + yl)*OTS + c] = f2bf(ob[gg][yl]);
    }
    __syncthreads();

    // phase 2c: line-coalesced cooperative write — one wave store = 16 full lines
    int rsub = lane >> 2;                      // 0..15
    int gyq  = lane & 3;                       // 0..3
    int y0   = gyq*4;
#pragma unroll
    for (int it = 0; it < 8; it++){
        int r  = wid*128 + it*16 + rsub;       // 0..511 = gx*128 + c2
        int gx = r >> 7;
        int c2 = r & 127;
        if (y0 < ymax){
            float4 o4;
            o4.x = bf2f(ot[(gx*16 + y0+0)*OTS + c2]);
            o4.y = bf2f(ot[(gx*16 + y0+1)*OTS + c2]);
            o4.z = bf2f(ot[(gx*16 + y0+2)*OTS + c2]);
            o4.w = bf2f(ot[(gx*16 + y0+3)*OTS + c2]);
            *(float4*)(out + ((size_t)b*258 + ch0 + c2)*GXY
                       + (size_t)(gx0+gx)*GYd + gy0 + y0) = o4;
        }
    }
}

// ---------- residual channels ----------
__global__ __launch_bounds__(256)
void k_res(const unsigned* __restrict__ pres, float* __restrict__ out){
    int idx = blockIdx.x*256 + threadIdx.x;
    const int total = NBd*2*GXY;
    if (idx >= total) return;
    int gy = idx % GYd;
    int t  = idx / GYd;
    int gx = t % GXd;  t /= GXd;
    int r  = t & 1;
    int b  = t >> 1;
    unsigned u = pres[idx];
    float f = u ? unmapf(u) : 0.f;
    out[(((size_t)b*258 + 256 + r)*GXd + gx)*GYd + gy] = f;
}

extern "C" void kernel_launch(void* const* d_in, const int* in_sizes, int n_in,
                              void* d_out, int out_size, void* d_ws, size_t ws_size,
                              hipStream_t stream){
    (void)n_in; (void)out_size; (void)ws_size;
    const float* fea   = (const float*)d_in[0];
    const int*   ind   = (const int*)  d_in[1];
    const float* bn0_g = (const float*)d_in[2];
    const float* bn0_b = (const float*)d_in[3];
    const float* w1    = (const float*)d_in[4];
    const float* b1    = (const float*)d_in[5];
    const float* bn1_g = (const float*)d_in[6];
    const float* bn1_b = (const float*)d_in[7];
    const float* w2    = (const float*)d_in[8];
    const float* b2    = (const float*)d_in[9];
    const float* bn2_g = (const float*)d_in[10];
    const float* bn2_b = (const float*)d_in[11];
    const float* w3    = (const float*)d_in[12];
    const float* b3    = (const float*)d_in[13];
    const float* bn3_g = (const float*)d_in[14];
    const float* bn3_b = (const float*)d_in[15];
    const float* w4    = (const float*)d_in[16];
    const float* b4    = (const float*)d_in[17];

    int n = in_sizes[0] / 11;
    float invN = 1.0f / (float)n;

    // ---- ws layout ----
    const size_t Z4_B     = (size_t)240000*256*2;       // 122,880,000
    const size_t POOL_B   = (size_t)NCELL*256*2;        // 176,947,200 (z1/z2/z3 arena)
    const size_t PRES_B   = (size_t)NBd*2*GXY*4;        //   5,529,600
    const size_t CNT_B    = (size_t)NCELL*4;            //   2,764,800
    const size_t STAT_B   = 960*4;
    const size_t GCTR_B   = 256;

    char* base = (char*)d_ws;
    unsigned short* z4 = (unsigned short*)base;
    float*          z1 = (float*)(base + Z4_B);
    float*          z2 = (float*)(base + Z4_B + 30720000);
    unsigned short* z3 = (unsigned short*)(base + Z4_B + 92160000);
    unsigned* pres  = (unsigned*)(base + Z4_B + POOL_B);
    unsigned* cnt   = (unsigned*)((char*)pres + PRES_B);
    float*    stats = (float*)((char*)cnt + CNT_B);
    unsigned* gctr  = (unsigned*)((char*)stats + STAT_B);
    unsigned* off   = (unsigned*)((char*)gctr + GCTR_B);
    unsigned* list  = (unsigned*)((char*)off + CNT_B);
    unsigned* rank  = (unsigned*)((char*)list + (size_t)240000*4);

    float* sum0 = stats;       float* sq0 = stats + 16;
    float* sum1 = stats + 32;  float* sq1 = stats + 64;
    float* sum2 = stats + 96;  float* sq2 = stats + 160;
    float* sum3 = stats + 224; float* sq3 = stats + 352;
    float* a0 = stats + 480;   float* c0 = stats + 496;
    float* a1 = stats + 512;   float* c1 = stats + 544;
    float* a2 = stats + 576;   float* c2 = stats + 640;
    float* a3 = stats + 704;   float* c3 = stats + 832;

    hipMemsetAsync(pres, 0, PRES_B + CNT_B + STAT_B + GCTR_B, stream);

    int nb = (n + 255) / 256;
    int nb64 = (n + 63) / 64;
    k_stats0<<<nb, 256, 0, stream>>>(fea, sum0, sq0, n);
    k_fin<<<1, 128, 0, stream>>>(sum0, sq0, bn0_g, bn0_b, a0, c0, 9,  invN);
    k_l1<<<nb, 256, 0, stream>>>(fea, ind, w1, b1, a0, c0, z1, pres, cnt, rank, sum1, sq1, n);
    k_fin<<<1, 128, 0, stream>>>(sum1, sq1, bn1_g, bn1_b, a1, c1, 32, invN);
    k_l2<<<nb64, 256, 0, stream>>>(z1, w2, b2, a1, c1, z2, sum2, sq2, n);
    k_fin<<<1, 128, 0, stream>>>(sum2, sq2, bn2_g, bn2_b, a2, c2, 64, invN);
    k_l3<<<nb64, 256, 0, stream>>>(z2, w3, b3, a2, c2, z3, sum3, sq3, n);
    k_fin<<<1, 128, 0, stream>>>(sum3, sq3, bn3_g, bn3_b, a3, c3, 128, invN);

    k_off <<<(NCELL + 1023)/1024, 256, 0, stream>>>(cnt, off, gctr);
    k_fill<<<nb, 256, 0, stream>>>(ind, rank, off, list, n);

    k_l4<<<nb64, 256, 0, stream>>>(z3, list, w4, b4, a3, c3, z4, n);

    k_gpool<<<dim3(23, 120, 4), 256, 0, stream>>>(cnt, off, z4, (float*)d_out);

    k_res<<<(NBd*2*GXY + 255) / 256, 256, 0, stream>>>(pres, (float*)d_out);
}

// Round 19
// 629.036 us; speedup vs baseline: 1.2662x; 1.0186x over previous
//
#include <hip/hip_runtime.h>
#include <cstdint>
#include <cstddef>

#define GXd 480
#define GYd 360
#define NBd 2
#define GXY (480*360)
#define NCELL (NBd*GXY)
#define EPSBN 1e-5f

typedef float  f32x4  __attribute__((ext_vector_type(4)));
typedef short  bf16x8 __attribute__((ext_vector_type(8)));

// ---------- order-preserving float <-> uint map (residual atomics only) ----------
__device__ __forceinline__ unsigned mapf(float f){
    unsigned u = __float_as_uint(f);
    return (u & 0x80000000u) ? ~u : (u | 0x80000000u);
}
__device__ __forceinline__ float unmapf(unsigned m){
    return (m & 0x80000000u) ? __uint_as_float(m ^ 0x80000000u)
                             : __uint_as_float(~m);
}

// ---------- bf16 helpers ----------
__device__ __forceinline__ unsigned short f2bf(float f){            // RTN-even
    unsigned u = __float_as_uint(f);
    unsigned r = (u + 0x7FFFu + ((u >> 16) & 1u)) >> 16;
    return (unsigned short)r;
}
__device__ __forceinline__ unsigned short bftrunc(float f){         // exact when value is bf16-representable
    return (unsigned short)(__float_as_uint(f) >> 16);
}
__device__ __forceinline__ float bf2f(unsigned short s){
    return __uint_as_float(((unsigned)s) << 16);
}

// ---------- dense layer helper ----------
template<int DIN, int DOUT>
__device__ __forceinline__ void dense(const float (&in)[DIN], float (&out)[DOUT],
                                      const float* __restrict__ w,
                                      const float* __restrict__ b){
#pragma unroll
    for (int j = 0; j < DOUT; j++) out[j] = b[j];
#pragma unroll
    for (int d = 0; d < DIN; d++){
        float v = in[d];
#pragma unroll
        for (int j = 0; j < DOUT; j++) out[j] = fmaf(v, w[d*DOUT + j], out[j]);
    }
}

// ---------- block-level sum/sumsq reduction ----------
template<int D>
__device__ __forceinline__ void reduce_stats(const float (&h)[D], bool valid,
                                             float* __restrict__ gsum,
                                             float* __restrict__ gsq){
    __shared__ float ssum[D];
    __shared__ float ssq[D];
    int tid = threadIdx.x;
    for (int t = tid; t < D; t += 256){ ssum[t] = 0.f; ssq[t] = 0.f; }
    __syncthreads();
#pragma unroll
    for (int j = 0; j < D; j++){
        float v = valid ? h[j] : 0.f;
        float s = v * v;
#pragma unroll
        for (int o = 32; o > 0; o >>= 1){
            v += __shfl_down(v, o, 64);
            s += __shfl_down(s, o, 64);
        }
        if ((tid & 63) == 0){
            atomicAdd(&ssum[j], v);
            atomicAdd(&ssq[j], s);
        }
    }
    __syncthreads();
    for (int t = tid; t < D; t += 256){
        atomicAdd(&gsum[t], ssum[t]);
        atomicAdd(&gsq[t], ssq[t]);
    }
}

// ---------- BN coefficient from sums (inline finalize) ----------
__device__ __forceinline__ void bn_coef(const float* __restrict__ sum,
                                        const float* __restrict__ sq,
                                        const float* __restrict__ g,
                                        const float* __restrict__ bb,
                                        float invN, int c,
                                        float* __restrict__ a_out,
                                        float* __restrict__ c_out){
    float mu  = sum[c] * invN;
    float var = fmaf(-mu, mu, sq[c] * invN);
    float rs  = rsqrtf(var + EPSBN);
    float a   = rs * g[c];
    a_out[c] = a;
    c_out[c] = fmaf(-mu, a, bb[c]);
}

// ---------- stats of raw input columns 0..8 ----------
__global__ __launch_bounds__(256)
void k_stats0(const float* __restrict__ fea, float* gsum, float* gsq, int n){
    int i = blockIdx.x*256 + threadIdx.x;
    bool valid = i < n;
    int i2 = valid ? i : 0;
    float x[9];
#pragma unroll
    for (int d = 0; d < 9; d++) x[d] = fea[(size_t)i2*11 + d];
    reduce_stats<9>(x, valid, gsum, gsq);
}

// ---------- layer1: bn0 (inline fin) -> 9x32; z1 bf16; stats(rounded); cnt/rank; res ----------
__global__ __launch_bounds__(256)
void k_l1(const float* __restrict__ fea, const int* __restrict__ ind,
          const float* __restrict__ w1, const float* __restrict__ b1,
          const float* __restrict__ sum0, const float* __restrict__ sq0,
          const float* __restrict__ g0, const float* __restrict__ bb0, float invN,
          unsigned short* __restrict__ z1, unsigned* __restrict__ pres,
          unsigned* __restrict__ cnt, unsigned* __restrict__ rank,
          float* gsum, float* gsq, int n){
    __shared__ float a0s[9], c0s[9];
    int tid = threadIdx.x;
    if (tid < 9) bn_coef(sum0, sq0, g0, bb0, invN, tid, a0s, c0s);
    __syncthreads();

    int i = blockIdx.x*256 + tid;
    bool valid = i < n;
    int i2 = valid ? i : 0;
    float x[9];
#pragma unroll
    for (int d = 0; d < 9; d++) x[d] = fmaf(fea[(size_t)i2*11 + d], a0s[d], c0s[d]);
    float h[32];
    dense<9,32>(x, h, w1, b1);
    // round to bf16; stats from rounded values
    unsigned ob[16];
#pragma unroll
    for (int m = 0; m < 16; m++){
        unsigned short lo = f2bf(h[2*m]);
        unsigned short hi = f2bf(h[2*m+1]);
        ob[m] = (unsigned)lo | ((unsigned)hi << 16);
        h[2*m]   = bf2f(lo);
        h[2*m+1] = bf2f(hi);
    }
    if (valid){
        uint4* dst = (uint4*)(z1 + (size_t)i*32);
#pragma unroll
        for (int q = 0; q < 4; q++)
            dst[q] = make_uint4(ob[q*4], ob[q*4+1], ob[q*4+2], ob[q*4+3]);
        float r0 = fea[(size_t)i*11 + 9];
        float r1 = fea[(size_t)i*11 + 10];
        int bb = ind[(size_t)i*3 + 0];
        int gx = ind[(size_t)i*3 + 1];
        int gy = ind[(size_t)i*3 + 2];
        unsigned vox = ((unsigned)bb*GXd + (unsigned)gx)*GYd + (unsigned)gy;
        rank[i] = atomicAdd(&cnt[vox], 1u);
        size_t rbase = (size_t)bb*2*GXY + (size_t)gx*GYd + gy;
        atomicMax(pres + rbase,       mapf(r0));
        atomicMax(pres + rbase + GXY, mapf(r1));
    }
    reduce_stats<32>(h, valid, gsum, gsq);
}

// ---------- layer2 via MFMA: z2 bf16 = bn1relu(z1 bf16) @ w2; stats(rounded) ----------
__global__ __launch_bounds__(256)
void k_l2(const unsigned short* __restrict__ z1,
          const float* __restrict__ w2, const float* __restrict__ b2,
          const float* __restrict__ sum1, const float* __restrict__ sq1,
          const float* __restrict__ g1, const float* __restrict__ bb1, float invN,
          unsigned short* __restrict__ z2, float* gsum, float* gsq, int n){
    __shared__ short w2t[64*40];             // 5120 B
    __shared__ float a1s[32], c1s[32];
    __shared__ float ssum[64], ssq[64];
    int tid = threadIdx.x;
    if (tid < 64){ ssum[tid] = 0.f; ssq[tid] = 0.f; }
    if (tid < 32) bn_coef(sum1, sq1, g1, bb1, invN, tid, a1s, c1s);
    for (int e = tid; e < 2048; e += 256){
        int k = e >> 6, c = e & 63;
        w2t[c*40 + k] = (short)f2bf(w2[k*64 + c]);
    }
    __syncthreads();

    int lane = tid & 63, wid = tid >> 6;
    int l15 = lane & 15, lg = lane >> 4;
    int p0 = blockIdx.x*64 + wid*16;
    int prow = p0 + l15;
    int prow2 = prow < n ? prow : (n - 1);
    int kbase = lg*8;
    uint4 ua = *(const uint4*)(z1 + (size_t)prow2*32 + kbase);
    float4 av0 = *(const float4*)&a1s[kbase];
    float4 av1 = *(const float4*)&a1s[kbase + 4];
    float4 cv0 = *(const float4*)&c1s[kbase];
    float4 cv1 = *(const float4*)&c1s[kbase + 4];
    bf16x8 af;
    af[0] = (short)f2bf(fmaxf(fmaf(bf2f((unsigned short)(ua.x & 0xFFFFu)), av0.x, cv0.x), 0.f));
    af[1] = (short)f2bf(fmaxf(fmaf(bf2f((unsigned short)(ua.x >> 16)),     av0.y, cv0.y), 0.f));
    af[2] = (short)f2bf(fmaxf(fmaf(bf2f((unsigned short)(ua.y & 0xFFFFu)), av0.z, cv0.z), 0.f));
    af[3] = (short)f2bf(fmaxf(fmaf(bf2f((unsigned short)(ua.y >> 16)),     av0.w, cv0.w), 0.f));
    af[4] = (short)f2bf(fmaxf(fmaf(bf2f((unsigned short)(ua.z & 0xFFFFu)), av1.x, cv1.x), 0.f));
    af[5] = (short)f2bf(fmaxf(fmaf(bf2f((unsigned short)(ua.z >> 16)),     av1.y, cv1.y), 0.f));
    af[6] = (short)f2bf(fmaxf(fmaf(bf2f((unsigned short)(ua.w & 0xFFFFu)), av1.z, cv1.z), 0.f));
    af[7] = (short)f2bf(fmaxf(fmaf(bf2f((unsigned short)(ua.w >> 16)),     av1.w, cv1.w), 0.f));

    f32x4 acc[4];
#pragma unroll
    for (int t = 0; t < 4; t++){
        float bv = b2[t*16 + l15];
        acc[t] = (f32x4){bv, bv, bv, bv};
    }
#pragma unroll
    for (int t = 0; t < 4; t++){
        bf16x8 bf = *(const bf16x8*)&w2t[(t*16 + l15)*40 + kbase];
        acc[t] = __builtin_amdgcn_mfma_f32_16x16x32_bf16(af, bf, acc[t], 0, 0, 0);
    }

#pragma unroll
    for (int t = 0; t < 4; t++){
        int c = t*16 + l15;
        float s = 0.f, q = 0.f;
#pragma unroll
        for (int r = 0; r < 4; r++){
            int pr = p0 + lg*4 + r;
            unsigned short rb = f2bf(acc[t][r]);
            float rv = bf2f(rb);
            if (pr < n){
                z2[(size_t)pr*64 + c] = rb;
                s += rv; q += rv*rv;
            }
        }
        s += __shfl_xor(s, 16, 64);  q += __shfl_xor(q, 16, 64);
        s += __shfl_xor(s, 32, 64);  q += __shfl_xor(q, 32, 64);
        if (lg == 0){ atomicAdd(&ssum[c], s); atomicAdd(&ssq[c], q); }
    }
    __syncthreads();
    if (tid < 64){ atomicAdd(gsum + tid, ssum[tid]); atomicAdd(gsq + tid, ssq[tid]); }
}

// ---------- layer3 via MFMA: z3 bf16 = bn2relu(z2 bf16) @ w3; stats(rounded) ----------
__global__ __launch_bounds__(256)
void k_l3(const unsigned short* __restrict__ z2,
          const float* __restrict__ w3, const float* __restrict__ b3,
          const float* __restrict__ sum2, const float* __restrict__ sq2,
          const float* __restrict__ g2, const float* __restrict__ bb2, float invN,
          unsigned short* __restrict__ z3, float* gsum, float* gsq, int n){
    __shared__ short w3t[128*72];            // 18432 B, [c][k] stride 72
    __shared__ float a2s[64], c2s[64];
    __shared__ float ssum[128], ssq[128];
    int tid = threadIdx.x;
    if (tid < 128){ ssum[tid] = 0.f; ssq[tid] = 0.f; }
    if (tid < 64) bn_coef(sum2, sq2, g2, bb2, invN, tid, a2s, c2s);
    for (int e = tid; e < 8192; e += 256){
        int k = e >> 7, c = e & 127;
        w3t[c*72 + k] = (short)f2bf(w3[k*128 + c]);
    }
    __syncthreads();

    int lane = tid & 63, wid = tid >> 6;
    int l15 = lane & 15, lg = lane >> 4;
    int p0 = blockIdx.x*64 + wid*16;
    int prow = p0 + l15;
    int prow2 = prow < n ? prow : (n - 1);
    const unsigned short* zrow = z2 + (size_t)prow2*64;

    f32x4 acc[8];
#pragma unroll
    for (int t = 0; t < 8; t++){
        float bv = b3[t*16 + l15];
        acc[t] = (f32x4){bv, bv, bv, bv};
    }

#pragma unroll
    for (int ks = 0; ks < 2; ks++){
        int kbase = ks*32 + lg*8;
        uint4 ua = *(const uint4*)(zrow + kbase);
        float4 av0 = *(const float4*)&a2s[kbase];
        float4 av1 = *(const float4*)&a2s[kbase + 4];
        float4 cv0 = *(const float4*)&c2s[kbase];
        float4 cv1 = *(const float4*)&c2s[kbase + 4];
        bf16x8 af;
        af[0] = (short)f2bf(fmaxf(fmaf(bf2f((unsigned short)(ua.x & 0xFFFFu)), av0.x, cv0.x), 0.f));
        af[1] = (short)f2bf(fmaxf(fmaf(bf2f((unsigned short)(ua.x >> 16)),     av0.y, cv0.y), 0.f));
        af[2] = (short)f2bf(fmaxf(fmaf(bf2f((unsigned short)(ua.y & 0xFFFFu)), av0.z, cv0.z), 0.f));
        af[3] = (short)f2bf(fmaxf(fmaf(bf2f((unsigned short)(ua.y >> 16)),     av0.w, cv0.w), 0.f));
        af[4] = (short)f2bf(fmaxf(fmaf(bf2f((unsigned short)(ua.z & 0xFFFFu)), av1.x, cv1.x), 0.f));
        af[5] = (short)f2bf(fmaxf(fmaf(bf2f((unsigned short)(ua.z >> 16)),     av1.y, cv1.y), 0.f));
        af[6] = (short)f2bf(fmaxf(fmaf(bf2f((unsigned short)(ua.w & 0xFFFFu)), av1.z, cv1.z), 0.f));
        af[7] = (short)f2bf(fmaxf(fmaf(bf2f((unsigned short)(ua.w >> 16)),     av1.w, cv1.w), 0.f));
#pragma unroll
        for (int t = 0; t < 8; t++){
            bf16x8 bf = *(const bf16x8*)&w3t[(t*16 + l15)*72 + kbase];
            acc[t] = __builtin_amdgcn_mfma_f32_16x16x32_bf16(af, bf, acc[t], 0, 0, 0);
        }
    }

#pragma unroll
    for (int t = 0; t < 8; t++){
        int c = t*16 + l15;
        float s = 0.f, q = 0.f;
#pragma unroll
        for (int r = 0; r < 4; r++){
            int pr = p0 + lg*4 + r;
            unsigned short rb = f2bf(acc[t][r]);
            float rv = bf2f(rb);
            if (pr < n){
                z3[(size_t)pr*128 + c] = rb;
                s += rv; q += rv*rv;
            }
        }
        s += __shfl_xor(s, 16, 64);  q += __shfl_xor(q, 16, 64);
        s += __shfl_xor(s, 32, 64);  q += __shfl_xor(q, 32, 64);
        if (lg == 0){ atomicAdd(&ssum[c], s); atomicAdd(&ssq[c], q); }
    }
    __syncthreads();
    if (tid < 128){ atomicAdd(gsum + tid, ssum[tid]); atomicAdd(gsq + tid, ssq[tid]); }
}

// ---------- exclusive scan of cnt via block tickets ----------
__global__ __launch_bounds__(256)
void k_off(const unsigned* __restrict__ cnt, unsigned* __restrict__ off,
           unsigned* __restrict__ gctr){
    __shared__ unsigned wtot[4];
    __shared__ unsigned wbase[4];
    int t = threadIdx.x;
    int lane = t & 63, w = t >> 6;
    int base = blockIdx.x * 1024 + t * 4;
    bool ok = base < NCELL;
    unsigned c0 = 0, c1 = 0, c2 = 0, c3 = 0;
    if (ok){ c0 = cnt[base]; c1 = cnt[base+1]; c2 = cnt[base+2]; c3 = cnt[base+3]; }
    unsigned tot = c0 + c1 + c2 + c3;
    unsigned incl = tot;
#pragma unroll
    for (int o = 1; o < 64; o <<= 1){
        unsigned v = __shfl_up(incl, o, 64);
        if (lane >= o) incl += v;
    }
    if (lane == 63) wtot[w] = incl;
    __syncthreads();
    if (t == 0){
        unsigned bt = wtot[0] + wtot[1] + wtot[2] + wtot[3];
        unsigned gb = atomicAdd(gctr, bt);
        unsigned s = 0;
#pragma unroll
        for (int q = 0; q < 4; q++){ wbase[q] = gb + s; s += wtot[q]; }
    }
    __syncthreads();
    if (ok){
        unsigned tb = wbase[w] + incl - tot;
        off[base]   = tb;
        off[base+1] = tb + c0;
        off[base+2] = tb + c0 + c1;
        off[base+3] = tb + c0 + c1 + c2;
    }
}

// ---------- fill per-cell point lists ----------
__global__ __launch_bounds__(256)
void k_fill(const int* __restrict__ ind, const unsigned* __restrict__ rank,
            const unsigned* __restrict__ off, unsigned* __restrict__ list, int n){
    int i = blockIdx.x*256 + threadIdx.x;
    if (i >= n) return;
    int bb = ind[(size_t)i*3], gx = ind[(size_t)i*3+1], gy = ind[(size_t)i*3+2];
    unsigned vox = ((unsigned)bb*GXd + (unsigned)gx)*GYd + (unsigned)gy;
    list[off[vox] + rank[i]] = (unsigned)i;
}

// ---------- layer4 via MFMA, SORTED output ----------
__global__ __launch_bounds__(256)
void k_l4(const unsigned short* __restrict__ z3, const unsigned* __restrict__ list,
          const float* __restrict__ w4, const float* __restrict__ b4,
          const float* __restrict__ sum3, const float* __restrict__ sq3,
          const float* __restrict__ g3, const float* __restrict__ bb3, float invN,
          unsigned short* __restrict__ z4, int n){
    __shared__ short w4t[256*128];           // 64 KB: bf16 w4^T [c][k], swizzled
    __shared__ float a3s[128], c3s[128];
    int tid = threadIdx.x;
    if (tid < 128) bn_coef(sum3, sq3, g3, bb3, invN, tid, a3s, c3s);
    for (int e = tid; e < 16384; e += 256){
        int k2 = e >> 8;
        int c  = e & 255;
        unsigned lo = f2bf(w4[(size_t)(2*k2)*256 + c]);
        unsigned hi = f2bf(w4[(size_t)(2*k2+1)*256 + c]);
        int addr = (c*256 + k2*4) ^ ((c & 7) << 4);
        *(unsigned*)((char*)w4t + addr) = lo | (hi << 16);
    }
    __syncthreads();

    int lane = tid & 63, wid = tid >> 6;
    int l15 = lane & 15, lg = lane >> 4;
    int p0 = blockIdx.x*64 + wid*16;
    int prow = p0 + l15;
    int prow2 = prow < n ? prow : (n - 1);
    int srow = (int)list[prow2];             // original point id (sorted by cell)
    const unsigned short* zrow = z3 + (size_t)srow*128;

    f32x4 acc[16];
#pragma unroll
    for (int t = 0; t < 16; t++){
        float bv = b4[t*16 + l15];
        acc[t] = (f32x4){bv, bv, bv, bv};
    }

#pragma unroll
    for (int ks = 0; ks < 4; ks++){
        int kbase = ks*32 + lg*8;
        uint4 ua = *(const uint4*)(zrow + kbase);
        float4 av0 = *(const float4*)&a3s[kbase];
        float4 av1 = *(const float4*)&a3s[kbase + 4];
        float4 cv0 = *(const float4*)&c3s[kbase];
        float4 cv1 = *(const float4*)&c3s[kbase + 4];
        bf16x8 af;
        af[0] = (short)f2bf(fmaxf(fmaf(bf2f((unsigned short)(ua.x & 0xFFFFu)), av0.x, cv0.x), 0.f));
        af[1] = (short)f2bf(fmaxf(fmaf(bf2f((unsigned short)(ua.x >> 16)),     av0.y, cv0.y), 0.f));
        af[2] = (short)f2bf(fmaxf(fmaf(bf2f((unsigned short)(ua.y & 0xFFFFu)), av0.z, cv0.z), 0.f));
        af[3] = (short)f2bf(fmaxf(fmaf(bf2f((unsigned short)(ua.y >> 16)),     av0.w, cv0.w), 0.f));
        af[4] = (short)f2bf(fmaxf(fmaf(bf2f((unsigned short)(ua.z & 0xFFFFu)), av1.x, cv1.x), 0.f));
        af[5] = (short)f2bf(fmaxf(fmaf(bf2f((unsigned short)(ua.z >> 16)),     av1.y, cv1.y), 0.f));
        af[6] = (short)f2bf(fmaxf(fmaf(bf2f((unsigned short)(ua.w & 0xFFFFu)), av1.z, cv1.z), 0.f));
        af[7] = (short)f2bf(fmaxf(fmaf(bf2f((unsigned short)(ua.w >> 16)),     av1.w, cv1.w), 0.f));
#pragma unroll
        for (int t = 0; t < 16; t++){
            int c = t*16 + l15;
            int addr = (c*256 + kbase*2) ^ ((c & 7) << 4);
            bf16x8 bf = *(const bf16x8*)((const char*)w4t + addr);
            acc[t] = __builtin_amdgcn_mfma_f32_16x16x32_bf16(af, bf, acc[t], 0, 0, 0);
        }
    }

#pragma unroll
    for (int t = 0; t < 16; t++){
#pragma unroll
        for (int r = 0; r < 4; r++){
            int pr = p0 + lg*4 + r;
            if (pr < n)
                z4[(size_t)pr*256 + t*16 + l15] = f2bf(acc[t][r]);
        }
    }
}

// ---------- FUSED gather-max + 3x3 maxpool, CHANNEL-SPLIT, line-coalesced writes ----------
#define NOCELL 0xFFFFFFFFu
#define OTS 132
__global__ __launch_bounds__(256)
void k_gpool(const unsigned* __restrict__ cnt, const unsigned* __restrict__ off,
             const unsigned short* __restrict__ z4, float* __restrict__ out){
    __shared__ unsigned short cm[6*18*128];   // 27648 B
    __shared__ unsigned cno[216];
    int t = threadIdx.x;
    int gy0 = blockIdx.x * 16;
    int gx0 = blockIdx.y * 4;
    int bz  = blockIdx.z;
    int b   = bz >> 1;
    int ch0 = (bz & 1) * 128;

    for (int e = t; e < 108; e += 256){
        int xx = e / 18, ty = e % 18;
        int gxx = gx0 - 1 + xx, gyy = gy0 - 1 + ty;
        unsigned c = NOCELL, o = 0;
        if ((unsigned)gxx < (unsigned)GXd && (unsigned)gyy < (unsigned)GYd){
            unsigned cell = ((unsigned)b*GXd + gxx)*GYd + gyy;
            c = cnt[cell]; o = off[cell];
        }
        cno[e*2]   = c;
        cno[e*2+1] = o;
    }
    __syncthreads();

    int lane = t & 63, wid = t >> 6;
    const float NEGINF = -__builtin_inff();
    for (int e = wid; e < 108; e += 16){
        unsigned cn_[4], o_[4], n_[4];
#pragma unroll
        for (int k = 0; k < 4; k++){
            int ek = e + k*4;
            bool hv = ek < 108;
            unsigned cc = hv ? cno[ek*2]   : NOCELL;
            unsigned oo = hv ? cno[ek*2+1] : 0;
            cn_[k] = cc;  o_[k] = oo;
            n_[k] = (cc == NOCELL) ? 0u : cc;
        }
        float m0[4], m1[4];
#pragma unroll
        for (int k = 0; k < 4; k++){ m0[k] = NEGINF; m1[k] = NEGINF; }
        unsigned nm = 0;
#pragma unroll
        for (int k = 0; k < 4; k++) nm = nm > n_[k] ? nm : n_[k];
        for (unsigned p = 0; p < nm; p++){
#pragma unroll
            for (int k = 0; k < 4; k++){
                if (p < n_[k]){
                    unsigned u = *(const unsigned*)(z4 + (size_t)(o_[k] + p)*256 + ch0 + lane*2);
                    m0[k] = fmaxf(m0[k], bf2f((unsigned short)(u & 0xFFFFu)));
                    m1[k] = fmaxf(m1[k], bf2f((unsigned short)(u >> 16)));
                }
            }
        }
#pragma unroll
        for (int k = 0; k < 4; k++){
            int ek = e + k*4;
            if (ek < 108){
                float a0 = m0[k], a1 = m1[k];
                if (cn_[k] == 0u){ a0 = 0.f; a1 = 0.f; }
                *(unsigned*)&cm[ek*128 + lane*2] =
                    (unsigned)bftrunc(a0) | ((unsigned)bftrunc(a1) << 16);
            }
        }
    }
    __syncthreads();

    int c  = t & 127;
    int gp = t >> 7;
    int ymax = GYd - gy0; if (ymax > 16) ymax = 16;
    float rA[2], rB[2];
    float ob[2][16];
#pragma unroll
    for (int gg = 0; gg < 2; gg++){ rA[gg] = 0.f; rB[gg] = 0.f; }
#pragma unroll
    for (int ty = 0; ty < 18; ty++){
        float v[6];
#pragma unroll
        for (int xx = 0; xx < 6; xx++)
            v[xx] = bf2f(cm[(xx*18 + ty)*128 + c]);
        float c3[2];
#pragma unroll
        for (int gg = 0; gg < 2; gg++){
            float va = (gp == 0) ? v[gg]     : v[gg+2];
            float vb = (gp == 0) ? v[gg+1]   : v[gg+3];
            float vc = (gp == 0) ? v[gg+2]   : v[gg+4];
            c3[gg] = fmaxf(fmaxf(va, vb), vc);
        }
        if (ty >= 2){
#pragma unroll
            for (int gg = 0; gg < 2; gg++)
                ob[gg][ty - 2] = fmaxf(fmaxf(rA[gg], rB[gg]), c3[gg]);
        }
#pragma unroll
        for (int gg = 0; gg < 2; gg++){ rA[gg] = rB[gg]; rB[gg] = c3[gg]; }
    }
    __syncthreads();

    unsigned short* ot = cm;                   // 4*16*OTS shorts = 16896 B
#pragma unroll
    for (int gg = 0; gg < 2; gg++){
        int g = gp*2 + gg;
#pragma unroll
        for (int yl = 0; yl < 16; yl++)
            ot[(g*16 + yl)*OTS + c] = bftrunc(ob[gg][yl]);
    }
    __syncthreads();

    int rsub = lane >> 2;
    int gyq  = lane & 3;
    int y0   = gyq*4;
#pragma unroll
    for (int it = 0; it < 8; it++){
        int r  = wid*128 + it*16 + rsub;
        int gx = r >> 7;
        int c2 = r & 127;
        if (y0 < ymax){
            float4 o4;
            o4.x = bf2f(ot[(gx*16 + y0+0)*OTS + c2]);
            o4.y = bf2f(ot[(gx*16 + y0+1)*OTS + c2]);
            o4.z = bf2f(ot[(gx*16 + y0+2)*OTS + c2]);
            o4.w = bf2f(ot[(gx*16 + y0+3)*OTS + c2]);
            *(float4*)(out + ((size_t)b*258 + ch0 + c2)*GXY
                       + (size_t)(gx0+gx)*GYd + gy0 + y0) = o4;
        }
    }
}

// ---------- residual channels ----------
__global__ __launch_bounds__(256)
void k_res(const unsigned* __restrict__ pres, float* __restrict__ out){
    int idx = blockIdx.x*256 + threadIdx.x;
    const int total = NBd*2*GXY;
    if (idx >= total) return;
    int gy = idx % GYd;
    int t  = idx / GYd;
    int gx = t % GXd;  t /= GXd;
    int r  = t & 1;
    int b  = t >> 1;
    unsigned u = pres[idx];
    float f = u ? unmapf(u) : 0.f;
    out[(((size_t)b*258 + 256 + r)*GXd + gx)*GYd + gy] = f;
}

extern "C" void kernel_launch(void* const* d_in, const int* in_sizes, int n_in,
                              void* d_out, int out_size, void* d_ws, size_t ws_size,
                              hipStream_t stream){
    (void)n_in; (void)out_size; (void)ws_size;
    const float* fea   = (const float*)d_in[0];
    const int*   ind   = (const int*)  d_in[1];
    const float* bn0_g = (const float*)d_in[2];
    const float* bn0_b = (const float*)d_in[3];
    const float* w1    = (const float*)d_in[4];
    const float* b1    = (const float*)d_in[5];
    const float* bn1_g = (const float*)d_in[6];
    const float* bn1_b = (const float*)d_in[7];
    const float* w2    = (const float*)d_in[8];
    const float* b2    = (const float*)d_in[9];
    const float* bn2_g = (const float*)d_in[10];
    const float* bn2_b = (const float*)d_in[11];
    const float* w3    = (const float*)d_in[12];
    const float* b3    = (const float*)d_in[13];
    const float* bn3_g = (const float*)d_in[14];
    const float* bn3_b = (const float*)d_in[15];
    const float* w4    = (const float*)d_in[16];
    const float* b4    = (const float*)d_in[17];

    int n = in_sizes[0] / 11;
    float invN = 1.0f / (float)n;

    // ---- ws layout ----
    const size_t Z4_B     = (size_t)240000*256*2;       // 122,880,000
    const size_t POOL_B   = (size_t)NCELL*256*2;        // arena for z1/z2/z3
    const size_t PRES_B   = (size_t)NBd*2*GXY*4;
    const size_t CNT_B    = (size_t)NCELL*4;
    const size_t STAT_B   = 960*4;
    const size_t GCTR_B   = 256;

    char* base = (char*)d_ws;
    unsigned short* z4 = (unsigned short*)base;
    unsigned short* z1 = (unsigned short*)(base + Z4_B);                // 15.36 MB
    unsigned short* z2 = (unsigned short*)(base + Z4_B + 15360000);     // 30.72 MB
    unsigned short* z3 = (unsigned short*)(base + Z4_B + 46080000);     // 61.44 MB
    unsigned* pres  = (unsigned*)(base + Z4_B + POOL_B);
    unsigned* cnt   = (unsigned*)((char*)pres + PRES_B);
    float*    stats = (float*)((char*)cnt + CNT_B);
    unsigned* gctr  = (unsigned*)((char*)stats + STAT_B);
    unsigned* off   = (unsigned*)((char*)gctr + GCTR_B);
    unsigned* list  = (unsigned*)((char*)off + CNT_B);
    unsigned* rank  = (unsigned*)((char*)list + (size_t)240000*4);

    float* sum0 = stats;       float* sq0 = stats + 16;
    float* sum1 = stats + 32;  float* sq1 = stats + 64;
    float* sum2 = stats + 96;  float* sq2 = stats + 160;
    float* sum3 = stats + 224; float* sq3 = stats + 352;

    hipMemsetAsync(pres, 0, PRES_B + CNT_B + STAT_B + GCTR_B, stream);

    int nb = (n + 255) / 256;
    int nb64 = (n + 63) / 64;
    k_stats0<<<nb, 256, 0, stream>>>(fea, sum0, sq0, n);
    k_l1<<<nb, 256, 0, stream>>>(fea, ind, w1, b1, sum0, sq0, bn0_g, bn0_b, invN,
                                 z1, pres, cnt, rank, sum1, sq1, n);
    k_l2<<<nb64, 256, 0, stream>>>(z1, w2, b2, sum1, sq1, bn1_g, bn1_b, invN,
                                   z2, sum2, sq2, n);
    k_l3<<<nb64, 256, 0, stream>>>(z2, w3, b3, sum2, sq2, bn2_g, bn2_b, invN,
                                   z3, sum3, sq3, n);

    k_off <<<(NCELL + 1023)/1024, 256, 0, stream>>>(cnt, off, gctr);
    k_fill<<<nb, 256, 0, stream>>>(ind, rank, off, list, n);

    k_l4<<<nb64, 256, 0, stream>>>(z3, list, w4, b4, sum3, sq3, bn3_g, bn3_b, invN,
                                   z4, n);

    k_gpool<<<dim3(23, 120, 4), 256, 0, stream>>>(cnt, off, z4, (float*)d_out);

    k_res<<<(NBd*2*GXY + 255) / 256, 256, 0, stream>>>(pres, (float*)d_out);
}

// Round 20
// 533.355 us; speedup vs baseline: 1.4933x; 1.1794x over previous
//
#include <hip/hip_runtime.h>
#include <cstdint>
#include <cstddef>

#define GXd 480
#define GYd 360
#define NBd 2
#define GXY (480*360)
#define NCELL (NBd*GXY)
#define EPSBN 1e-5f

typedef float  f32x4  __attribute__((ext_vector_type(4)));
typedef short  bf16x8 __attribute__((ext_vector_type(8)));

// ---------- order-preserving float <-> uint map (residual atomics only) ----------
__device__ __forceinline__ unsigned mapf(float f){
    unsigned u = __float_as_uint(f);
    return (u & 0x80000000u) ? ~u : (u | 0x80000000u);
}
__device__ __forceinline__ float unmapf(unsigned m){
    return (m & 0x80000000u) ? __uint_as_float(m ^ 0x80000000u)
                             : __uint_as_float(~m);
}

// ---------- bf16 helpers ----------
__device__ __forceinline__ unsigned short f2bf(float f){            // RTN-even
    unsigned u = __float_as_uint(f);
    unsigned r = (u + 0x7FFFu + ((u >> 16) & 1u)) >> 16;
    return (unsigned short)r;
}
__device__ __forceinline__ float bf2f(unsigned short s){
    return __uint_as_float(((unsigned)s) << 16);
}

// ---------- dense layer helper ----------
template<int DIN, int DOUT>
__device__ __forceinline__ void dense(const float (&in)[DIN], float (&out)[DOUT],
                                      const float* __restrict__ w,
                                      const float* __restrict__ b){
#pragma unroll
    for (int j = 0; j < DOUT; j++) out[j] = b[j];
#pragma unroll
    for (int d = 0; d < DIN; d++){
        float v = in[d];
#pragma unroll
        for (int j = 0; j < DOUT; j++) out[j] = fmaf(v, w[d*DOUT + j], out[j]);
    }
}

// ---------- block-level sum/sumsq reduction ----------
template<int D>
__device__ __forceinline__ void reduce_stats(const float (&h)[D], bool valid,
                                             float* __restrict__ gsum,
                                             float* __restrict__ gsq){
    __shared__ float ssum[D];
    __shared__ float ssq[D];
    int tid = threadIdx.x;
    for (int t = tid; t < D; t += 256){ ssum[t] = 0.f; ssq[t] = 0.f; }
    __syncthreads();
#pragma unroll
    for (int j = 0; j < D; j++){
        float v = valid ? h[j] : 0.f;
        float s = v * v;
#pragma unroll
        for (int o = 32; o > 0; o >>= 1){
            v += __shfl_down(v, o, 64);
            s += __shfl_down(s, o, 64);
        }
        if ((tid & 63) == 0){
            atomicAdd(&ssum[j], v);
            atomicAdd(&ssq[j], s);
        }
    }
    __syncthreads();
    for (int t = tid; t < D; t += 256){
        atomicAdd(&gsum[t], ssum[t]);
        atomicAdd(&gsq[t], ssq[t]);
    }
}

// ---------- BN coefficient from sums (inline finalize) ----------
__device__ __forceinline__ void bn_coef(const float* __restrict__ sum,
                                        const float* __restrict__ sq,
                                        const float* __restrict__ g,
                                        const float* __restrict__ bb,
                                        float invN, int c,
                                        float* __restrict__ a_out,
                                        float* __restrict__ c_out){
    float mu  = sum[c] * invN;
    float var = fmaf(-mu, mu, sq[c] * invN);
    float rs  = rsqrtf(var + EPSBN);
    float a   = rs * g[c];
    a_out[c] = a;
    c_out[c] = fmaf(-mu, a, bb[c]);
}

// ---------- stats of raw input columns 0..8 ----------
__global__ __launch_bounds__(256)
void k_stats0(const float* __restrict__ fea, float* gsum, float* gsq, int n){
    int i = blockIdx.x*256 + threadIdx.x;
    bool valid = i < n;
    int i2 = valid ? i : 0;
    float x[9];
#pragma unroll
    for (int d = 0; d < 9; d++) x[d] = fea[(size_t)i2*11 + d];
    reduce_stats<9>(x, valid, gsum, gsq);
}

// ---------- layer1: bn0 (inline fin) -> 9x32; z1 bf16; stats(rounded); cnt/rank; res ----------
__global__ __launch_bounds__(256)
void k_l1(const float* __restrict__ fea, const int* __restrict__ ind,
          const float* __restrict__ w1, const float* __restrict__ b1,
          const float* __restrict__ sum0, const float* __restrict__ sq0,
          const float* __restrict__ g0, const float* __restrict__ bb0, float invN,
          unsigned short* __restrict__ z1, unsigned* __restrict__ pres,
          unsigned* __restrict__ cnt, unsigned* __restrict__ rank,
          float* gsum, float* gsq, int n){
    __shared__ float a0s[9], c0s[9];
    int tid = threadIdx.x;
    if (tid < 9) bn_coef(sum0, sq0, g0, bb0, invN, tid, a0s, c0s);
    __syncthreads();

    int i = blockIdx.x*256 + tid;
    bool valid = i < n;
    int i2 = valid ? i : 0;
    float x[9];
#pragma unroll
    for (int d = 0; d < 9; d++) x[d] = fmaf(fea[(size_t)i2*11 + d], a0s[d], c0s[d]);
    float h[32];
    dense<9,32>(x, h, w1, b1);
    unsigned ob[16];
#pragma unroll
    for (int m = 0; m < 16; m++){
        unsigned short lo = f2bf(h[2*m]);
        unsigned short hi = f2bf(h[2*m+1]);
        ob[m] = (unsigned)lo | ((unsigned)hi << 16);
        h[2*m]   = bf2f(lo);
        h[2*m+1] = bf2f(hi);
    }
    if (valid){
        uint4* dst = (uint4*)(z1 + (size_t)i*32);
#pragma unroll
        for (int q = 0; q < 4; q++)
            dst[q] = make_uint4(ob[q*4], ob[q*4+1], ob[q*4+2], ob[q*4+3]);
        float r0 = fea[(size_t)i*11 + 9];
        float r1 = fea[(size_t)i*11 + 10];
        int bb = ind[(size_t)i*3 + 0];
        int gx = ind[(size_t)i*3 + 1];
        int gy = ind[(size_t)i*3 + 2];
        unsigned vox = ((unsigned)bb*GXd + (unsigned)gx)*GYd + (unsigned)gy;
        rank[i] = atomicAdd(&cnt[vox], 1u);
        size_t rbase = (size_t)bb*2*GXY + (size_t)gx*GYd + gy;
        atomicMax(pres + rbase,       mapf(r0));
        atomicMax(pres + rbase + GXY, mapf(r1));
    }
    reduce_stats<32>(h, valid, gsum, gsq);
}

// ---------- layer2 via MFMA (4 row-groups/block): z2 bf16; stats(rounded) ----------
__global__ __launch_bounds__(256)
void k_l2(const unsigned short* __restrict__ z1,
          const float* __restrict__ w2, const float* __restrict__ b2,
          const float* __restrict__ sum1, const float* __restrict__ sq1,
          const float* __restrict__ g1, const float* __restrict__ bb1, float invN,
          unsigned short* __restrict__ z2, float* gsum, float* gsq, int n){
    __shared__ short w2t[64*40];
    __shared__ float a1s[32], c1s[32];
    __shared__ float ssum[64], ssq[64];
    int tid = threadIdx.x;
    if (tid < 64){ ssum[tid] = 0.f; ssq[tid] = 0.f; }
    if (tid < 32) bn_coef(sum1, sq1, g1, bb1, invN, tid, a1s, c1s);
    for (int e = tid; e < 2048; e += 256){
        int k = e >> 6, c = e & 63;
        w2t[c*40 + k] = (short)f2bf(w2[k*64 + c]);
    }
    __syncthreads();

    int lane = tid & 63, wid = tid >> 6;
    int l15 = lane & 15, lg = lane >> 4;
    int kbase = lg*8;
    float4 av0 = *(const float4*)&a1s[kbase];
    float4 av1 = *(const float4*)&a1s[kbase + 4];
    float4 cv0 = *(const float4*)&c1s[kbase];
    float4 cv1 = *(const float4*)&c1s[kbase + 4];

#pragma unroll 1
    for (int rg = 0; rg < 4; rg++){
        int p0 = blockIdx.x*256 + rg*64 + wid*16;
        int prow = p0 + l15;
        int prow2 = prow < n ? prow : (n - 1);
        uint4 ua = *(const uint4*)(z1 + (size_t)prow2*32 + kbase);
        bf16x8 af;
        af[0] = (short)f2bf(fmaxf(fmaf(bf2f((unsigned short)(ua.x & 0xFFFFu)), av0.x, cv0.x), 0.f));
        af[1] = (short)f2bf(fmaxf(fmaf(bf2f((unsigned short)(ua.x >> 16)),     av0.y, cv0.y), 0.f));
        af[2] = (short)f2bf(fmaxf(fmaf(bf2f((unsigned short)(ua.y & 0xFFFFu)), av0.z, cv0.z), 0.f));
        af[3] = (short)f2bf(fmaxf(fmaf(bf2f((unsigned short)(ua.y >> 16)),     av0.w, cv0.w), 0.f));
        af[4] = (short)f2bf(fmaxf(fmaf(bf2f((unsigned short)(ua.z & 0xFFFFu)), av1.x, cv1.x), 0.f));
        af[5] = (short)f2bf(fmaxf(fmaf(bf2f((unsigned short)(ua.z >> 16)),     av1.y, cv1.y), 0.f));
        af[6] = (short)f2bf(fmaxf(fmaf(bf2f((unsigned short)(ua.w & 0xFFFFu)), av1.z, cv1.z), 0.f));
        af[7] = (short)f2bf(fmaxf(fmaf(bf2f((unsigned short)(ua.w >> 16)),     av1.w, cv1.w), 0.f));

        f32x4 acc[4];
#pragma unroll
        for (int t = 0; t < 4; t++){
            float bv = b2[t*16 + l15];
            acc[t] = (f32x4){bv, bv, bv, bv};
        }
#pragma unroll
        for (int t = 0; t < 4; t++){
            bf16x8 bf = *(const bf16x8*)&w2t[(t*16 + l15)*40 + kbase];
            acc[t] = __builtin_amdgcn_mfma_f32_16x16x32_bf16(af, bf, acc[t], 0, 0, 0);
        }

#pragma unroll
        for (int t = 0; t < 4; t++){
            int c = t*16 + l15;
            float s = 0.f, q = 0.f;
#pragma unroll
            for (int r = 0; r < 4; r++){
                int pr = p0 + lg*4 + r;
                unsigned short rb = f2bf(acc[t][r]);
                float rv = bf2f(rb);
                if (pr < n){
                    z2[(size_t)pr*64 + c] = rb;
                    s += rv; q += rv*rv;
                }
            }
            s += __shfl_xor(s, 16, 64);  q += __shfl_xor(q, 16, 64);
            s += __shfl_xor(s, 32, 64);  q += __shfl_xor(q, 32, 64);
            if (lg == 0){ atomicAdd(&ssum[c], s); atomicAdd(&ssq[c], q); }
        }
    }
    __syncthreads();
    if (tid < 64){ atomicAdd(gsum + tid, ssum[tid]); atomicAdd(gsq + tid, ssq[tid]); }
}

// ---------- layer3 via MFMA (4 row-groups/block): z3 bf16; stats(rounded) ----------
__global__ __launch_bounds__(256)
void k_l3(const unsigned short* __restrict__ z2,
          const float* __restrict__ w3, const float* __restrict__ b3,
          const float* __restrict__ sum2, const float* __restrict__ sq2,
          const float* __restrict__ g2, const float* __restrict__ bb2, float invN,
          unsigned short* __restrict__ z3, float* gsum, float* gsq, int n){
    __shared__ short w3t[128*72];
    __shared__ float a2s[64], c2s[64];
    __shared__ float ssum[128], ssq[128];
    int tid = threadIdx.x;
    if (tid < 128){ ssum[tid] = 0.f; ssq[tid] = 0.f; }
    if (tid < 64) bn_coef(sum2, sq2, g2, bb2, invN, tid, a2s, c2s);
    for (int e = tid; e < 8192; e += 256){
        int k = e >> 7, c = e & 127;
        w3t[c*72 + k] = (short)f2bf(w3[k*128 + c]);
    }
    __syncthreads();

    int lane = tid & 63, wid = tid >> 6;
    int l15 = lane & 15, lg = lane >> 4;

#pragma unroll 1
    for (int rg = 0; rg < 4; rg++){
        int p0 = blockIdx.x*256 + rg*64 + wid*16;
        int prow = p0 + l15;
        int prow2 = prow < n ? prow : (n - 1);
        const unsigned short* zrow = z2 + (size_t)prow2*64;

        f32x4 acc[8];
#pragma unroll
        for (int t = 0; t < 8; t++){
            float bv = b3[t*16 + l15];
            acc[t] = (f32x4){bv, bv, bv, bv};
        }

#pragma unroll
        for (int ks = 0; ks < 2; ks++){
            int kbase = ks*32 + lg*8;
            uint4 ua = *(const uint4*)(zrow + kbase);
            float4 av0 = *(const float4*)&a2s[kbase];
            float4 av1 = *(const float4*)&a2s[kbase + 4];
            float4 cv0 = *(const float4*)&c2s[kbase];
            float4 cv1 = *(const float4*)&c2s[kbase + 4];
            bf16x8 af;
            af[0] = (short)f2bf(fmaxf(fmaf(bf2f((unsigned short)(ua.x & 0xFFFFu)), av0.x, cv0.x), 0.f));
            af[1] = (short)f2bf(fmaxf(fmaf(bf2f((unsigned short)(ua.x >> 16)),     av0.y, cv0.y), 0.f));
            af[2] = (short)f2bf(fmaxf(fmaf(bf2f((unsigned short)(ua.y & 0xFFFFu)), av0.z, cv0.z), 0.f));
            af[3] = (short)f2bf(fmaxf(fmaf(bf2f((unsigned short)(ua.y >> 16)),     av0.w, cv0.w), 0.f));
            af[4] = (short)f2bf(fmaxf(fmaf(bf2f((unsigned short)(ua.z & 0xFFFFu)), av1.x, cv1.x), 0.f));
            af[5] = (short)f2bf(fmaxf(fmaf(bf2f((unsigned short)(ua.z >> 16)),     av1.y, cv1.y), 0.f));
            af[6] = (short)f2bf(fmaxf(fmaf(bf2f((unsigned short)(ua.w & 0xFFFFu)), av1.z, cv1.z), 0.f));
            af[7] = (short)f2bf(fmaxf(fmaf(bf2f((unsigned short)(ua.w >> 16)),     av1.w, cv1.w), 0.f));
#pragma unroll
            for (int t = 0; t < 8; t++){
                bf16x8 bf = *(const bf16x8*)&w3t[(t*16 + l15)*72 + kbase];
                acc[t] = __builtin_amdgcn_mfma_f32_16x16x32_bf16(af, bf, acc[t], 0, 0, 0);
            }
        }

#pragma unroll
        for (int t = 0; t < 8; t++){
            int c = t*16 + l15;
            float s = 0.f, q = 0.f;
#pragma unroll
            for (int r = 0; r < 4; r++){
                int pr = p0 + lg*4 + r;
                unsigned short rb = f2bf(acc[t][r]);
                float rv = bf2f(rb);
                if (pr < n){
                    z3[(size_t)pr*128 + c] = rb;
                    s += rv; q += rv*rv;
                }
            }
            s += __shfl_xor(s, 16, 64);  q += __shfl_xor(q, 16, 64);
            s += __shfl_xor(s, 32, 64);  q += __shfl_xor(q, 32, 64);
            if (lg == 0){ atomicAdd(&ssum[c], s); atomicAdd(&ssq[c], q); }
        }
    }
    __syncthreads();
    if (tid < 128){ atomicAdd(gsum + tid, ssum[tid]); atomicAdd(gsq + tid, ssq[tid]); }
}

// ---------- exclusive scan of cnt via block tickets ----------
__global__ __launch_bounds__(256)
void k_off(const unsigned* __restrict__ cnt, unsigned* __restrict__ off,
           unsigned* __restrict__ gctr){
    __shared__ unsigned wtot[4];
    __shared__ unsigned wbase[4];
    int t = threadIdx.x;
    int lane = t & 63, w = t >> 6;
    int base = blockIdx.x * 1024 + t * 4;
    bool ok = base < NCELL;
    unsigned c0 = 0, c1 = 0, c2 = 0, c3 = 0;
    if (ok){ c0 = cnt[base]; c1 = cnt[base+1]; c2 = cnt[base+2]; c3 = cnt[base+3]; }
    unsigned tot = c0 + c1 + c2 + c3;
    unsigned incl = tot;
#pragma unroll
    for (int o = 1; o < 64; o <<= 1){
        unsigned v = __shfl_up(incl, o, 64);
        if (lane >= o) incl += v;
    }
    if (lane == 63) wtot[w] = incl;
    __syncthreads();
    if (t == 0){
        unsigned bt = wtot[0] + wtot[1] + wtot[2] + wtot[3];
        unsigned gb = atomicAdd(gctr, bt);
        unsigned s = 0;
#pragma unroll
        for (int q = 0; q < 4; q++){ wbase[q] = gb + s; s += wtot[q]; }
    }
    __syncthreads();
    if (ok){
        unsigned tb = wbase[w] + incl - tot;
        off[base]   = tb;
        off[base+1] = tb + c0;
        off[base+2] = tb + c0 + c1;
        off[base+3] = tb + c0 + c1 + c2;
    }
}

// ---------- fill per-cell point lists ----------
__global__ __launch_bounds__(256)
void k_fill(const int* __restrict__ ind, const unsigned* __restrict__ rank,
            const unsigned* __restrict__ off, unsigned* __restrict__ list, int n){
    int i = blockIdx.x*256 + threadIdx.x;
    if (i >= n) return;
    int bb = ind[(size_t)i*3], gx = ind[(size_t)i*3+1], gy = ind[(size_t)i*3+2];
    unsigned vox = ((unsigned)bb*GXd + (unsigned)gx)*GYd + (unsigned)gy;
    list[off[vox] + rank[i]] = (unsigned)i;
}

// ---------- layer4 via MFMA (4 row-groups/block), SORTED output ----------
__global__ __launch_bounds__(256)
void k_l4(const unsigned short* __restrict__ z3, const unsigned* __restrict__ list,
          const float* __restrict__ w4, const float* __restrict__ b4,
          const float* __restrict__ sum3, const float* __restrict__ sq3,
          const float* __restrict__ g3, const float* __restrict__ bb3, float invN,
          unsigned short* __restrict__ z4, int n){
    __shared__ short w4t[256*128];           // 64 KB
    __shared__ float a3s[128], c3s[128];
    int tid = threadIdx.x;
    if (tid < 128) bn_coef(sum3, sq3, g3, bb3, invN, tid, a3s, c3s);
    for (int e = tid; e < 16384; e += 256){
        int k2 = e >> 8;
        int c  = e & 255;
        unsigned lo = f2bf(w4[(size_t)(2*k2)*256 + c]);
        unsigned hi = f2bf(w4[(size_t)(2*k2+1)*256 + c]);
        int addr = (c*256 + k2*4) ^ ((c & 7) << 4);
        *(unsigned*)((char*)w4t + addr) = lo | (hi << 16);
    }
    __syncthreads();

    int lane = tid & 63, wid = tid >> 6;
    int l15 = lane & 15, lg = lane >> 4;

#pragma unroll 1
    for (int rg = 0; rg < 4; rg++){
        int p0 = blockIdx.x*256 + rg*64 + wid*16;
        int prow = p0 + l15;
        int prow2 = prow < n ? prow : (n - 1);
        int srow = (int)list[prow2];
        const unsigned short* zrow = z3 + (size_t)srow*128;

        f32x4 acc[16];
#pragma unroll
        for (int t = 0; t < 16; t++){
            float bv = b4[t*16 + l15];
            acc[t] = (f32x4){bv, bv, bv, bv};
        }

#pragma unroll
        for (int ks = 0; ks < 4; ks++){
            int kbase = ks*32 + lg*8;
            uint4 ua = *(const uint4*)(zrow + kbase);
            float4 av0 = *(const float4*)&a3s[kbase];
            float4 av1 = *(const float4*)&a3s[kbase + 4];
            float4 cv0 = *(const float4*)&c3s[kbase];
            float4 cv1 = *(const float4*)&c3s[kbase + 4];
            bf16x8 af;
            af[0] = (short)f2bf(fmaxf(fmaf(bf2f((unsigned short)(ua.x & 0xFFFFu)), av0.x, cv0.x), 0.f));
            af[1] = (short)f2bf(fmaxf(fmaf(bf2f((unsigned short)(ua.x >> 16)),     av0.y, cv0.y), 0.f));
            af[2] = (short)f2bf(fmaxf(fmaf(bf2f((unsigned short)(ua.y & 0xFFFFu)), av0.z, cv0.z), 0.f));
            af[3] = (short)f2bf(fmaxf(fmaf(bf2f((unsigned short)(ua.y >> 16)),     av0.w, cv0.w), 0.f));
            af[4] = (short)f2bf(fmaxf(fmaf(bf2f((unsigned short)(ua.z & 0xFFFFu)), av1.x, cv1.x), 0.f));
            af[5] = (short)f2bf(fmaxf(fmaf(bf2f((unsigned short)(ua.z >> 16)),     av1.y, cv1.y), 0.f));
            af[6] = (short)f2bf(fmaxf(fmaf(bf2f((unsigned short)(ua.w & 0xFFFFu)), av1.z, cv1.z), 0.f));
            af[7] = (short)f2bf(fmaxf(fmaf(bf2f((unsigned short)(ua.w >> 16)),     av1.w, cv1.w), 0.f));
#pragma unroll
            for (int t = 0; t < 16; t++){
                int c = t*16 + l15;
                int addr = (c*256 + kbase*2) ^ ((c & 7) << 4);
                bf16x8 bf = *(const bf16x8*)((const char*)w4t + addr);
                acc[t] = __builtin_amdgcn_mfma_f32_16x16x32_bf16(af, bf, acc[t], 0, 0, 0);
            }
        }

#pragma unroll
        for (int t = 0; t < 16; t++){
#pragma unroll
            for (int r = 0; r < 4; r++){
                int pr = p0 + lg*4 + r;
                if (pr < n)
                    z4[(size_t)pr*256 + t*16 + l15] = f2bf(acc[t][r]);
            }
        }
    }
}

// ---------- FUSED gather-max + 3x3 maxpool + residual, CHANNEL-SPLIT ----------
#define NOCELL 0xFFFFFFFFu
#define OTS 132
__global__ __launch_bounds__(256)
void k_gpool(const unsigned* __restrict__ cnt, const unsigned* __restrict__ off,
             const unsigned short* __restrict__ z4, const unsigned* __restrict__ pres,
             float* __restrict__ out){
    __shared__ unsigned short cm[6*18*128];   // 27648 B
    __shared__ unsigned cno[216];
    int t = threadIdx.x;
    int gy0 = blockIdx.x * 16;
    int gx0 = blockIdx.y * 4;
    int bz  = blockIdx.z;
    int b   = bz >> 1;
    int ch0 = (bz & 1) * 128;
    int ymax = GYd - gy0; if (ymax > 16) ymax = 16;

    for (int e = t; e < 108; e += 256){
        int xx = e / 18, ty = e % 18;
        int gxx = gx0 - 1 + xx, gyy = gy0 - 1 + ty;
        unsigned c = NOCELL, o = 0;
        if ((unsigned)gxx < (unsigned)GXd && (unsigned)gyy < (unsigned)GYd){
            unsigned cell = ((unsigned)b*GXd + gxx)*GYd + gyy;
            c = cnt[cell]; o = off[cell];
        }
        cno[e*2]   = c;
        cno[e*2+1] = o;
    }
    __syncthreads();

    int lane = t & 63, wid = t >> 6;
    const float NEGINF = -__builtin_inff();
    for (int e = wid; e < 108; e += 16){
        unsigned cn_[4], o_[4], n_[4];
#pragma unroll
        for (int k = 0; k < 4; k++){
            int ek = e + k*4;
            bool hv = ek < 108;
            unsigned cc = hv ? cno[ek*2]   : NOCELL;
            unsigned oo = hv ? cno[ek*2+1] : 0;
            cn_[k] = cc;  o_[k] = oo;
            n_[k] = (cc == NOCELL) ? 0u : cc;
        }
        float m0[4], m1[4];                    // m0 = lo channel, m1 = hi channel
#pragma unroll
        for (int k = 0; k < 4; k++){ m0[k] = NEGINF; m1[k] = NEGINF; }
        unsigned nm = 0;
#pragma unroll
        for (int k = 0; k < 4; k++) nm = nm > n_[k] ? nm : n_[k];
        for (unsigned p = 0; p < nm; p++){
#pragma unroll
            for (int k = 0; k < 4; k++){
                if (p < n_[k]){
                    unsigned u = *(const unsigned*)(z4 + (size_t)(o_[k] + p)*256 + ch0 + lane*2);
                    m0[k] = fmaxf(m0[k], __uint_as_float(u << 16));
                    m1[k] = fmaxf(m1[k], __uint_as_float(u & 0xFFFF0000u));
                }
            }
        }
#pragma unroll
        for (int k = 0; k < 4; k++){
            int ek = e + k*4;
            if (ek < 108){
                float a0 = m0[k], a1 = m1[k];
                if (cn_[k] == 0u){ a0 = 0.f; a1 = 0.f; }
                *(unsigned*)&cm[ek*128 + lane*2] =
                    (__float_as_uint(a0) >> 16) | (__float_as_uint(a1) & 0xFFFF0000u);
            }
        }
    }
    __syncthreads();

    int c  = t & 127;
    int gp = t >> 7;
    float rA[2], rB[2];
    float ob[2][16];
#pragma unroll
    for (int gg = 0; gg < 2; gg++){ rA[gg] = 0.f; rB[gg] = 0.f; }
#pragma unroll
    for (int ty = 0; ty < 18; ty++){
        float v[6];
#pragma unroll
        for (int xx = 0; xx < 6; xx++)
            v[xx] = bf2f(cm[(xx*18 + ty)*128 + c]);
        float c3[2];
#pragma unroll
        for (int gg = 0; gg < 2; gg++){
            float va = (gp == 0) ? v[gg]     : v[gg+2];
            float vb = (gp == 0) ? v[gg+1]   : v[gg+3];
            float vc = (gp == 0) ? v[gg+2]   : v[gg+4];
            c3[gg] = fmaxf(fmaxf(va, vb), vc);
        }
        if (ty >= 2){
#pragma unroll
            for (int gg = 0; gg < 2; gg++)
                ob[gg][ty - 2] = fmaxf(fmaxf(rA[gg], rB[gg]), c3[gg]);
        }
#pragma unroll
        for (int gg = 0; gg < 2; gg++){ rA[gg] = rB[gg]; rB[gg] = c3[gg]; }
    }
    __syncthreads();

    unsigned short* ot = cm;
#pragma unroll
    for (int gg = 0; gg < 2; gg++){
        int g = gp*2 + gg;
#pragma unroll
        for (int yl = 0; yl < 16; yl++)
            ot[(g*16 + yl)*OTS + c] = (unsigned short)(__float_as_uint(ob[gg][yl]) >> 16);
    }
    __syncthreads();

    int rsub = lane >> 2;
    int gyq  = lane & 3;
    int y0   = gyq*4;
#pragma unroll
    for (int it = 0; it < 8; it++){
        int r  = wid*128 + it*16 + rsub;
        int gx = r >> 7;
        int c2 = r & 127;
        if (y0 < ymax){
            float4 o4;
            o4.x = bf2f(ot[(gx*16 + y0+0)*OTS + c2]);
            o4.y = bf2f(ot[(gx*16 + y0+1)*OTS + c2]);
            o4.z = bf2f(ot[(gx*16 + y0+2)*OTS + c2]);
            o4.w = bf2f(ot[(gx*16 + y0+3)*OTS + c2]);
            *(float4*)(out + ((size_t)b*258 + ch0 + c2)*GXY
                       + (size_t)(gx0+gx)*GYd + gy0 + y0) = o4;
        }
    }

    // residual channels for this tile (even-z blocks only)
    if ((bz & 1) == 0 && t < 128){
        int r  = t >> 6;                       // 0/1
        int g  = (t >> 4) & 3;                 // 0..3
        int y  = t & 15;
        if (y < ymax){
            unsigned u = pres[((size_t)b*2 + r)*GXY + (size_t)(gx0+g)*GYd + gy0 + y];
            float f = u ? unmapf(u) : 0.f;
            out[((size_t)b*258 + 256 + r)*GXY + (size_t)(gx0+g)*GYd + gy0 + y] = f;
        }
    }
}

extern "C" void kernel_launch(void* const* d_in, const int* in_sizes, int n_in,
                              void* d_out, int out_size, void* d_ws, size_t ws_size,
                              hipStream_t stream){
    (void)n_in; (void)out_size; (void)ws_size;
    const float* fea   = (const float*)d_in[0];
    const int*   ind   = (const int*)  d_in[1];
    const float* bn0_g = (const float*)d_in[2];
    const float* bn0_b = (const float*)d_in[3];
    const float* w1    = (const float*)d_in[4];
    const float* b1    = (const float*)d_in[5];
    const float* bn1_g = (const float*)d_in[6];
    const float* bn1_b = (const float*)d_in[7];
    const float* w2    = (const float*)d_in[8];
    const float* b2    = (const float*)d_in[9];
    const float* bn2_g = (const float*)d_in[10];
    const float* bn2_b = (const float*)d_in[11];
    const float* w3    = (const float*)d_in[12];
    const float* b3    = (const float*)d_in[13];
    const float* bn3_g = (const float*)d_in[14];
    const float* bn3_b = (const float*)d_in[15];
    const float* w4    = (const float*)d_in[16];
    const float* b4    = (const float*)d_in[17];

    int n = in_sizes[0] / 11;
    float invN = 1.0f / (float)n;

    // ---- ws layout ----
    const size_t Z4_B     = (size_t)240000*256*2;
    const size_t POOL_B   = (size_t)NCELL*256*2;        // arena for z1/z2/z3
    const size_t PRES_B   = (size_t)NBd*2*GXY*4;
    const size_t CNT_B    = (size_t)NCELL*4;
    const size_t STAT_B   = 960*4;
    const size_t GCTR_B   = 256;

    char* base = (char*)d_ws;
    unsigned short* z4 = (unsigned short*)base;
    unsigned short* z1 = (unsigned short*)(base + Z4_B);
    unsigned short* z2 = (unsigned short*)(base + Z4_B + 15360000);
    unsigned short* z3 = (unsigned short*)(base + Z4_B + 46080000);
    unsigned* pres  = (unsigned*)(base + Z4_B + POOL_B);
    unsigned* cnt   = (unsigned*)((char*)pres + PRES_B);
    float*    stats = (float*)((char*)cnt + CNT_B);
    unsigned* gctr  = (unsigned*)((char*)stats + STAT_B);
    unsigned* off   = (unsigned*)((char*)gctr + GCTR_B);
    unsigned* list  = (unsigned*)((char*)off + CNT_B);
    unsigned* rank  = (unsigned*)((char*)list + (size_t)240000*4);

    float* sum0 = stats;       float* sq0 = stats + 16;
    float* sum1 = stats + 32;  float* sq1 = stats + 64;
    float* sum2 = stats + 96;  float* sq2 = stats + 160;
    float* sum3 = stats + 224; float* sq3 = stats + 352;

    hipMemsetAsync(pres, 0, PRES_B + CNT_B + STAT_B + GCTR_B, stream);

    int nb = (n + 255) / 256;
    k_stats0<<<nb, 256, 0, stream>>>(fea, sum0, sq0, n);
    k_l1<<<nb, 256, 0, stream>>>(fea, ind, w1, b1, sum0, sq0, bn0_g, bn0_b, invN,
                                 z1, pres, cnt, rank, sum1, sq1, n);
    k_l2<<<nb, 256, 0, stream>>>(z1, w2, b2, sum1, sq1, bn1_g, bn1_b, invN,
                                 z2, sum2, sq2, n);
    k_l3<<<nb, 256, 0, stream>>>(z2, w3, b3, sum2, sq2, bn2_g, bn2_b, invN,
                                 z3, sum3, sq3, n);

    k_off <<<(NCELL + 1023)/1024, 256, 0, stream>>>(cnt, off, gctr);
    k_fill<<<nb, 256, 0, stream>>>(ind, rank, off, list, n);

    k_l4<<<nb, 256, 0, stream>>>(z3, list, w4, b4, sum3, sq3, bn3_g, bn3_b, invN,
                                 z4, n);

    k_gpool<<<dim3(23, 120, 4), 256, 0, stream>>>(cnt, off, z4, pres, (float*)d_out);
}

// Round 21
// 505.368 us; speedup vs baseline: 1.5760x; 1.0554x over previous
//
#include <hip/hip_runtime.h>
#include <cstdint>
#include <cstddef>

#define GXd 480
#define GYd 360
#define NBd 2
#define GXY (480*360)
#define NCELL (NBd*GXY)
#define EPSBN 1e-5f

typedef float  f32x4  __attribute__((ext_vector_type(4)));
typedef short  bf16x8 __attribute__((ext_vector_type(8)));

// ---------- order-preserving float <-> uint map (residual atomics only) ----------
__device__ __forceinline__ unsigned mapf(float f){
    unsigned u = __float_as_uint(f);
    return (u & 0x80000000u) ? ~u : (u | 0x80000000u);
}
__device__ __forceinline__ float unmapf(unsigned m){
    return (m & 0x80000000u) ? __uint_as_float(m ^ 0x80000000u)
                             : __uint_as_float(~m);
}

// ---------- bf16 helpers ----------
__device__ __forceinline__ unsigned short f2bf(float f){            // RTN-even
    unsigned u = __float_as_uint(f);
    unsigned r = (u + 0x7FFFu + ((u >> 16) & 1u)) >> 16;
    return (unsigned short)r;
}
__device__ __forceinline__ float bf2f(unsigned short s){
    return __uint_as_float(((unsigned)s) << 16);
}

// ---------- dense layer helper ----------
template<int DIN, int DOUT>
__device__ __forceinline__ void dense(const float (&in)[DIN], float (&out)[DOUT],
                                      const float* __restrict__ w,
                                      const float* __restrict__ b){
#pragma unroll
    for (int j = 0; j < DOUT; j++) out[j] = b[j];
#pragma unroll
    for (int d = 0; d < DIN; d++){
        float v = in[d];
#pragma unroll
        for (int j = 0; j < DOUT; j++) out[j] = fmaf(v, w[d*DOUT + j], out[j]);
    }
}

// ---------- block-level sum/sumsq reduction ----------
template<int D>
__device__ __forceinline__ void reduce_stats(const float (&h)[D], bool valid,
                                             float* __restrict__ gsum,
                                             float* __restrict__ gsq){
    __shared__ float ssum[D];
    __shared__ float ssq[D];
    int tid = threadIdx.x;
    for (int t = tid; t < D; t += 256){ ssum[t] = 0.f; ssq[t] = 0.f; }
    __syncthreads();
#pragma unroll
    for (int j = 0; j < D; j++){
        float v = valid ? h[j] : 0.f;
        float s = v * v;
#pragma unroll
        for (int o = 32; o > 0; o >>= 1){
            v += __shfl_down(v, o, 64);
            s += __shfl_down(s, o, 64);
        }
        if ((tid & 63) == 0){
            atomicAdd(&ssum[j], v);
            atomicAdd(&ssq[j], s);
        }
    }
    __syncthreads();
    for (int t = tid; t < D; t += 256){
        atomicAdd(&gsum[t], ssum[t]);
        atomicAdd(&gsq[t], ssq[t]);
    }
}

// ---------- BN coefficient from sums (inline finalize) ----------
__device__ __forceinline__ void bn_coef(const float* __restrict__ sum,
                                        const float* __restrict__ sq,
                                        const float* __restrict__ g,
                                        const float* __restrict__ bb,
                                        float invN, int c,
                                        float* __restrict__ a_out,
                                        float* __restrict__ c_out){
    float mu  = sum[c] * invN;
    float var = fmaf(-mu, mu, sq[c] * invN);
    float rs  = rsqrtf(var + EPSBN);
    float a   = rs * g[c];
    a_out[c] = a;
    c_out[c] = fmaf(-mu, a, bb[c]);
}

// ---------- stats of raw input columns 0..8 ----------
__global__ __launch_bounds__(256)
void k_stats0(const float* __restrict__ fea, float* gsum, float* gsq, int n){
    int i = blockIdx.x*256 + threadIdx.x;
    bool valid = i < n;
    int i2 = valid ? i : 0;
    float x[9];
#pragma unroll
    for (int d = 0; d < 9; d++) x[d] = fea[(size_t)i2*11 + d];
    reduce_stats<9>(x, valid, gsum, gsq);
}

// ---------- layer1: bn0 (inline fin) -> 9x32; z1 bf16; stats(rounded); cnt/rank; res ----------
__global__ __launch_bounds__(256)
void k_l1(const float* __restrict__ fea, const int* __restrict__ ind,
          const float* __restrict__ w1, const float* __restrict__ b1,
          const float* __restrict__ sum0, const float* __restrict__ sq0,
          const float* __restrict__ g0, const float* __restrict__ bb0, float invN,
          unsigned short* __restrict__ z1, unsigned* __restrict__ pres,
          unsigned* __restrict__ cnt, unsigned* __restrict__ rank,
          float* gsum, float* gsq, int n){
    __shared__ float a0s[9], c0s[9];
    int tid = threadIdx.x;
    if (tid < 9) bn_coef(sum0, sq0, g0, bb0, invN, tid, a0s, c0s);
    __syncthreads();

    int i = blockIdx.x*256 + tid;
    bool valid = i < n;
    int i2 = valid ? i : 0;
    float x[9];
#pragma unroll
    for (int d = 0; d < 9; d++) x[d] = fmaf(fea[(size_t)i2*11 + d], a0s[d], c0s[d]);
    float h[32];
    dense<9,32>(x, h, w1, b1);
    unsigned ob[16];
#pragma unroll
    for (int m = 0; m < 16; m++){
        unsigned short lo = f2bf(h[2*m]);
        unsigned short hi = f2bf(h[2*m+1]);
        ob[m] = (unsigned)lo | ((unsigned)hi << 16);
        h[2*m]   = bf2f(lo);
        h[2*m+1] = bf2f(hi);
    }
    if (valid){
        uint4* dst = (uint4*)(z1 + (size_t)i*32);
#pragma unroll
        for (int q = 0; q < 4; q++)
            dst[q] = make_uint4(ob[q*4], ob[q*4+1], ob[q*4+2], ob[q*4+3]);
        float r0 = fea[(size_t)i*11 + 9];
        float r1 = fea[(size_t)i*11 + 10];
        int bb = ind[(size_t)i*3 + 0];
        int gx = ind[(size_t)i*3 + 1];
        int gy = ind[(size_t)i*3 + 2];
        unsigned vox = ((unsigned)bb*GXd + (unsigned)gx)*GYd + (unsigned)gy;
        rank[i] = atomicAdd(&cnt[vox], 1u);
        size_t rbase = (size_t)bb*2*GXY + (size_t)gx*GYd + gy;
        atomicMax(pres + rbase,       mapf(r0));
        atomicMax(pres + rbase + GXY, mapf(r1));
    }
    reduce_stats<32>(h, valid, gsum, gsq);
}

// ---------- layer2 via MFMA (8 row-groups/block): z2 bf16; stats(rounded) ----------
__global__ __launch_bounds__(256)
void k_l2(const unsigned short* __restrict__ z1,
          const float* __restrict__ w2, const float* __restrict__ b2,
          const float* __restrict__ sum1, const float* __restrict__ sq1,
          const float* __restrict__ g1, const float* __restrict__ bb1, float invN,
          unsigned short* __restrict__ z2, float* gsum, float* gsq, int n){
    __shared__ short w2t[64*40];
    __shared__ float a1s[32], c1s[32];
    __shared__ float ssum[64], ssq[64];
    int tid = threadIdx.x;
    if (tid < 64){ ssum[tid] = 0.f; ssq[tid] = 0.f; }
    if (tid < 32) bn_coef(sum1, sq1, g1, bb1, invN, tid, a1s, c1s);
    for (int e = tid; e < 2048; e += 256){
        int k = e >> 6, c = e & 63;
        w2t[c*40 + k] = (short)f2bf(w2[k*64 + c]);
    }
    __syncthreads();

    int lane = tid & 63, wid = tid >> 6;
    int l15 = lane & 15, lg = lane >> 4;
    int kbase = lg*8;
    float4 av0 = *(const float4*)&a1s[kbase];
    float4 av1 = *(const float4*)&a1s[kbase + 4];
    float4 cv0 = *(const float4*)&c1s[kbase];
    float4 cv1 = *(const float4*)&c1s[kbase + 4];

#pragma unroll 1
    for (int rg = 0; rg < 8; rg++){
        int p0 = blockIdx.x*512 + rg*64 + wid*16;
        int prow = p0 + l15;
        int prow2 = prow < n ? prow : (n - 1);
        uint4 ua = *(const uint4*)(z1 + (size_t)prow2*32 + kbase);
        bf16x8 af;
        af[0] = (short)f2bf(fmaxf(fmaf(bf2f((unsigned short)(ua.x & 0xFFFFu)), av0.x, cv0.x), 0.f));
        af[1] = (short)f2bf(fmaxf(fmaf(bf2f((unsigned short)(ua.x >> 16)),     av0.y, cv0.y), 0.f));
        af[2] = (short)f2bf(fmaxf(fmaf(bf2f((unsigned short)(ua.y & 0xFFFFu)), av0.z, cv0.z), 0.f));
        af[3] = (short)f2bf(fmaxf(fmaf(bf2f((unsigned short)(ua.y >> 16)),     av0.w, cv0.w), 0.f));
        af[4] = (short)f2bf(fmaxf(fmaf(bf2f((unsigned short)(ua.z & 0xFFFFu)), av1.x, cv1.x), 0.f));
        af[5] = (short)f2bf(fmaxf(fmaf(bf2f((unsigned short)(ua.z >> 16)),     av1.y, cv1.y), 0.f));
        af[6] = (short)f2bf(fmaxf(fmaf(bf2f((unsigned short)(ua.w & 0xFFFFu)), av1.z, cv1.z), 0.f));
        af[7] = (short)f2bf(fmaxf(fmaf(bf2f((unsigned short)(ua.w >> 16)),     av1.w, cv1.w), 0.f));

        f32x4 acc[4];
#pragma unroll
        for (int t = 0; t < 4; t++){
            float bv = b2[t*16 + l15];
            acc[t] = (f32x4){bv, bv, bv, bv};
        }
#pragma unroll
        for (int t = 0; t < 4; t++){
            bf16x8 bf = *(const bf16x8*)&w2t[(t*16 + l15)*40 + kbase];
            acc[t] = __builtin_amdgcn_mfma_f32_16x16x32_bf16(af, bf, acc[t], 0, 0, 0);
        }

#pragma unroll
        for (int t = 0; t < 4; t++){
            int c = t*16 + l15;
            float s = 0.f, q = 0.f;
#pragma unroll
            for (int r = 0; r < 4; r++){
                int pr = p0 + lg*4 + r;
                unsigned short rb = f2bf(acc[t][r]);
                float rv = bf2f(rb);
                if (pr < n){
                    z2[(size_t)pr*64 + c] = rb;
                    s += rv; q += rv*rv;
                }
            }
            s += __shfl_xor(s, 16, 64);  q += __shfl_xor(q, 16, 64);
            s += __shfl_xor(s, 32, 64);  q += __shfl_xor(q, 32, 64);
            if (lg == 0){ atomicAdd(&ssum[c], s); atomicAdd(&ssq[c], q); }
        }
    }
    __syncthreads();
    if (tid < 64){ atomicAdd(gsum + tid, ssum[tid]); atomicAdd(gsq + tid, ssq[tid]); }
}

// ---------- layer3 via MFMA (8 row-groups/block): z3 bf16; stats(rounded) ----------
__global__ __launch_bounds__(256)
void k_l3(const unsigned short* __restrict__ z2,
          const float* __restrict__ w3, const float* __restrict__ b3,
          const float* __restrict__ sum2, const float* __restrict__ sq2,
          const float* __restrict__ g2, const float* __restrict__ bb2, float invN,
          unsigned short* __restrict__ z3, float* gsum, float* gsq, int n){
    __shared__ short w3t[128*72];
    __shared__ float a2s[64], c2s[64];
    __shared__ float ssum[128], ssq[128];
    int tid = threadIdx.x;
    if (tid < 128){ ssum[tid] = 0.f; ssq[tid] = 0.f; }
    if (tid < 64) bn_coef(sum2, sq2, g2, bb2, invN, tid, a2s, c2s);
    for (int e = tid; e < 8192; e += 256){
        int k = e >> 7, c = e & 127;
        w3t[c*72 + k] = (short)f2bf(w3[k*128 + c]);
    }
    __syncthreads();

    int lane = tid & 63, wid = tid >> 6;
    int l15 = lane & 15, lg = lane >> 4;

#pragma unroll 1
    for (int rg = 0; rg < 8; rg++){
        int p0 = blockIdx.x*512 + rg*64 + wid*16;
        int prow = p0 + l15;
        int prow2 = prow < n ? prow : (n - 1);
        const unsigned short* zrow = z2 + (size_t)prow2*64;

        f32x4 acc[8];
#pragma unroll
        for (int t = 0; t < 8; t++){
            float bv = b3[t*16 + l15];
            acc[t] = (f32x4){bv, bv, bv, bv};
        }

#pragma unroll
        for (int ks = 0; ks < 2; ks++){
            int kbase = ks*32 + lg*8;
            uint4 ua = *(const uint4*)(zrow + kbase);
            float4 av0 = *(const float4*)&a2s[kbase];
            float4 av1 = *(const float4*)&a2s[kbase + 4];
            float4 cv0 = *(const float4*)&c2s[kbase];
            float4 cv1 = *(const float4*)&c2s[kbase + 4];
            bf16x8 af;
            af[0] = (short)f2bf(fmaxf(fmaf(bf2f((unsigned short)(ua.x & 0xFFFFu)), av0.x, cv0.x), 0.f));
            af[1] = (short)f2bf(fmaxf(fmaf(bf2f((unsigned short)(ua.x >> 16)),     av0.y, cv0.y), 0.f));
            af[2] = (short)f2bf(fmaxf(fmaf(bf2f((unsigned short)(ua.y & 0xFFFFu)), av0.z, cv0.z), 0.f));
            af[3] = (short)f2bf(fmaxf(fmaf(bf2f((unsigned short)(ua.y >> 16)),     av0.w, cv0.w), 0.f));
            af[4] = (short)f2bf(fmaxf(fmaf(bf2f((unsigned short)(ua.z & 0xFFFFu)), av1.x, cv1.x), 0.f));
            af[5] = (short)f2bf(fmaxf(fmaf(bf2f((unsigned short)(ua.z >> 16)),     av1.y, cv1.y), 0.f));
            af[6] = (short)f2bf(fmaxf(fmaf(bf2f((unsigned short)(ua.w & 0xFFFFu)), av1.z, cv1.z), 0.f));
            af[7] = (short)f2bf(fmaxf(fmaf(bf2f((unsigned short)(ua.w >> 16)),     av1.w, cv1.w), 0.f));
#pragma unroll
            for (int t = 0; t < 8; t++){
                bf16x8 bf = *(const bf16x8*)&w3t[(t*16 + l15)*72 + kbase];
                acc[t] = __builtin_amdgcn_mfma_f32_16x16x32_bf16(af, bf, acc[t], 0, 0, 0);
            }
        }

#pragma unroll
        for (int t = 0; t < 8; t++){
            int c = t*16 + l15;
            float s = 0.f, q = 0.f;
#pragma unroll
            for (int r = 0; r < 4; r++){
                int pr = p0 + lg*4 + r;
                unsigned short rb = f2bf(acc[t][r]);
                float rv = bf2f(rb);
                if (pr < n){
                    z3[(size_t)pr*128 + c] = rb;
                    s += rv; q += rv*rv;
                }
            }
            s += __shfl_xor(s, 16, 64);  q += __shfl_xor(q, 16, 64);
            s += __shfl_xor(s, 32, 64);  q += __shfl_xor(q, 32, 64);
            if (lg == 0){ atomicAdd(&ssum[c], s); atomicAdd(&ssq[c], q); }
        }
    }
    __syncthreads();
    if (tid < 128){ atomicAdd(gsum + tid, ssum[tid]); atomicAdd(gsq + tid, ssq[tid]); }
}

// ---------- exclusive scan of cnt via block tickets ----------
__global__ __launch_bounds__(256)
void k_off(const unsigned* __restrict__ cnt, unsigned* __restrict__ off,
           unsigned* __restrict__ gctr){
    __shared__ unsigned wtot[4];
    __shared__ unsigned wbase[4];
    int t = threadIdx.x;
    int lane = t & 63, w = t >> 6;
    int base = blockIdx.x * 1024 + t * 4;
    bool ok = base < NCELL;
    unsigned c0 = 0, c1 = 0, c2 = 0, c3 = 0;
    if (ok){ c0 = cnt[base]; c1 = cnt[base+1]; c2 = cnt[base+2]; c3 = cnt[base+3]; }
    unsigned tot = c0 + c1 + c2 + c3;
    unsigned incl = tot;
#pragma unroll
    for (int o = 1; o < 64; o <<= 1){
        unsigned v = __shfl_up(incl, o, 64);
        if (lane >= o) incl += v;
    }
    if (lane == 63) wtot[w] = incl;
    __syncthreads();
    if (t == 0){
        unsigned bt = wtot[0] + wtot[1] + wtot[2] + wtot[3];
        unsigned gb = atomicAdd(gctr, bt);
        unsigned s = 0;
#pragma unroll
        for (int q = 0; q < 4; q++){ wbase[q] = gb + s; s += wtot[q]; }
    }
    __syncthreads();
    if (ok){
        unsigned tb = wbase[w] + incl - tot;
        off[base]   = tb;
        off[base+1] = tb + c0;
        off[base+2] = tb + c0 + c1;
        off[base+3] = tb + c0 + c1 + c2;
    }
}

// ---------- fill per-cell point lists ----------
__global__ __launch_bounds__(256)
void k_fill(const int* __restrict__ ind, const unsigned* __restrict__ rank,
            const unsigned* __restrict__ off, unsigned* __restrict__ list, int n){
    int i = blockIdx.x*256 + threadIdx.x;
    if (i >= n) return;
    int bb = ind[(size_t)i*3], gx = ind[(size_t)i*3+1], gy = ind[(size_t)i*3+2];
    unsigned vox = ((unsigned)bb*GXd + (unsigned)gx)*GYd + (unsigned)gy;
    list[off[vox] + rank[i]] = (unsigned)i;
}

// ---------- layer4 via MFMA (8 row-groups/block), SORTED output ----------
__global__ __launch_bounds__(256)
void k_l4(const unsigned short* __restrict__ z3, const unsigned* __restrict__ list,
          const float* __restrict__ w4, const float* __restrict__ b4,
          const float* __restrict__ sum3, const float* __restrict__ sq3,
          const float* __restrict__ g3, const float* __restrict__ bb3, float invN,
          unsigned short* __restrict__ z4, int n){
    __shared__ short w4t[256*128];           // 64 KB
    __shared__ float a3s[128], c3s[128];
    int tid = threadIdx.x;
    if (tid < 128) bn_coef(sum3, sq3, g3, bb3, invN, tid, a3s, c3s);
    for (int e = tid; e < 16384; e += 256){
        int k2 = e >> 8;
        int c  = e & 255;
        unsigned lo = f2bf(w4[(size_t)(2*k2)*256 + c]);
        unsigned hi = f2bf(w4[(size_t)(2*k2+1)*256 + c]);
        int addr = (c*256 + k2*4) ^ ((c & 7) << 4);
        *(unsigned*)((char*)w4t + addr) = lo | (hi << 16);
    }
    __syncthreads();

    int lane = tid & 63, wid = tid >> 6;
    int l15 = lane & 15, lg = lane >> 4;

#pragma unroll 1
    for (int rg = 0; rg < 8; rg++){
        int p0 = blockIdx.x*512 + rg*64 + wid*16;
        int prow = p0 + l15;
        int prow2 = prow < n ? prow : (n - 1);
        int srow = (int)list[prow2];
        const unsigned short* zrow = z3 + (size_t)srow*128;

        f32x4 acc[16];
#pragma unroll
        for (int t = 0; t < 16; t++){
            float bv = b4[t*16 + l15];
            acc[t] = (f32x4){bv, bv, bv, bv};
        }

#pragma unroll
        for (int ks = 0; ks < 4; ks++){
            int kbase = ks*32 + lg*8;
            uint4 ua = *(const uint4*)(zrow + kbase);
            float4 av0 = *(const float4*)&a3s[kbase];
            float4 av1 = *(const float4*)&a3s[kbase + 4];
            float4 cv0 = *(const float4*)&c3s[kbase];
            float4 cv1 = *(const float4*)&c3s[kbase + 4];
            bf16x8 af;
            af[0] = (short)f2bf(fmaxf(fmaf(bf2f((unsigned short)(ua.x & 0xFFFFu)), av0.x, cv0.x), 0.f));
            af[1] = (short)f2bf(fmaxf(fmaf(bf2f((unsigned short)(ua.x >> 16)),     av0.y, cv0.y), 0.f));
            af[2] = (short)f2bf(fmaxf(fmaf(bf2f((unsigned short)(ua.y & 0xFFFFu)), av0.z, cv0.z), 0.f));
            af[3] = (short)f2bf(fmaxf(fmaf(bf2f((unsigned short)(ua.y >> 16)),     av0.w, cv0.w), 0.f));
            af[4] = (short)f2bf(fmaxf(fmaf(bf2f((unsigned short)(ua.z & 0xFFFFu)), av1.x, cv1.x), 0.f));
            af[5] = (short)f2bf(fmaxf(fmaf(bf2f((unsigned short)(ua.z >> 16)),     av1.y, cv1.y), 0.f));
            af[6] = (short)f2bf(fmaxf(fmaf(bf2f((unsigned short)(ua.w & 0xFFFFu)), av1.z, cv1.z), 0.f));
            af[7] = (short)f2bf(fmaxf(fmaf(bf2f((unsigned short)(ua.w >> 16)),     av1.w, cv1.w), 0.f));
#pragma unroll
            for (int t = 0; t < 16; t++){
                int c = t*16 + l15;
                int addr = (c*256 + kbase*2) ^ ((c & 7) << 4);
                bf16x8 bf = *(const bf16x8*)((const char*)w4t + addr);
                acc[t] = __builtin_amdgcn_mfma_f32_16x16x32_bf16(af, bf, acc[t], 0, 0, 0);
            }
        }

#pragma unroll
        for (int t = 0; t < 16; t++){
#pragma unroll
            for (int r = 0; r < 4; r++){
                int pr = p0 + lg*4 + r;
                if (pr < n)
                    z4[(size_t)pr*256 + t*16 + l15] = f2bf(acc[t][r]);
            }
        }
    }
}

// ---------- FUSED gather-max + 3x3 maxpool + residual, CHANNEL-SPLIT ----------
#define NOCELL 0xFFFFFFFFu
#define OTS 132
__global__ __launch_bounds__(256)
void k_gpool(const unsigned* __restrict__ cnt, const unsigned* __restrict__ off,
             const unsigned short* __restrict__ z4, const unsigned* __restrict__ pres,
             float* __restrict__ out){
    __shared__ unsigned short cm[6*18*128];   // 27648 B
    __shared__ unsigned cno[216];
    int t = threadIdx.x;
    int gy0 = blockIdx.x * 16;
    int gx0 = blockIdx.y * 4;
    int bz  = blockIdx.z;
    int b   = bz >> 1;
    int ch0 = (bz & 1) * 128;
    int ymax = GYd - gy0; if (ymax > 16) ymax = 16;

    for (int e = t; e < 108; e += 256){
        int xx = e / 18, ty = e % 18;
        int gxx = gx0 - 1 + xx, gyy = gy0 - 1 + ty;
        unsigned c = NOCELL, o = 0;
        if ((unsigned)gxx < (unsigned)GXd && (unsigned)gyy < (unsigned)GYd){
            unsigned cell = ((unsigned)b*GXd + gxx)*GYd + gyy;
            c = cnt[cell]; o = off[cell];
        }
        cno[e*2]   = c;
        cno[e*2+1] = o;
    }
    __syncthreads();

    int lane = t & 63, wid = t >> 6;
    const float NEGINF = -__builtin_inff();
    for (int e = wid; e < 108; e += 16){
        unsigned cn_[4], o_[4], n_[4];
#pragma unroll
        for (int k = 0; k < 4; k++){
            int ek = e + k*4;
            bool hv = ek < 108;
            unsigned cc = hv ? cno[ek*2]   : NOCELL;
            unsigned oo = hv ? cno[ek*2+1] : 0;
            cn_[k] = cc;  o_[k] = oo;
            n_[k] = (cc == NOCELL) ? 0u : cc;
        }
        float m0[4], m1[4];
#pragma unroll
        for (int k = 0; k < 4; k++){ m0[k] = NEGINF; m1[k] = NEGINF; }
        unsigned nm = 0;
#pragma unroll
        for (int k = 0; k < 4; k++) nm = nm > n_[k] ? nm : n_[k];
        for (unsigned p = 0; p < nm; p++){
#pragma unroll
            for (int k = 0; k < 4; k++){
                if (p < n_[k]){
                    unsigned u = *(const unsigned*)(z4 + (size_t)(o_[k] + p)*256 + ch0 + lane*2);
                    m0[k] = fmaxf(m0[k], __uint_as_float(u << 16));
                    m1[k] = fmaxf(m1[k], __uint_as_float(u & 0xFFFF0000u));
                }
            }
        }
#pragma unroll
        for (int k = 0; k < 4; k++){
            int ek = e + k*4;
            if (ek < 108){
                float a0 = m0[k], a1 = m1[k];
                if (cn_[k] == 0u){ a0 = 0.f; a1 = 0.f; }
                *(unsigned*)&cm[ek*128 + lane*2] =
                    (__float_as_uint(a0) >> 16) | (__float_as_uint(a1) & 0xFFFF0000u);
            }
        }
    }
    __syncthreads();

    int c  = t & 127;
    int gp = t >> 7;
    float rA[2], rB[2];
    float ob[2][16];
#pragma unroll
    for (int gg = 0; gg < 2; gg++){ rA[gg] = 0.f; rB[gg] = 0.f; }
#pragma unroll
    for (int ty = 0; ty < 18; ty++){
        float v[6];
#pragma unroll
        for (int xx = 0; xx < 6; xx++)
            v[xx] = bf2f(cm[(xx*18 + ty)*128 + c]);
        float c3[2];
#pragma unroll
        for (int gg = 0; gg < 2; gg++){
            float va = (gp == 0) ? v[gg]     : v[gg+2];
            float vb = (gp == 0) ? v[gg+1]   : v[gg+3];
            float vc = (gp == 0) ? v[gg+2]   : v[gg+4];
            c3[gg] = fmaxf(fmaxf(va, vb), vc);
        }
        if (ty >= 2){
#pragma unroll
            for (int gg = 0; gg < 2; gg++)
                ob[gg][ty - 2] = fmaxf(fmaxf(rA[gg], rB[gg]), c3[gg]);
        }
#pragma unroll
        for (int gg = 0; gg < 2; gg++){ rA[gg] = rB[gg]; rB[gg] = c3[gg]; }
    }
    __syncthreads();

    unsigned short* ot = cm;
#pragma unroll
    for (int gg = 0; gg < 2; gg++){
        int g = gp*2 + gg;
#pragma unroll
        for (int yl = 0; yl < 16; yl++)
            ot[(g*16 + yl)*OTS + c] = (unsigned short)(__float_as_uint(ob[gg][yl]) >> 16);
    }
    __syncthreads();

    int rsub = lane >> 2;
    int gyq  = lane & 3;
    int y0   = gyq*4;
#pragma unroll
    for (int it = 0; it < 8; it++){
        int r  = wid*128 + it*16 + rsub;
        int gx = r >> 7;
        int c2 = r & 127;
        if (y0 < ymax){
            float4 o4;
            o4.x = bf2f(ot[(gx*16 + y0+0)*OTS + c2]);
            o4.y = bf2f(ot[(gx*16 + y0+1)*OTS + c2]);
            o4.z = bf2f(ot[(gx*16 + y0+2)*OTS + c2]);
            o4.w = bf2f(ot[(gx*16 + y0+3)*OTS + c2]);
            *(float4*)(out + ((size_t)b*258 + ch0 + c2)*GXY
                       + (size_t)(gx0+gx)*GYd + gy0 + y0) = o4;
        }
    }

    // residual channels for this tile (even-z blocks only)
    if ((bz & 1) == 0 && t < 128){
        int r  = t >> 6;                       // 0/1
        int g  = (t >> 4) & 3;                 // 0..3
        int y  = t & 15;
        if (y < ymax){
            unsigned u = pres[((size_t)b*2 + r)*GXY + (size_t)(gx0+g)*GYd + gy0 + y];
            float f = u ? unmapf(u) : 0.f;
            out[((size_t)b*258 + 256 + r)*GXY + (size_t)(gx0+g)*GYd + gy0 + y] = f;
        }
    }
}

extern "C" void kernel_launch(void* const* d_in, const int* in_sizes, int n_in,
                              void* d_out, int out_size, void* d_ws, size_t ws_size,
                              hipStream_t stream){
    (void)n_in; (void)out_size; (void)ws_size;
    const float* fea   = (const float*)d_in[0];
    const int*   ind   = (const int*)  d_in[1];
    const float* bn0_g = (const float*)d_in[2];
    const float* bn0_b = (const float*)d_in[3];
    const float* w1    = (const float*)d_in[4];
    const float* b1    = (const float*)d_in[5];
    const float* bn1_g = (const float*)d_in[6];
    const float* bn1_b = (const float*)d_in[7];
    const float* w2    = (const float*)d_in[8];
    const float* b2    = (const float*)d_in[9];
    const float* bn2_g = (const float*)d_in[10];
    const float* bn2_b = (const float*)d_in[11];
    const float* w3    = (const float*)d_in[12];
    const float* b3    = (const float*)d_in[13];
    const float* bn3_g = (const float*)d_in[14];
    const float* bn3_b = (const float*)d_in[15];
    const float* w4    = (const float*)d_in[16];
    const float* b4    = (const float*)d_in[17];

    int n = in_sizes[0] / 11;
    float invN = 1.0f / (float)n;

    // ---- ws layout ----
    const size_t Z4_B     = (size_t)240000*256*2;
    const size_t POOL_B   = (size_t)NCELL*256*2;        // arena for z1/z2/z3
    const size_t PRES_B   = (size_t)NBd*2*GXY*4;
    const size_t CNT_B    = (size_t)NCELL*4;
    const size_t STAT_B   = 960*4;
    const size_t GCTR_B   = 256;

    char* base = (char*)d_ws;
    unsigned short* z4 = (unsigned short*)base;
    unsigned short* z1 = (unsigned short*)(base + Z4_B);
    unsigned short* z2 = (unsigned short*)(base + Z4_B + 15360000);
    unsigned short* z3 = (unsigned short*)(base + Z4_B + 46080000);
    unsigned* pres  = (unsigned*)(base + Z4_B + POOL_B);
    unsigned* cnt   = (unsigned*)((char*)pres + PRES_B);
    float*    stats = (float*)((char*)cnt + CNT_B);
    unsigned* gctr  = (unsigned*)((char*)stats + STAT_B);
    unsigned* off   = (unsigned*)((char*)gctr + GCTR_B);
    unsigned* list  = (unsigned*)((char*)off + CNT_B);
    unsigned* rank  = (unsigned*)((char*)list + (size_t)240000*4);

    float* sum0 = stats;       float* sq0 = stats + 16;
    float* sum1 = stats + 32;  float* sq1 = stats + 64;
    float* sum2 = stats + 96;  float* sq2 = stats + 160;
    float* sum3 = stats + 224; float* sq3 = stats + 352;

    hipMemsetAsync(pres, 0, PRES_B + CNT_B + STAT_B + GCTR_B, stream);

    int nb = (n + 255) / 256;
    int nb512 = (n + 511) / 512;
    k_stats0<<<nb, 256, 0, stream>>>(fea, sum0, sq0, n);
    k_l1<<<nb, 256, 0, stream>>>(fea, ind, w1, b1, sum0, sq0, bn0_g, bn0_b, invN,
                                 z1, pres, cnt, rank, sum1, sq1, n);
    k_l2<<<nb512, 256, 0, stream>>>(z1, w2, b2, sum1, sq1, bn1_g, bn1_b, invN,
                                    z2, sum2, sq2, n);
    k_l3<<<nb512, 256, 0, stream>>>(z2, w3, b3, sum2, sq2, bn2_g, bn2_b, invN,
                                    z3, sum3, sq3, n);

    k_off <<<(NCELL + 1023)/1024, 256, 0, stream>>>(cnt, off, gctr);
    k_fill<<<nb, 256, 0, stream>>>(ind, rank, off, list, n);

    k_l4<<<nb512, 256, 0, stream>>>(z3, list, w4, b4, sum3, sq3, bn3_g, bn3_b, invN,
                                    z4, n);

    k_gpool<<<dim3(23, 120, 4), 256, 0, stream>>>(cnt, off, z4, pres, (float*)d_out);
}

// Round 22
// 501.353 us; speedup vs baseline: 1.5887x; 1.0080x over previous
//
#include <hip/hip_runtime.h>
#include <cstdint>
#include <cstddef>

#define GXd 480
#define GYd 360
#define NBd 2
#define GXY (480*360)
#define NCELL (NBd*GXY)
#define EPSBN 1e-5f

typedef float  f32x4  __attribute__((ext_vector_type(4)));
typedef short  bf16x8 __attribute__((ext_vector_type(8)));

// ---------- order-preserving float <-> uint map (residual atomics only) ----------
__device__ __forceinline__ unsigned mapf(float f){
    unsigned u = __float_as_uint(f);
    return (u & 0x80000000u) ? ~u : (u | 0x80000000u);
}
__device__ __forceinline__ float unmapf(unsigned m){
    return (m & 0x80000000u) ? __uint_as_float(m ^ 0x80000000u)
                             : __uint_as_float(~m);
}

// ---------- bf16 helpers ----------
__device__ __forceinline__ unsigned short f2bf(float f){            // RTN-even
    unsigned u = __float_as_uint(f);
    unsigned r = (u + 0x7FFFu + ((u >> 16) & 1u)) >> 16;
    return (unsigned short)r;
}
__device__ __forceinline__ float bf2f(unsigned short s){
    return __uint_as_float(((unsigned)s) << 16);
}

// ---------- dense layer helper ----------
template<int DIN, int DOUT>
__device__ __forceinline__ void dense(const float (&in)[DIN], float (&out)[DOUT],
                                      const float* __restrict__ w,
                                      const float* __restrict__ b){
#pragma unroll
    for (int j = 0; j < DOUT; j++) out[j] = b[j];
#pragma unroll
    for (int d = 0; d < DIN; d++){
        float v = in[d];
#pragma unroll
        for (int j = 0; j < DOUT; j++) out[j] = fmaf(v, w[d*DOUT + j], out[j]);
    }
}

// ---------- block-level sum/sumsq reduction ----------
template<int D>
__device__ __forceinline__ void reduce_stats(const float (&h)[D], bool valid,
                                             float* __restrict__ gsum,
                                             float* __restrict__ gsq){
    __shared__ float ssum[D];
    __shared__ float ssq[D];
    int tid = threadIdx.x;
    for (int t = tid; t < D; t += 256){ ssum[t] = 0.f; ssq[t] = 0.f; }
    __syncthreads();
#pragma unroll
    for (int j = 0; j < D; j++){
        float v = valid ? h[j] : 0.f;
        float s = v * v;
#pragma unroll
        for (int o = 32; o > 0; o >>= 1){
            v += __shfl_down(v, o, 64);
            s += __shfl_down(s, o, 64);
        }
        if ((tid & 63) == 0){
            atomicAdd(&ssum[j], v);
            atomicAdd(&ssq[j], s);
        }
    }
    __syncthreads();
    for (int t = tid; t < D; t += 256){
        atomicAdd(&gsum[t], ssum[t]);
        atomicAdd(&gsq[t], ssq[t]);
    }
}

// ---------- BN coefficient from sums (inline finalize) ----------
__device__ __forceinline__ void bn_coef(const float* __restrict__ sum,
                                        const float* __restrict__ sq,
                                        const float* __restrict__ g,
                                        const float* __restrict__ bb,
                                        float invN, int c,
                                        float* __restrict__ a_out,
                                        float* __restrict__ c_out){
    float mu  = sum[c] * invN;
    float var = fmaf(-mu, mu, sq[c] * invN);
    float rs  = rsqrtf(var + EPSBN);
    float a   = rs * g[c];
    a_out[c] = a;
    c_out[c] = fmaf(-mu, a, bb[c]);
}

// ---------- stats of raw input columns 0..8 ----------
__global__ __launch_bounds__(256)
void k_stats0(const float* __restrict__ fea, float* gsum, float* gsq, int n){
    int i = blockIdx.x*256 + threadIdx.x;
    bool valid = i < n;
    int i2 = valid ? i : 0;
    float x[9];
#pragma unroll
    for (int d = 0; d < 9; d++) x[d] = fea[(size_t)i2*11 + d];
    reduce_stats<9>(x, valid, gsum, gsq);
}

// ---------- layer1: bn0 (inline fin) -> 9x32; z1 bf16; stats(rounded); cnt/rank; res ----------
__global__ __launch_bounds__(256)
void k_l1(const float* __restrict__ fea, const int* __restrict__ ind,
          const float* __restrict__ w1, const float* __restrict__ b1,
          const float* __restrict__ sum0, const float* __restrict__ sq0,
          const float* __restrict__ g0, const float* __restrict__ bb0, float invN,
          unsigned short* __restrict__ z1, unsigned* __restrict__ pres,
          unsigned* __restrict__ cnt, unsigned* __restrict__ rank,
          float* gsum, float* gsq, int n){
    __shared__ float a0s[9], c0s[9];
    int tid = threadIdx.x;
    if (tid < 9) bn_coef(sum0, sq0, g0, bb0, invN, tid, a0s, c0s);
    __syncthreads();

    int i = blockIdx.x*256 + tid;
    bool valid = i < n;
    int i2 = valid ? i : 0;
    float x[9];
#pragma unroll
    for (int d = 0; d < 9; d++) x[d] = fmaf(fea[(size_t)i2*11 + d], a0s[d], c0s[d]);
    float h[32];
    dense<9,32>(x, h, w1, b1);
    unsigned ob[16];
#pragma unroll
    for (int m = 0; m < 16; m++){
        unsigned short lo = f2bf(h[2*m]);
        unsigned short hi = f2bf(h[2*m+1]);
        ob[m] = (unsigned)lo | ((unsigned)hi << 16);
        h[2*m]   = bf2f(lo);
        h[2*m+1] = bf2f(hi);
    }
    if (valid){
        uint4* dst = (uint4*)(z1 + (size_t)i*32);
#pragma unroll
        for (int q = 0; q < 4; q++)
            dst[q] = make_uint4(ob[q*4], ob[q*4+1], ob[q*4+2], ob[q*4+3]);
        float r0 = fea[(size_t)i*11 + 9];
        float r1 = fea[(size_t)i*11 + 10];
        int bb = ind[(size_t)i*3 + 0];
        int gx = ind[(size_t)i*3 + 1];
        int gy = ind[(size_t)i*3 + 2];
        unsigned vox = ((unsigned)bb*GXd + (unsigned)gx)*GYd + (unsigned)gy;
        rank[i] = atomicAdd(&cnt[vox], 1u);
        size_t rbase = (size_t)bb*2*GXY + (size_t)gx*GYd + gy;
        atomicMax(pres + rbase,       mapf(r0));
        atomicMax(pres + rbase + GXY, mapf(r1));
    }
    reduce_stats<32>(h, valid, gsum, gsq);
}

// ---------- layer2 via MFMA (8 row-groups/block): z2 bf16; stats(rounded) ----------
__global__ __launch_bounds__(256)
void k_l2(const unsigned short* __restrict__ z1,
          const float* __restrict__ w2, const float* __restrict__ b2,
          const float* __restrict__ sum1, const float* __restrict__ sq1,
          const float* __restrict__ g1, const float* __restrict__ bb1, float invN,
          unsigned short* __restrict__ z2, float* gsum, float* gsq, int n){
    __shared__ short w2t[64*40];
    __shared__ float a1s[32], c1s[32];
    __shared__ float ssum[64], ssq[64];
    int tid = threadIdx.x;
    if (tid < 64){ ssum[tid] = 0.f; ssq[tid] = 0.f; }
    if (tid < 32) bn_coef(sum1, sq1, g1, bb1, invN, tid, a1s, c1s);
    for (int e = tid; e < 2048; e += 256){
        int k = e >> 6, c = e & 63;
        w2t[c*40 + k] = (short)f2bf(w2[k*64 + c]);
    }
    __syncthreads();

    int lane = tid & 63, wid = tid >> 6;
    int l15 = lane & 15, lg = lane >> 4;
    int kbase = lg*8;
    float4 av0 = *(const float4*)&a1s[kbase];
    float4 av1 = *(const float4*)&a1s[kbase + 4];
    float4 cv0 = *(const float4*)&c1s[kbase];
    float4 cv1 = *(const float4*)&c1s[kbase + 4];

#pragma unroll 1
    for (int rg = 0; rg < 8; rg++){
        int p0 = blockIdx.x*512 + rg*64 + wid*16;
        int prow = p0 + l15;
        int prow2 = prow < n ? prow : (n - 1);
        uint4 ua = *(const uint4*)(z1 + (size_t)prow2*32 + kbase);
        bf16x8 af;
        af[0] = (short)f2bf(fmaxf(fmaf(bf2f((unsigned short)(ua.x & 0xFFFFu)), av0.x, cv0.x), 0.f));
        af[1] = (short)f2bf(fmaxf(fmaf(bf2f((unsigned short)(ua.x >> 16)),     av0.y, cv0.y), 0.f));
        af[2] = (short)f2bf(fmaxf(fmaf(bf2f((unsigned short)(ua.y & 0xFFFFu)), av0.z, cv0.z), 0.f));
        af[3] = (short)f2bf(fmaxf(fmaf(bf2f((unsigned short)(ua.y >> 16)),     av0.w, cv0.w), 0.f));
        af[4] = (short)f2bf(fmaxf(fmaf(bf2f((unsigned short)(ua.z & 0xFFFFu)), av1.x, cv1.x), 0.f));
        af[5] = (short)f2bf(fmaxf(fmaf(bf2f((unsigned short)(ua.z >> 16)),     av1.y, cv1.y), 0.f));
        af[6] = (short)f2bf(fmaxf(fmaf(bf2f((unsigned short)(ua.w & 0xFFFFu)), av1.z, cv1.z), 0.f));
        af[7] = (short)f2bf(fmaxf(fmaf(bf2f((unsigned short)(ua.w >> 16)),     av1.w, cv1.w), 0.f));

        f32x4 acc[4];
#pragma unroll
        for (int t = 0; t < 4; t++){
            float bv = b2[t*16 + l15];
            acc[t] = (f32x4){bv, bv, bv, bv};
        }
#pragma unroll
        for (int t = 0; t < 4; t++){
            bf16x8 bf = *(const bf16x8*)&w2t[(t*16 + l15)*40 + kbase];
            acc[t] = __builtin_amdgcn_mfma_f32_16x16x32_bf16(af, bf, acc[t], 0, 0, 0);
        }

#pragma unroll
        for (int t = 0; t < 4; t++){
            int c = t*16 + l15;
            float s = 0.f, q = 0.f;
#pragma unroll
            for (int r = 0; r < 4; r++){
                int pr = p0 + lg*4 + r;
                unsigned short rb = f2bf(acc[t][r]);
                float rv = bf2f(rb);
                if (pr < n){
                    z2[(size_t)pr*64 + c] = rb;
                    s += rv; q += rv*rv;
                }
            }
            s += __shfl_xor(s, 16, 64);  q += __shfl_xor(q, 16, 64);
            s += __shfl_xor(s, 32, 64);  q += __shfl_xor(q, 32, 64);
            if (lg == 0){ atomicAdd(&ssum[c], s); atomicAdd(&ssq[c], q); }
        }
    }
    __syncthreads();
    if (tid < 64){ atomicAdd(gsum + tid, ssum[tid]); atomicAdd(gsq + tid, ssq[tid]); }
}

// ---------- layer3 via MFMA (8 row-groups/block): z3 bf16; stats(rounded) ----------
__global__ __launch_bounds__(256)
void k_l3(const unsigned short* __restrict__ z2,
          const float* __restrict__ w3, const float* __restrict__ b3,
          const float* __restrict__ sum2, const float* __restrict__ sq2,
          const float* __restrict__ g2, const float* __restrict__ bb2, float invN,
          unsigned short* __restrict__ z3, float* gsum, float* gsq, int n){
    __shared__ short w3t[128*72];
    __shared__ float a2s[64], c2s[64];
    __shared__ float ssum[128], ssq[128];
    int tid = threadIdx.x;
    if (tid < 128){ ssum[tid] = 0.f; ssq[tid] = 0.f; }
    if (tid < 64) bn_coef(sum2, sq2, g2, bb2, invN, tid, a2s, c2s);
    for (int e = tid; e < 8192; e += 256){
        int k = e >> 7, c = e & 127;
        w3t[c*72 + k] = (short)f2bf(w3[k*128 + c]);
    }
    __syncthreads();

    int lane = tid & 63, wid = tid >> 6;
    int l15 = lane & 15, lg = lane >> 4;

#pragma unroll 1
    for (int rg = 0; rg < 8; rg++){
        int p0 = blockIdx.x*512 + rg*64 + wid*16;
        int prow = p0 + l15;
        int prow2 = prow < n ? prow : (n - 1);
        const unsigned short* zrow = z2 + (size_t)prow2*64;

        f32x4 acc[8];
#pragma unroll
        for (int t = 0; t < 8; t++){
            float bv = b3[t*16 + l15];
            acc[t] = (f32x4){bv, bv, bv, bv};
        }

#pragma unroll
        for (int ks = 0; ks < 2; ks++){
            int kbase = ks*32 + lg*8;
            uint4 ua = *(const uint4*)(zrow + kbase);
            float4 av0 = *(const float4*)&a2s[kbase];
            float4 av1 = *(const float4*)&a2s[kbase + 4];
            float4 cv0 = *(const float4*)&c2s[kbase];
            float4 cv1 = *(const float4*)&c2s[kbase + 4];
            bf16x8 af;
            af[0] = (short)f2bf(fmaxf(fmaf(bf2f((unsigned short)(ua.x & 0xFFFFu)), av0.x, cv0.x), 0.f));
            af[1] = (short)f2bf(fmaxf(fmaf(bf2f((unsigned short)(ua.x >> 16)),     av0.y, cv0.y), 0.f));
            af[2] = (short)f2bf(fmaxf(fmaf(bf2f((unsigned short)(ua.y & 0xFFFFu)), av0.z, cv0.z), 0.f));
            af[3] = (short)f2bf(fmaxf(fmaf(bf2f((unsigned short)(ua.y >> 16)),     av0.w, cv0.w), 0.f));
            af[4] = (short)f2bf(fmaxf(fmaf(bf2f((unsigned short)(ua.z & 0xFFFFu)), av1.x, cv1.x), 0.f));
            af[5] = (short)f2bf(fmaxf(fmaf(bf2f((unsigned short)(ua.z >> 16)),     av1.y, cv1.y), 0.f));
            af[6] = (short)f2bf(fmaxf(fmaf(bf2f((unsigned short)(ua.w & 0xFFFFu)), av1.z, cv1.z), 0.f));
            af[7] = (short)f2bf(fmaxf(fmaf(bf2f((unsigned short)(ua.w >> 16)),     av1.w, cv1.w), 0.f));
#pragma unroll
            for (int t = 0; t < 8; t++){
                bf16x8 bf = *(const bf16x8*)&w3t[(t*16 + l15)*72 + kbase];
                acc[t] = __builtin_amdgcn_mfma_f32_16x16x32_bf16(af, bf, acc[t], 0, 0, 0);
            }
        }

#pragma unroll
        for (int t = 0; t < 8; t++){
            int c = t*16 + l15;
            float s = 0.f, q = 0.f;
#pragma unroll
            for (int r = 0; r < 4; r++){
                int pr = p0 + lg*4 + r;
                unsigned short rb = f2bf(acc[t][r]);
                float rv = bf2f(rb);
                if (pr < n){
                    z3[(size_t)pr*128 + c] = rb;
                    s += rv; q += rv*rv;
                }
            }
            s += __shfl_xor(s, 16, 64);  q += __shfl_xor(q, 16, 64);
            s += __shfl_xor(s, 32, 64);  q += __shfl_xor(q, 32, 64);
            if (lg == 0){ atomicAdd(&ssum[c], s); atomicAdd(&ssq[c], q); }
        }
    }
    __syncthreads();
    if (tid < 128){ atomicAdd(gsum + tid, ssum[tid]); atomicAdd(gsq + tid, ssq[tid]); }
}

// ---------- exclusive scan of cnt via block tickets ----------
__global__ __launch_bounds__(256)
void k_off(const unsigned* __restrict__ cnt, unsigned* __restrict__ off,
           unsigned* __restrict__ gctr){
    __shared__ unsigned wtot[4];
    __shared__ unsigned wbase[4];
    int t = threadIdx.x;
    int lane = t & 63, w = t >> 6;
    int base = blockIdx.x * 1024 + t * 4;
    bool ok = base < NCELL;
    unsigned c0 = 0, c1 = 0, c2 = 0, c3 = 0;
    if (ok){ c0 = cnt[base]; c1 = cnt[base+1]; c2 = cnt[base+2]; c3 = cnt[base+3]; }
    unsigned tot = c0 + c1 + c2 + c3;
    unsigned incl = tot;
#pragma unroll
    for (int o = 1; o < 64; o <<= 1){
        unsigned v = __shfl_up(incl, o, 64);
        if (lane >= o) incl += v;
    }
    if (lane == 63) wtot[w] = incl;
    __syncthreads();
    if (t == 0){
        unsigned bt = wtot[0] + wtot[1] + wtot[2] + wtot[3];
        unsigned gb = atomicAdd(gctr, bt);
        unsigned s = 0;
#pragma unroll
        for (int q = 0; q < 4; q++){ wbase[q] = gb + s; s += wtot[q]; }
    }
    __syncthreads();
    if (ok){
        unsigned tb = wbase[w] + incl - tot;
        off[base]   = tb;
        off[base+1] = tb + c0;
        off[base+2] = tb + c0 + c1;
        off[base+3] = tb + c0 + c1 + c2;
    }
}

// ---------- fill per-cell point lists ----------
__global__ __launch_bounds__(256)
void k_fill(const int* __restrict__ ind, const unsigned* __restrict__ rank,
            const unsigned* __restrict__ off, unsigned* __restrict__ list, int n){
    int i = blockIdx.x*256 + threadIdx.x;
    if (i >= n) return;
    int bb = ind[(size_t)i*3], gx = ind[(size_t)i*3+1], gy = ind[(size_t)i*3+2];
    unsigned vox = ((unsigned)bb*GXd + (unsigned)gx)*GYd + (unsigned)gy;
    list[off[vox] + rank[i]] = (unsigned)i;
}

// ---------- layer4 via MFMA (16 row-groups/block), SORTED output ----------
__global__ __launch_bounds__(256)
void k_l4(const unsigned short* __restrict__ z3, const unsigned* __restrict__ list,
          const float* __restrict__ w4, const float* __restrict__ b4,
          const float* __restrict__ sum3, const float* __restrict__ sq3,
          const float* __restrict__ g3, const float* __restrict__ bb3, float invN,
          unsigned short* __restrict__ z4, int n){
    __shared__ short w4t[256*128];           // 64 KB
    __shared__ float a3s[128], c3s[128];
    int tid = threadIdx.x;
    if (tid < 128) bn_coef(sum3, sq3, g3, bb3, invN, tid, a3s, c3s);
    for (int e = tid; e < 16384; e += 256){
        int k2 = e >> 8;
        int c  = e & 255;
        unsigned lo = f2bf(w4[(size_t)(2*k2)*256 + c]);
        unsigned hi = f2bf(w4[(size_t)(2*k2+1)*256 + c]);
        int addr = (c*256 + k2*4) ^ ((c & 7) << 4);
        *(unsigned*)((char*)w4t + addr) = lo | (hi << 16);
    }
    __syncthreads();

    int lane = tid & 63, wid = tid >> 6;
    int l15 = lane & 15, lg = lane >> 4;

#pragma unroll 1
    for (int rg = 0; rg < 16; rg++){
        int p0 = blockIdx.x*1024 + rg*64 + wid*16;
        int prow = p0 + l15;
        int prow2 = prow < n ? prow : (n - 1);
        int srow = (int)list[prow2];
        const unsigned short* zrow = z3 + (size_t)srow*128;

        f32x4 acc[16];
#pragma unroll
        for (int t = 0; t < 16; t++){
            float bv = b4[t*16 + l15];
            acc[t] = (f32x4){bv, bv, bv, bv};
        }

#pragma unroll
        for (int ks = 0; ks < 4; ks++){
            int kbase = ks*32 + lg*8;
            uint4 ua = *(const uint4*)(zrow + kbase);
            float4 av0 = *(const float4*)&a3s[kbase];
            float4 av1 = *(const float4*)&a3s[kbase + 4];
            float4 cv0 = *(const float4*)&c3s[kbase];
            float4 cv1 = *(const float4*)&c3s[kbase + 4];
            bf16x8 af;
            af[0] = (short)f2bf(fmaxf(fmaf(bf2f((unsigned short)(ua.x & 0xFFFFu)), av0.x, cv0.x), 0.f));
            af[1] = (short)f2bf(fmaxf(fmaf(bf2f((unsigned short)(ua.x >> 16)),     av0.y, cv0.y), 0.f));
            af[2] = (short)f2bf(fmaxf(fmaf(bf2f((unsigned short)(ua.y & 0xFFFFu)), av0.z, cv0.z), 0.f));
            af[3] = (short)f2bf(fmaxf(fmaf(bf2f((unsigned short)(ua.y >> 16)),     av0.w, cv0.w), 0.f));
            af[4] = (short)f2bf(fmaxf(fmaf(bf2f((unsigned short)(ua.z & 0xFFFFu)), av1.x, cv1.x), 0.f));
            af[5] = (short)f2bf(fmaxf(fmaf(bf2f((unsigned short)(ua.z >> 16)),     av1.y, cv1.y), 0.f));
            af[6] = (short)f2bf(fmaxf(fmaf(bf2f((unsigned short)(ua.w & 0xFFFFu)), av1.z, cv1.z), 0.f));
            af[7] = (short)f2bf(fmaxf(fmaf(bf2f((unsigned short)(ua.w >> 16)),     av1.w, cv1.w), 0.f));
#pragma unroll
            for (int t = 0; t < 16; t++){
                int c = t*16 + l15;
                int addr = (c*256 + kbase*2) ^ ((c & 7) << 4);
                bf16x8 bf = *(const bf16x8*)((const char*)w4t + addr);
                acc[t] = __builtin_amdgcn_mfma_f32_16x16x32_bf16(af, bf, acc[t], 0, 0, 0);
            }
        }

#pragma unroll
        for (int t = 0; t < 16; t++){
#pragma unroll
            for (int r = 0; r < 4; r++){
                int pr = p0 + lg*4 + r;
                if (pr < n)
                    z4[(size_t)pr*256 + t*16 + l15] = f2bf(acc[t][r]);
            }
        }
    }
}

// ---------- FUSED gather-max + 3x3 maxpool + residual, CHANNEL-SPLIT, 8-deep staging ----------
#define NOCELL 0xFFFFFFFFu
#define OTS 132
__global__ __launch_bounds__(256)
void k_gpool(const unsigned* __restrict__ cnt, const unsigned* __restrict__ off,
             const unsigned short* __restrict__ z4, const unsigned* __restrict__ pres,
             float* __restrict__ out){
    __shared__ unsigned short cm[6*18*128];   // 27648 B
    __shared__ unsigned cno[216];
    int t = threadIdx.x;
    int gy0 = blockIdx.x * 16;
    int gx0 = blockIdx.y * 4;
    int bz  = blockIdx.z;
    int b   = bz >> 1;
    int ch0 = (bz & 1) * 128;
    int ymax = GYd - gy0; if (ymax > 16) ymax = 16;

    for (int e = t; e < 108; e += 256){
        int xx = e / 18, ty = e % 18;
        int gxx = gx0 - 1 + xx, gyy = gy0 - 1 + ty;
        unsigned c = NOCELL, o = 0;
        if ((unsigned)gxx < (unsigned)GXd && (unsigned)gyy < (unsigned)GYd){
            unsigned cell = ((unsigned)b*GXd + gxx)*GYd + gyy;
            c = cnt[cell]; o = off[cell];
        }
        cno[e*2]   = c;
        cno[e*2+1] = o;
    }
    __syncthreads();

    int lane = t & 63, wid = t >> 6;
    const float NEGINF = -__builtin_inff();
    // 8 cells in flight per wave: cells e, e+4, ..., e+28 (stride 4 across 4 waves)
    for (int e = wid; e < 108; e += 32){
        unsigned cn_[8], o_[8], n_[8];
#pragma unroll
        for (int k = 0; k < 8; k++){
            int ek = e + k*4;
            bool hv = ek < 108;
            unsigned cc = hv ? cno[ek*2]   : NOCELL;
            unsigned oo = hv ? cno[ek*2+1] : 0;
            cn_[k] = cc;  o_[k] = oo;
            n_[k] = (cc == NOCELL) ? 0u : cc;
        }
        float m0[8], m1[8];
#pragma unroll
        for (int k = 0; k < 8; k++){ m0[k] = NEGINF; m1[k] = NEGINF; }
        unsigned nm = 0;
#pragma unroll
        for (int k = 0; k < 8; k++) nm = nm > n_[k] ? nm : n_[k];
        for (unsigned p = 0; p < nm; p++){
#pragma unroll
            for (int k = 0; k < 8; k++){
                if (p < n_[k]){
                    unsigned u = *(const unsigned*)(z4 + (size_t)(o_[k] + p)*256 + ch0 + lane*2);
                    m0[k] = fmaxf(m0[k], __uint_as_float(u << 16));
                    m1[k] = fmaxf(m1[k], __uint_as_float(u & 0xFFFF0000u));
                }
            }
        }
#pragma unroll
        for (int k = 0; k < 8; k++){
            int ek = e + k*4;
            if (ek < 108){
                float a0 = m0[k], a1 = m1[k];
                if (cn_[k] == 0u){ a0 = 0.f; a1 = 0.f; }
                *(unsigned*)&cm[ek*128 + lane*2] =
                    (__float_as_uint(a0) >> 16) | (__float_as_uint(a1) & 0xFFFF0000u);
            }
        }
    }
    __syncthreads();

    int c  = t & 127;
    int gp = t >> 7;
    float rA[2], rB[2];
    float ob[2][16];
#pragma unroll
    for (int gg = 0; gg < 2; gg++){ rA[gg] = 0.f; rB[gg] = 0.f; }
#pragma unroll
    for (int ty = 0; ty < 18; ty++){
        float v[6];
#pragma unroll
        for (int xx = 0; xx < 6; xx++)
            v[xx] = bf2f(cm[(xx*18 + ty)*128 + c]);
        float c3[2];
#pragma unroll
        for (int gg = 0; gg < 2; gg++){
            float va = (gp == 0) ? v[gg]     : v[gg+2];
            float vb = (gp == 0) ? v[gg+1]   : v[gg+3];
            float vc = (gp == 0) ? v[gg+2]   : v[gg+4];
            c3[gg] = fmaxf(fmaxf(va, vb), vc);
        }
        if (ty >= 2){
#pragma unroll
            for (int gg = 0; gg < 2; gg++)
                ob[gg][ty - 2] = fmaxf(fmaxf(rA[gg], rB[gg]), c3[gg]);
        }
#pragma unroll
        for (int gg = 0; gg < 2; gg++){ rA[gg] = rB[gg]; rB[gg] = c3[gg]; }
    }
    __syncthreads();

    unsigned short* ot = cm;
#pragma unroll
    for (int gg = 0; gg < 2; gg++){
        int g = gp*2 + gg;
#pragma unroll
        for (int yl = 0; yl < 16; yl++)
            ot[(g*16 + yl)*OTS + c] = (unsigned short)(__float_as_uint(ob[gg][yl]) >> 16);
    }
    __syncthreads();

    int rsub = lane >> 2;
    int gyq  = lane & 3;
    int y0   = gyq*4;
#pragma unroll
    for (int it = 0; it < 8; it++){
        int r  = wid*128 + it*16 + rsub;
        int gx = r >> 7;
        int c2 = r & 127;
        if (y0 < ymax){
            float4 o4;
            o4.x = bf2f(ot[(gx*16 + y0+0)*OTS + c2]);
            o4.y = bf2f(ot[(gx*16 + y0+1)*OTS + c2]);
            o4.z = bf2f(ot[(gx*16 + y0+2)*OTS + c2]);
            o4.w = bf2f(ot[(gx*16 + y0+3)*OTS + c2]);
            *(float4*)(out + ((size_t)b*258 + ch0 + c2)*GXY
                       + (size_t)(gx0+gx)*GYd + gy0 + y0) = o4;
        }
    }

    // residual channels for this tile (even-z blocks only)
    if ((bz & 1) == 0 && t < 128){
        int r  = t >> 6;                       // 0/1
        int g  = (t >> 4) & 3;                 // 0..3
        int y  = t & 15;
        if (y < ymax){
            unsigned u = pres[((size_t)b*2 + r)*GXY + (size_t)(gx0+g)*GYd + gy0 + y];
            float f = u ? unmapf(u) : 0.f;
            out[((size_t)b*258 + 256 + r)*GXY + (size_t)(gx0+g)*GYd + gy0 + y] = f;
        }
    }
}

extern "C" void kernel_launch(void* const* d_in, const int* in_sizes, int n_in,
                              void* d_out, int out_size, void* d_ws, size_t ws_size,
                              hipStream_t stream){
    (void)n_in; (void)out_size; (void)ws_size;
    const float* fea   = (const float*)d_in[0];
    const int*   ind   = (const int*)  d_in[1];
    const float* bn0_g = (const float*)d_in[2];
    const float* bn0_b = (const float*)d_in[3];
    const float* w1    = (const float*)d_in[4];
    const float* b1    = (const float*)d_in[5];
    const float* bn1_g = (const float*)d_in[6];
    const float* bn1_b = (const float*)d_in[7];
    const float* w2    = (const float*)d_in[8];
    const float* b2    = (const float*)d_in[9];
    const float* bn2_g = (const float*)d_in[10];
    const float* bn2_b = (const float*)d_in[11];
    const float* w3    = (const float*)d_in[12];
    const float* b3    = (const float*)d_in[13];
    const float* bn3_g = (const float*)d_in[14];
    const float* bn3_b = (const float*)d_in[15];
    const float* w4    = (const float*)d_in[16];
    const float* b4    = (const float*)d_in[17];

    int n = in_sizes[0] / 11;
    float invN = 1.0f / (float)n;

    // ---- ws layout ----
    const size_t Z4_B     = (size_t)240000*256*2;
    const size_t POOL_B   = (size_t)NCELL*256*2;        // arena for z1/z2/z3
    const size_t PRES_B   = (size_t)NBd*2*GXY*4;
    const size_t CNT_B    = (size_t)NCELL*4;
    const size_t STAT_B   = 960*4;
    const size_t GCTR_B   = 256;

    char* base = (char*)d_ws;
    unsigned short* z4 = (unsigned short*)base;
    unsigned short* z1 = (unsigned short*)(base + Z4_B);
    unsigned short* z2 = (unsigned short*)(base + Z4_B + 15360000);
    unsigned short* z3 = (unsigned short*)(base + Z4_B + 46080000);
    unsigned* pres  = (unsigned*)(base + Z4_B + POOL_B);
    unsigned* cnt   = (unsigned*)((char*)pres + PRES_B);
    float*    stats = (float*)((char*)cnt + CNT_B);
    unsigned* gctr  = (unsigned*)((char*)stats + STAT_B);
    unsigned* off   = (unsigned*)((char*)gctr + GCTR_B);
    unsigned* list  = (unsigned*)((char*)off + CNT_B);
    unsigned* rank  = (unsigned*)((char*)list + (size_t)240000*4);

    float* sum0 = stats;       float* sq0 = stats + 16;
    float* sum1 = stats + 32;  float* sq1 = stats + 64;
    float* sum2 = stats + 96;  float* sq2 = stats + 160;
    float* sum3 = stats + 224; float* sq3 = stats + 352;

    hipMemsetAsync(pres, 0, PRES_B + CNT_B + STAT_B + GCTR_B, stream);

    int nb = (n + 255) / 256;
    int nb512 = (n + 511) / 512;
    int nb1024 = (n + 1023) / 1024;
    k_stats0<<<nb, 256, 0, stream>>>(fea, sum0, sq0, n);
    k_l1<<<nb, 256, 0, stream>>>(fea, ind, w1, b1, sum0, sq0, bn0_g, bn0_b, invN,
                                 z1, pres, cnt, rank, sum1, sq1, n);
    k_l2<<<nb512, 256, 0, stream>>>(z1, w2, b2, sum1, sq1, bn1_g, bn1_b, invN,
                                    z2, sum2, sq2, n);
    k_l3<<<nb512, 256, 0, stream>>>(z2, w3, b3, sum2, sq2, bn2_g, bn2_b, invN,
                                    z3, sum3, sq3, n);

    k_off <<<(NCELL + 1023)/1024, 256, 0, stream>>>(cnt, off, gctr);
    k_fill<<<nb, 256, 0, stream>>>(ind, rank, off, list, n);

    k_l4<<<nb1024, 256, 0, stream>>>(z3, list, w4, b4, sum3, sq3, bn3_g, bn3_b, invN,
                                     z4, n);

    k_gpool<<<dim3(23, 120, 4), 256, 0, stream>>>(cnt, off, z4, pres, (float*)d_out);
}